// Round 1
// baseline (1352.353 us; speedup 1.0000x reference)
//
#include <hip/hip_runtime.h>
#include <math.h>

#define S_LEN 2048
#define D_MODEL 1024
#define NHEAD 16
#define HDIM 64
#define DFF 4096
#define IH 4
#define IDM 64
#define TOPK 64

// ---------------- LayerNorm (1 block per row, D=1024, 256 thr x float4) ----------------
__global__ __launch_bounds__(256) void ln_kernel(const float* __restrict__ x,
    const float* __restrict__ g, const float* __restrict__ b, float* __restrict__ out)
{
    int row = blockIdx.x, tid = threadIdx.x;
    const float4 v = *(const float4*)(x + (size_t)row * D_MODEL + tid * 4);
    float s = v.x + v.y + v.z + v.w;
    float ss = v.x * v.x + v.y * v.y + v.z * v.z + v.w * v.w;
    int lane = tid & 63, wv = tid >> 6;
    for (int o = 32; o; o >>= 1) { s += __shfl_xor(s, o); ss += __shfl_xor(ss, o); }
    __shared__ float rs[4], rss[4];
    if (lane == 0) { rs[wv] = s; rss[wv] = ss; }
    __syncthreads();
    float S = rs[0] + rs[1] + rs[2] + rs[3];
    float SS = rss[0] + rss[1] + rss[2] + rss[3];
    float mean = S * (1.f / D_MODEL);
    float var = SS * (1.f / D_MODEL) - mean * mean;
    float r = rsqrtf(var + 1e-5f);
    float4 gv = *(const float4*)(g + tid * 4);
    float4 bv = *(const float4*)(b + tid * 4);
    float4 o4;
    o4.x = (v.x - mean) * r * gv.x + bv.x;
    o4.y = (v.y - mean) * r * gv.y + bv.y;
    o4.z = (v.z - mean) * r * gv.z + bv.z;
    o4.w = (v.w - mean) * r * gv.w + bv.w;
    *(float4*)(out + (size_t)row * D_MODEL + tid * 4) = o4;
}

// ---------------- Generic fp32 GEMM: C[M,N] = act(A[M,K]@B[K,N] + bias) + R ----------------
// 64x64 tile, 256 threads, 4x4 per thread, BK=16. N-guarded (N can be 4/64/256/...).
// act: 0=none, 1=exact GELU. bias/R may be null. M%64==0, K%16==0 assumed.
__global__ __launch_bounds__(256) void gemm64(const float* __restrict__ A,
    const float* __restrict__ B, float* __restrict__ C,
    const float* __restrict__ bias, const float* __restrict__ R,
    int M, int N, int K, int act)
{
    __shared__ float As[16][68];  // [k][m], padded
    __shared__ float Bs[16][68];  // [k][n], padded
    int tid = threadIdx.x;
    int bm = blockIdx.y, bn = blockIdx.x;
    int tx = tid & 15, ty = tid >> 4;
    int arow = tid >> 2;              // 0..63
    int acol = (tid & 3) << 2;        // 0,4,8,12
    int brow = tid >> 4;              // 0..15
    int bcol = (tid & 15) << 2;       // 0..60
    const float* Abase = A + (size_t)(bm * 64 + arow) * K + acol;
    float c[4][4] = {};
    for (int k0 = 0; k0 < K; k0 += 16) {
        float4 av = *(const float4*)(Abase + k0);
        As[acol + 0][arow] = av.x;
        As[acol + 1][arow] = av.y;
        As[acol + 2][arow] = av.z;
        As[acol + 3][arow] = av.w;
        int gcol = bn * 64 + bcol;
        const float* Bb = B + (size_t)(k0 + brow) * N;
        float4 bv;
        if (gcol + 3 < N) {
            bv = *(const float4*)(Bb + gcol);
        } else {
            bv.x = (gcol + 0 < N) ? Bb[gcol + 0] : 0.f;
            bv.y = (gcol + 1 < N) ? Bb[gcol + 1] : 0.f;
            bv.z = (gcol + 2 < N) ? Bb[gcol + 2] : 0.f;
            bv.w = (gcol + 3 < N) ? Bb[gcol + 3] : 0.f;
        }
        *(float4*)&Bs[brow][bcol] = bv;
        __syncthreads();
#pragma unroll
        for (int kk = 0; kk < 16; ++kk) {
            float4 a4 = *(const float4*)&As[kk][ty * 4];
            float4 b4 = *(const float4*)&Bs[kk][tx * 4];
            float av4[4] = { a4.x, a4.y, a4.z, a4.w };
            float bv4[4] = { b4.x, b4.y, b4.z, b4.w };
#pragma unroll
            for (int i = 0; i < 4; ++i)
#pragma unroll
                for (int j = 0; j < 4; ++j)
                    c[i][j] += av4[i] * bv4[j];
        }
        __syncthreads();
    }
#pragma unroll
    for (int i = 0; i < 4; ++i) {
        int row = bm * 64 + ty * 4 + i;
#pragma unroll
        for (int j = 0; j < 4; ++j) {
            int col = bn * 64 + tx * 4 + j;
            if (col < N) {
                float v = c[i][j];
                if (bias) v += bias[col];
                if (act == 1) v = 0.5f * v * (1.f + erff(v * 0.70710678118654752f));
                size_t off = (size_t)row * N + col;
                if (R) v += R[off];
                C[off] = v;
            }
        }
    }
}

// ---------------- RoPE table: theta_i = 10000^(-i/32), ang = t*theta ----------------
__global__ __launch_bounds__(256) void rope_table_kernel(float* __restrict__ ct, float* __restrict__ st)
{
    int g = blockIdx.x * 256 + threadIdx.x;   // < 2048*32
    int t = g >> 5, i = g & 31;
    float theta = powf(10000.f, -(float)i / 32.f);
    float ang = (float)t * theta;
    ct[g] = cosf(ang);
    st[g] = sinf(ang);
}

// ---------------- RoPE apply (interleaved pairs) on q,k halves of qkv, in-place ----------------
__global__ __launch_bounds__(512) void rope_apply_kernel(float* __restrict__ qkv,
    const float* __restrict__ ct, const float* __restrict__ st)
{
    int t = blockIdx.x, tid = threadIdx.x;   // 512 = 16 heads * 32 pairs
    int h = tid >> 5, i = tid & 31;
    float c = ct[t * 32 + i], s = st[t * 32 + i];
    float* qp = qkv + (size_t)t * (3 * D_MODEL) + h * HDIM + 2 * i;
    float2 q = *(float2*)qp;
    float2 qo = { q.x * c - q.y * s, q.y * c + q.x * s };
    *(float2*)qp = qo;
    float* kp = qp + D_MODEL;
    float2 k = *(float2*)kp;
    float2 ko = { k.x * c - k.y * s, k.y * c + k.x * s };
    *(float2*)kp = ko;
}

// ---------------- Indexer scores: I[t,s] = sum_h wi[t,h]*relu(qi[t,h,:].ki[s,:]), s<=t ----------------
// 32x32 tile per block, 256 threads (each: 1 s, 4 t).
__global__ __launch_bounds__(256) void scores_kernel(const float* __restrict__ qi,
    const float* __restrict__ ki, const float* __restrict__ wi, float* __restrict__ scores)
{
    int t0 = blockIdx.y * 32, s0 = blockIdx.x * 32;
    if (s0 > t0 + 31) return;   // strictly-above-diagonal tile: never read
    __shared__ float qis[32][256];
    __shared__ float kis[32][65];   // pad 65: bank = (s + d) % 32, conflict-free
    __shared__ float wis[32][4];
    int tid = threadIdx.x;
    // load qi tile: 32x256 floats
#pragma unroll
    for (int l = 0; l < 8; ++l) {
        int idx = l * 256 + tid;
        int r = idx >> 6, c = (idx & 63) << 2;
        *(float4*)&qis[r][c] = *(const float4*)(qi + (size_t)(t0 + r) * 256 + c);
    }
    // load ki tile: 32x64 floats (scalar stores into padded LDS)
#pragma unroll
    for (int l = 0; l < 2; ++l) {
        int idx = l * 256 + tid;
        int r = idx >> 6, c = idx & 63;
        // 256 threads cover 4 rows per pass of 64 cols? idx>>6: 0..7 rows per pass
        kis[r + l * 0][c] = 0.f; // placeholder overwritten below
    }
    // correct ki load: 2048 floats total, idx = l*256+tid, r = idx>>6 (0..31 over l=0..7)? use 8 passes of 256
#pragma unroll
    for (int l = 0; l < 8; ++l) {
        int idx = l * 256 + tid;
        int r = idx >> 6, c = idx & 63;
        kis[r][c] = ki[(size_t)(s0 + r) * 64 + c];
    }
    if (tid < 32) *(float4*)&wis[tid][0] = *(const float4*)(wi + (size_t)(t0 + tid) * 4);
    __syncthreads();
    int sl = tid & 31;
    int tb = (tid >> 5) * 4;
    float acc[4] = { 0.f, 0.f, 0.f, 0.f };
#pragma unroll
    for (int h = 0; h < 4; ++h) {
        float dots[4] = { 0.f, 0.f, 0.f, 0.f };
        for (int d = 0; d < 64; ++d) {
            float kv = kis[sl][d];
#pragma unroll
            for (int i = 0; i < 4; ++i)
                dots[i] += qis[tb + i][h * 64 + d] * kv;
        }
#pragma unroll
        for (int i = 0; i < 4; ++i)
            acc[i] += wis[tb + i][h] * fmaxf(dots[i], 0.f);
    }
#pragma unroll
    for (int i = 0; i < 4; ++i)
        scores[(size_t)(t0 + tb + i) * S_LEN + s0 + sl] = acc[i];
}

// ---------------- Top-K (iterative max-extract, ties -> lowest index, matches lax.top_k) ----------------
__global__ __launch_bounds__(256) void topk_kernel(const float* __restrict__ scores,
    int* __restrict__ topidx, int* __restrict__ topcnt)
{
    int t = blockIdx.x, tid = threadIdx.x;
    __shared__ float sc[S_LEN];
    __shared__ float wmax[4];
    __shared__ int widx[4];
    int n = t + 1;
    for (int j = tid; j < n; j += 256) sc[j] = scores[(size_t)t * S_LEN + j];
    __syncthreads();
    int kmax = n < TOPK ? n : TOPK;
    int lane = tid & 63, wv = tid >> 6;
    for (int it = 0; it < kmax; ++it) {
        float best = -INFINITY;
        int bidx = 0x7fffffff;
        for (int j = tid; j < n; j += 256) {
            float v = sc[j];
            if (v > best || (v == best && j < bidx)) { best = v; bidx = j; }
        }
        for (int o = 32; o; o >>= 1) {
            float ov = __shfl_xor(best, o);
            int oi = __shfl_xor(bidx, o);
            if (ov > best || (ov == best && oi < bidx)) { best = ov; bidx = oi; }
        }
        if (lane == 0) { wmax[wv] = best; widx[wv] = bidx; }
        __syncthreads();
        if (tid == 0) {
            float bb = wmax[0]; int bi = widx[0];
#pragma unroll
            for (int w = 1; w < 4; ++w)
                if (wmax[w] > bb || (wmax[w] == bb && widx[w] < bi)) { bb = wmax[w]; bi = widx[w]; }
            topidx[t * TOPK + it] = bi;
            sc[bi] = -INFINITY;
        }
        __syncthreads();
    }
    if (tid == 0) topcnt[t] = kmax;
}

// ---------------- Sparse SDPA: 1 block per query token, 1 wave handles a head's 64 keys ----------------
__global__ __launch_bounds__(256) void attn_kernel(const float* __restrict__ qkv,
    const int* __restrict__ topidx, const int* __restrict__ topcnt, float* __restrict__ out)
{
    int t = blockIdx.x, tid = threadIdx.x;
    __shared__ float qs[D_MODEL];
    __shared__ int sel[TOPK];
    *(float4*)(qs + tid * 4) = *(const float4*)(qkv + (size_t)t * (3 * D_MODEL) + tid * 4);
    if (tid < TOPK) sel[tid] = topidx[t * TOPK + tid];
    __syncthreads();
    int cnt = topcnt[t];
    int lane = tid & 63, wv = tid >> 6;
#pragma unroll
    for (int hh = 0; hh < 4; ++hh) {
        int h = wv * 4 + hh;
        float logit = -INFINITY;
        if (lane < cnt) {
            int s = sel[lane];
            const float4* kp = (const float4*)(qkv + (size_t)s * (3 * D_MODEL) + D_MODEL + h * HDIM);
            const float4* qp = (const float4*)(qs + h * HDIM);
            float acc = 0.f;
#pragma unroll
            for (int d4 = 0; d4 < 16; ++d4) {
                float4 k4 = kp[d4];
                float4 q4 = qp[d4];
                acc += q4.x * k4.x + q4.y * k4.y + q4.z * k4.z + q4.w * k4.w;
            }
            logit = acc * 0.125f;
        }
        float m = logit;
        for (int o = 32; o; o >>= 1) m = fmaxf(m, __shfl_xor(m, o));
        float p = (lane < cnt) ? expf(logit - m) : 0.f;
        float sum = p;
        for (int o = 32; o; o >>= 1) sum += __shfl_xor(sum, o);
        p /= sum;
        float acc = 0.f;
        for (int si = 0; si < cnt; ++si) {
            float pv = __shfl(p, si);
            int s = sel[si];
            acc += pv * qkv[(size_t)s * (3 * D_MODEL) + 2 * D_MODEL + h * HDIM + lane];
        }
        out[(size_t)t * D_MODEL + h * HDIM + lane] = acc;
    }
}

extern "C" void kernel_launch(void* const* d_in, const int* in_sizes, int n_in,
                              void* d_out, int out_size, void* d_ws, size_t ws_size,
                              hipStream_t stream)
{
    const float* x      = (const float*)d_in[0];
    const float* w_qkv  = (const float*)d_in[1];
    const float* w_o    = (const float*)d_in[2];
    const float* ffn_w1 = (const float*)d_in[3];
    const float* ffn_b1 = (const float*)d_in[4];
    const float* ffn_w2 = (const float*)d_in[5];
    const float* ffn_b2 = (const float*)d_in[6];
    const float* ln1_g  = (const float*)d_in[7];
    const float* ln1_b  = (const float*)d_in[8];
    const float* ln2_g  = (const float*)d_in[9];
    const float* ln2_b  = (const float*)d_in[10];
    const float* idx_wq = (const float*)d_in[11];
    const float* idx_wk = (const float*)d_in[12];
    const float* idx_ww = (const float*)d_in[13];
    float* outp = (float*)d_out;

    const size_t MB = 1ull << 20;
    char* ws = (char*)d_ws;
    float* normx   = (float*)(ws + 0);          // 8MB; reused as h (LN2 out)
    float* qkvb    = (float*)(ws + 8 * MB);     // 24MB; region 8..40MB reused as ffn1 (32MB)
    float* qib     = (float*)(ws + 32 * MB);    // 2MB
    float* kib     = (float*)(ws + 34 * MB);    // 512KB
    float* wib     = (float*)(ws + 35 * MB);    // 32KB
    float* ffn1    = qkvb;                      // 32MB (after attention done)
    float* scoresb = (float*)(ws + 40 * MB);    // 16MB; reused as attn_out (8MB)
    float* attn_o  = scoresb;
    int*   topidx  = (int*)(ws + 56 * MB);      // 512KB
    int*   topcnt  = (int*)(ws + 56 * MB + 512 * 1024);  // 8KB
    float* ctab    = (float*)(ws + 57 * MB);    // 256KB
    float* stab    = (float*)(ws + 57 * MB + 256 * 1024);

    dim3 blk256(256);
    auto gemmGrid = [](int N, int M) { return dim3((N + 63) / 64, M / 64); };

    // 1. norm_x = LN1(x)
    ln_kernel<<<S_LEN, blk256, 0, stream>>>(x, ln1_g, ln1_b, normx);
    // 2. rope tables
    rope_table_kernel<<<(S_LEN * 32) / 256, blk256, 0, stream>>>(ctab, stab);
    // 3. qkv = norm_x @ w_qkv
    gemm64<<<gemmGrid(3 * D_MODEL, S_LEN), blk256, 0, stream>>>(normx, w_qkv, qkvb,
        nullptr, nullptr, S_LEN, 3 * D_MODEL, D_MODEL, 0);
    // 4-6. indexer projections
    gemm64<<<gemmGrid(IH * IDM, S_LEN), blk256, 0, stream>>>(normx, idx_wq, qib,
        nullptr, nullptr, S_LEN, IH * IDM, D_MODEL, 0);
    gemm64<<<gemmGrid(IDM, S_LEN), blk256, 0, stream>>>(normx, idx_wk, kib,
        nullptr, nullptr, S_LEN, IDM, D_MODEL, 0);
    gemm64<<<gemmGrid(IH, S_LEN), blk256, 0, stream>>>(normx, idx_ww, wib,
        nullptr, nullptr, S_LEN, IH, D_MODEL, 0);
    // 7. RoPE on q,k
    rope_apply_kernel<<<S_LEN, dim3(512), 0, stream>>>(qkvb, ctab, stab);
    // 8. indexer scores (lower-triangular tiles only)
    scores_kernel<<<dim3(64, 64), blk256, 0, stream>>>(qib, kib, wib, scoresb);
    // 9. top-64 per row
    topk_kernel<<<S_LEN, blk256, 0, stream>>>(scoresb, topidx, topcnt);
    // 10. sparse attention
    attn_kernel<<<S_LEN, blk256, 0, stream>>>(qkvb, topidx, topcnt, attn_o);
    // 11. x1 = x + attn_out @ w_o   (written to d_out)
    gemm64<<<gemmGrid(D_MODEL, S_LEN), blk256, 0, stream>>>(attn_o, w_o, outp,
        nullptr, x, S_LEN, D_MODEL, D_MODEL, 0);
    // 12. h = LN2(x1)
    ln_kernel<<<S_LEN, blk256, 0, stream>>>(outp, ln2_g, ln2_b, normx);
    // 13. ffn1 = gelu(h @ w1 + b1)
    gemm64<<<gemmGrid(DFF, S_LEN), blk256, 0, stream>>>(normx, ffn_w1, ffn1,
        ffn_b1, nullptr, S_LEN, DFF, D_MODEL, 1);
    // 14. out = x1 + ffn1 @ w2 + b2
    gemm64<<<gemmGrid(D_MODEL, S_LEN), blk256, 0, stream>>>(ffn1, ffn_w2, outp,
        ffn_b2, outp, S_LEN, D_MODEL, DFF, 0);
}

// Round 2
// 825.228 us; speedup vs baseline: 1.6388x; 1.6388x over previous
//
#include <hip/hip_runtime.h>
#include <math.h>

#define S_LEN 2048
#define D_MODEL 1024
#define NHEAD 16
#define HDIM 64
#define DFF 4096
#define IH 4
#define IDM 64
#define TOPK 64

typedef float f32x4 __attribute__((ext_vector_type(4)));
typedef short bf16x8 __attribute__((ext_vector_type(8)));

__device__ __forceinline__ unsigned short f2bf(float f) {
    unsigned u = __builtin_bit_cast(unsigned, f);
    u += 0x7fff + ((u >> 16) & 1);
    return (unsigned short)(u >> 16);
}

__device__ __forceinline__ float gelu_exact(float v) {
    return 0.5f * v * (1.f + erff(v * 0.70710678118654752f));
}

__device__ __forceinline__ void gl_lds16(const void* g, void* l) {
    __builtin_amdgcn_global_load_lds(
        (const __attribute__((address_space(1))) void*)g,
        (__attribute__((address_space(3))) void*)l, 16, 0, 0);
}

// ---------------- LayerNorm: fp32 out (optional) + bf16 out (optional) ----------------
__global__ __launch_bounds__(256) void ln_kernel(const float* __restrict__ x,
    const float* __restrict__ g, const float* __restrict__ b,
    float* __restrict__ outf, unsigned short* __restrict__ outb)
{
    int row = blockIdx.x, tid = threadIdx.x;
    const float4 v = *(const float4*)(x + (size_t)row * D_MODEL + tid * 4);
    float s = v.x + v.y + v.z + v.w;
    float ss = v.x * v.x + v.y * v.y + v.z * v.z + v.w * v.w;
    int lane = tid & 63, wv = tid >> 6;
    for (int o = 32; o; o >>= 1) { s += __shfl_xor(s, o); ss += __shfl_xor(ss, o); }
    __shared__ float rs[4], rss[4];
    if (lane == 0) { rs[wv] = s; rss[wv] = ss; }
    __syncthreads();
    float S = rs[0] + rs[1] + rs[2] + rs[3];
    float SS = rss[0] + rss[1] + rss[2] + rss[3];
    float mean = S * (1.f / D_MODEL);
    float var = SS * (1.f / D_MODEL) - mean * mean;
    float r = rsqrtf(var + 1e-5f);
    float4 gv = *(const float4*)(g + tid * 4);
    float4 bv = *(const float4*)(b + tid * 4);
    float4 o4;
    o4.x = (v.x - mean) * r * gv.x + bv.x;
    o4.y = (v.y - mean) * r * gv.y + bv.y;
    o4.z = (v.z - mean) * r * gv.z + bv.z;
    o4.w = (v.w - mean) * r * gv.w + bv.w;
    if (outf) *(float4*)(outf + (size_t)row * D_MODEL + tid * 4) = o4;
    if (outb) {
        ushort4 u4 = { f2bf(o4.x), f2bf(o4.y), f2bf(o4.z), f2bf(o4.w) };
        *(ushort4*)(outb + (size_t)row * D_MODEL + tid * 4) = u4;
    }
}

// ---------------- Weight convert + transpose: fp32 [K][N] -> bf16 [N][K] ----------------
__global__ __launch_bounds__(256) void wtrans_kernel(const float* __restrict__ in,
    unsigned short* __restrict__ out, int K, int N)
{
    __shared__ float t[32][33];
    int k0 = blockIdx.y * 32, n0 = blockIdx.x * 32;
    int tid = threadIdx.x;
    int r = tid >> 5, c = tid & 31;
#pragma unroll
    for (int p = 0; p < 4; ++p)
        t[r + p * 8][c] = in[(size_t)(k0 + r + p * 8) * N + n0 + c];
    __syncthreads();
#pragma unroll
    for (int p = 0; p < 4; ++p)
        out[(size_t)(n0 + r + p * 8) * K + k0 + c] = f2bf(t[c][r + p * 8]);
}

// ---------------- bf16 MFMA GEMM (m97 structure): C = act(A @ Bt^T + bias) + R ----------------
// A: bf16 [M][K], Bt: bf16 [N][K]. 128x128 tile, BK=32, 4 waves, 4x4 frags/wave.
// M,N,K multiples of 128/128/32. C (fp32) and/or Cb (bf16) outputs, bias/R optional.
__global__ __launch_bounds__(256) void gemm_bf16(
    const unsigned short* __restrict__ A, const unsigned short* __restrict__ Bt,
    float* __restrict__ C, unsigned short* __restrict__ Cb,
    const float* __restrict__ bias, const float* __restrict__ R,
    int M, int N, int K, int act)
{
    __shared__ __attribute__((aligned(16))) unsigned short As[128 * 32];
    __shared__ __attribute__((aligned(16))) unsigned short Bs[128 * 32];
    int tid = threadIdx.x;
    int bm = blockIdx.y * 128, bn = blockIdx.x * 128;
    int wid = tid >> 6, lane = tid & 63;
    int wm = (wid >> 1) * 64, wn = (wid & 1) * 64;
    const unsigned short* Ab = A + (size_t)bm * K;
    const unsigned short* Bb = Bt + (size_t)bn * K;
    f32x4 acc[4][4];
#pragma unroll
    for (int i = 0; i < 4; ++i)
#pragma unroll
        for (int j = 0; j < 4; ++j)
            acc[i][j] = (f32x4){0.f, 0.f, 0.f, 0.f};

    int fr = lane & 15, fk = (lane >> 4) * 8;
    for (int k0 = 0; k0 < K; k0 += 32) {
#pragma unroll
        for (int i = 0; i < 2; ++i) {
            int e = (i * 256 + tid) * 8;      // elem offset in 128x32 tile
            int r = e >> 5, c = e & 31;
            gl_lds16(Ab + (size_t)r * K + k0 + c, As + e);
            gl_lds16(Bb + (size_t)r * K + k0 + c, Bs + e);
        }
        __syncthreads();
        bf16x8 af[4], bfv[4];
#pragma unroll
        for (int mi = 0; mi < 4; ++mi)
            af[mi] = *(const bf16x8*)&As[(wm + mi * 16 + fr) * 32 + fk];
#pragma unroll
        for (int ni = 0; ni < 4; ++ni)
            bfv[ni] = *(const bf16x8*)&Bs[(wn + ni * 16 + fr) * 32 + fk];
#pragma unroll
        for (int mi = 0; mi < 4; ++mi)
#pragma unroll
            for (int ni = 0; ni < 4; ++ni)
                acc[mi][ni] = __builtin_amdgcn_mfma_f32_16x16x32_bf16(
                    af[mi], bfv[ni], acc[mi][ni], 0, 0, 0);
        __syncthreads();
    }
    // epilogue: C/D layout col = lane&15, row = (lane>>4)*4 + reg
    int cl = lane & 15, rh = (lane >> 4) * 4;
#pragma unroll
    for (int mi = 0; mi < 4; ++mi) {
#pragma unroll
        for (int ni = 0; ni < 4; ++ni) {
            int col = bn + wn + ni * 16 + cl;
            float bv = bias ? bias[col] : 0.f;
#pragma unroll
            for (int r = 0; r < 4; ++r) {
                int row = bm + wm + mi * 16 + rh + r;
                float v = acc[mi][ni][r] + bv;
                if (act) v = gelu_exact(v);
                size_t off = (size_t)row * N + col;
                if (R) v += R[off];
                if (C) C[off] = v;
                if (Cb) Cb[off] = f2bf(v);
            }
        }
    }
}

// ---------------- Generic fp32 GEMM (indexer path only): C[M,N] = A[M,K]@B[K,N] ----------------
__global__ __launch_bounds__(256) void gemm64(const float* __restrict__ A,
    const float* __restrict__ B, float* __restrict__ C,
    int M, int N, int K)
{
    __shared__ float As[16][68];
    __shared__ float Bs[16][68];
    int tid = threadIdx.x;
    int bm = blockIdx.y, bn = blockIdx.x;
    int tx = tid & 15, ty = tid >> 4;
    int arow = tid >> 2;
    int acol = (tid & 3) << 2;
    int brow = tid >> 4;
    int bcol = (tid & 15) << 2;
    const float* Abase = A + (size_t)(bm * 64 + arow) * K + acol;
    float c[4][4] = {};
    for (int k0 = 0; k0 < K; k0 += 16) {
        float4 av = *(const float4*)(Abase + k0);
        As[acol + 0][arow] = av.x;
        As[acol + 1][arow] = av.y;
        As[acol + 2][arow] = av.z;
        As[acol + 3][arow] = av.w;
        int gcol = bn * 64 + bcol;
        const float* Bb = B + (size_t)(k0 + brow) * N;
        float4 bv;
        if (gcol + 3 < N) {
            bv = *(const float4*)(Bb + gcol);
        } else {
            bv.x = (gcol + 0 < N) ? Bb[gcol + 0] : 0.f;
            bv.y = (gcol + 1 < N) ? Bb[gcol + 1] : 0.f;
            bv.z = (gcol + 2 < N) ? Bb[gcol + 2] : 0.f;
            bv.w = (gcol + 3 < N) ? Bb[gcol + 3] : 0.f;
        }
        *(float4*)&Bs[brow][bcol] = bv;
        __syncthreads();
#pragma unroll
        for (int kk = 0; kk < 16; ++kk) {
            float4 a4 = *(const float4*)&As[kk][ty * 4];
            float4 b4 = *(const float4*)&Bs[kk][tx * 4];
            float av4[4] = { a4.x, a4.y, a4.z, a4.w };
            float bv4[4] = { b4.x, b4.y, b4.z, b4.w };
#pragma unroll
            for (int i = 0; i < 4; ++i)
#pragma unroll
                for (int j = 0; j < 4; ++j)
                    c[i][j] += av4[i] * bv4[j];
        }
        __syncthreads();
    }
#pragma unroll
    for (int i = 0; i < 4; ++i) {
        int row = bm * 64 + ty * 4 + i;
#pragma unroll
        for (int j = 0; j < 4; ++j) {
            int col = bn * 64 + tx * 4 + j;
            if (col < N)
                C[(size_t)row * N + col] = c[i][j];
        }
    }
}

// ---------------- RoPE table ----------------
__global__ __launch_bounds__(256) void rope_table_kernel(float* __restrict__ ct, float* __restrict__ st)
{
    int g = blockIdx.x * 256 + threadIdx.x;
    int t = g >> 5, i = g & 31;
    float theta = powf(10000.f, -(float)i / 32.f);
    float ang = (float)t * theta;
    ct[g] = cosf(ang);
    st[g] = sinf(ang);
}

// ---------------- RoPE apply (interleaved pairs) on q,k halves of qkv, in-place ----------------
__global__ __launch_bounds__(512) void rope_apply_kernel(float* __restrict__ qkv,
    const float* __restrict__ ct, const float* __restrict__ st)
{
    int t = blockIdx.x, tid = threadIdx.x;
    int h = tid >> 5, i = tid & 31;
    float c = ct[t * 32 + i], s = st[t * 32 + i];
    float* qp = qkv + (size_t)t * (3 * D_MODEL) + h * HDIM + 2 * i;
    float2 q = *(float2*)qp;
    float2 qo = { q.x * c - q.y * s, q.y * c + q.x * s };
    *(float2*)qp = qo;
    float* kp = qp + D_MODEL;
    float2 k = *(float2*)kp;
    float2 ko = { k.x * c - k.y * s, k.y * c + k.x * s };
    *(float2*)kp = ko;
}

// ---------------- Indexer scores (fp32 for top-k stability) ----------------
__global__ __launch_bounds__(256) void scores_kernel(const float* __restrict__ qi,
    const float* __restrict__ ki, const float* __restrict__ wi, float* __restrict__ scores)
{
    int t0 = blockIdx.y * 32, s0 = blockIdx.x * 32;
    if (s0 > t0 + 31) return;
    __shared__ float qis[32][256];
    __shared__ float kis[32][65];
    __shared__ float wis[32][4];
    int tid = threadIdx.x;
#pragma unroll
    for (int l = 0; l < 8; ++l) {
        int idx = l * 256 + tid;
        int r = idx >> 6, c = (idx & 63) << 2;
        *(float4*)&qis[r][c] = *(const float4*)(qi + (size_t)(t0 + r) * 256 + c);
    }
#pragma unroll
    for (int l = 0; l < 8; ++l) {
        int idx = l * 256 + tid;
        int r = idx >> 6, c = idx & 63;
        kis[r][c] = ki[(size_t)(s0 + r) * 64 + c];
    }
    if (tid < 32) *(float4*)&wis[tid][0] = *(const float4*)(wi + (size_t)(t0 + tid) * 4);
    __syncthreads();
    int sl = tid & 31;
    int tb = (tid >> 5) * 4;
    float acc[4] = { 0.f, 0.f, 0.f, 0.f };
#pragma unroll
    for (int h = 0; h < 4; ++h) {
        float dots[4] = { 0.f, 0.f, 0.f, 0.f };
        for (int d = 0; d < 64; ++d) {
            float kv = kis[sl][d];
#pragma unroll
            for (int i = 0; i < 4; ++i)
                dots[i] += qis[tb + i][h * 64 + d] * kv;
        }
#pragma unroll
        for (int i = 0; i < 4; ++i)
            acc[i] += wis[tb + i][h] * fmaxf(dots[i], 0.f);
    }
#pragma unroll
    for (int i = 0; i < 4; ++i)
        scores[(size_t)(t0 + tb + i) * S_LEN + s0 + sl] = acc[i];
}

// ---------------- Top-K (iterative max-extract, ties -> lowest index) ----------------
__global__ __launch_bounds__(256) void topk_kernel(const float* __restrict__ scores,
    int* __restrict__ topidx, int* __restrict__ topcnt)
{
    int t = blockIdx.x, tid = threadIdx.x;
    __shared__ float sc[S_LEN];
    __shared__ float wmax[4];
    __shared__ int widx[4];
    int n = t + 1;
    for (int j = tid; j < n; j += 256) sc[j] = scores[(size_t)t * S_LEN + j];
    __syncthreads();
    int kmax = n < TOPK ? n : TOPK;
    int lane = tid & 63, wv = tid >> 6;
    for (int it = 0; it < kmax; ++it) {
        float best = -INFINITY;
        int bidx = 0x7fffffff;
        for (int j = tid; j < n; j += 256) {
            float v = sc[j];
            if (v > best || (v == best && j < bidx)) { best = v; bidx = j; }
        }
        for (int o = 32; o; o >>= 1) {
            float ov = __shfl_xor(best, o);
            int oi = __shfl_xor(bidx, o);
            if (ov > best || (ov == best && oi < bidx)) { best = ov; bidx = oi; }
        }
        if (lane == 0) { wmax[wv] = best; widx[wv] = bidx; }
        __syncthreads();
        if (tid == 0) {
            float bb = wmax[0]; int bi = widx[0];
#pragma unroll
            for (int w = 1; w < 4; ++w)
                if (wmax[w] > bb || (wmax[w] == bb && widx[w] < bi)) { bb = wmax[w]; bi = widx[w]; }
            topidx[t * TOPK + it] = bi;
            sc[bi] = -INFINITY;
        }
        __syncthreads();
    }
    if (tid == 0) topcnt[t] = kmax;
}

// ---------------- Sparse SDPA -> bf16 output ----------------
__global__ __launch_bounds__(256) void attn_kernel(const float* __restrict__ qkv,
    const int* __restrict__ topidx, const int* __restrict__ topcnt,
    unsigned short* __restrict__ out)
{
    int t = blockIdx.x, tid = threadIdx.x;
    __shared__ float qs[D_MODEL];
    __shared__ int sel[TOPK];
    *(float4*)(qs + tid * 4) = *(const float4*)(qkv + (size_t)t * (3 * D_MODEL) + tid * 4);
    if (tid < TOPK) sel[tid] = topidx[t * TOPK + tid];
    __syncthreads();
    int cnt = topcnt[t];
    int lane = tid & 63, wv = tid >> 6;
#pragma unroll
    for (int hh = 0; hh < 4; ++hh) {
        int h = wv * 4 + hh;
        float logit = -INFINITY;
        if (lane < cnt) {
            int s = sel[lane];
            const float4* kp = (const float4*)(qkv + (size_t)s * (3 * D_MODEL) + D_MODEL + h * HDIM);
            const float4* qp = (const float4*)(qs + h * HDIM);
            float acc = 0.f;
#pragma unroll
            for (int d4 = 0; d4 < 16; ++d4) {
                float4 k4 = kp[d4];
                float4 q4 = qp[d4];
                acc += q4.x * k4.x + q4.y * k4.y + q4.z * k4.z + q4.w * k4.w;
            }
            logit = acc * 0.125f;
        }
        float m = logit;
        for (int o = 32; o; o >>= 1) m = fmaxf(m, __shfl_xor(m, o));
        float p = (lane < cnt) ? expf(logit - m) : 0.f;
        float sum = p;
        for (int o = 32; o; o >>= 1) sum += __shfl_xor(sum, o);
        p /= sum;
        float acc = 0.f;
        for (int si = 0; si < cnt; ++si) {
            float pv = __shfl(p, si);
            int s = sel[si];
            acc += pv * qkv[(size_t)s * (3 * D_MODEL) + 2 * D_MODEL + h * HDIM + lane];
        }
        out[(size_t)t * D_MODEL + h * HDIM + lane] = f2bf(acc);
    }
}

extern "C" void kernel_launch(void* const* d_in, const int* in_sizes, int n_in,
                              void* d_out, int out_size, void* d_ws, size_t ws_size,
                              hipStream_t stream)
{
    const float* x      = (const float*)d_in[0];
    const float* w_qkv  = (const float*)d_in[1];
    const float* w_o    = (const float*)d_in[2];
    const float* ffn_w1 = (const float*)d_in[3];
    const float* ffn_b1 = (const float*)d_in[4];
    const float* ffn_w2 = (const float*)d_in[5];
    const float* ffn_b2 = (const float*)d_in[6];
    const float* ln1_g  = (const float*)d_in[7];
    const float* ln1_b  = (const float*)d_in[8];
    const float* ln2_g  = (const float*)d_in[9];
    const float* ln2_b  = (const float*)d_in[10];
    const float* idx_wq = (const float*)d_in[11];
    const float* idx_wk = (const float*)d_in[12];
    const float* idx_ww = (const float*)d_in[13];
    float* outp = (float*)d_out;

    const size_t MB = 1ull << 20;
    char* ws = (char*)d_ws;
    // layout (~80.5 MB):
    float*          normx    = (float*)(ws + 0);           // 8MB fp32 LN1 out (indexer path)
    unsigned short* attno_bf = (unsigned short*)(ws + 0);  // 4MB, reuses normx after indexer gemms
    float*          qkvb     = (float*)(ws + 8 * MB);      // 24MB fp32
    unsigned short* normx_bf = (unsigned short*)(ws + 32 * MB); // 4MB (LN1 bf16; reused as LN2 bf16)
    unsigned short* h2_bf    = normx_bf;
    unsigned short* wqkv_t   = (unsigned short*)(ws + 36 * MB); // 6MB [3072][1024]
    unsigned short* wo_t     = (unsigned short*)(ws + 42 * MB); // 2MB [1024][1024]
    unsigned short* w1_t     = (unsigned short*)(ws + 44 * MB); // 8MB [4096][1024]
    unsigned short* w2_t     = (unsigned short*)(ws + 52 * MB); // 8MB [1024][4096]
    float*          scoresb  = (float*)(ws + 60 * MB);     // 16MB; reused as ffn1_bf
    unsigned short* ffn1_bf  = (unsigned short*)(ws + 60 * MB); // 16MB [2048][4096]
    float*          qib      = (float*)(ws + 76 * MB);     // 2MB
    float*          kib      = (float*)(ws + 78 * MB);     // 512KB
    float*          wib      = (float*)(ws + 78 * MB + 512 * 1024); // 32KB
    int*            topidx   = (int*)(ws + 79 * MB);       // 512KB
    int*            topcnt   = (int*)(ws + 79 * MB + 512 * 1024);  // 8KB
    float*          ctab     = (float*)(ws + 80 * MB);     // 256KB
    float*          stab     = (float*)(ws + 80 * MB + 256 * 1024);

    dim3 blk256(256);
    auto g64 = [](int N, int M) { return dim3((N + 63) / 64, M / 64); };
    auto g128 = [](int N, int M) { return dim3(N / 128, M / 128); };

    // 1. LN1 -> fp32 (indexer) + bf16 (qkv gemm)
    ln_kernel<<<S_LEN, blk256, 0, stream>>>(x, ln1_g, ln1_b, normx, normx_bf);
    // 2. rope tables + weight transposes (independent)
    rope_table_kernel<<<(S_LEN * 32) / 256, blk256, 0, stream>>>(ctab, stab);
    wtrans_kernel<<<dim3(3 * D_MODEL / 32, D_MODEL / 32), blk256, 0, stream>>>(w_qkv, wqkv_t, D_MODEL, 3 * D_MODEL);
    wtrans_kernel<<<dim3(D_MODEL / 32, D_MODEL / 32), blk256, 0, stream>>>(w_o, wo_t, D_MODEL, D_MODEL);
    wtrans_kernel<<<dim3(DFF / 32, D_MODEL / 32), blk256, 0, stream>>>(ffn_w1, w1_t, D_MODEL, DFF);
    wtrans_kernel<<<dim3(D_MODEL / 32, DFF / 32), blk256, 0, stream>>>(ffn_w2, w2_t, DFF, D_MODEL);
    // 3. qkv = norm_x @ w_qkv   (bf16 MFMA)
    gemm_bf16<<<g128(3 * D_MODEL, S_LEN), blk256, 0, stream>>>(normx_bf, wqkv_t,
        qkvb, nullptr, nullptr, nullptr, S_LEN, 3 * D_MODEL, D_MODEL, 0);
    // 4-6. indexer projections (fp32 — feed discrete top-k)
    gemm64<<<g64(IH * IDM, S_LEN), blk256, 0, stream>>>(normx, idx_wq, qib, S_LEN, IH * IDM, D_MODEL);
    gemm64<<<g64(IDM, S_LEN), blk256, 0, stream>>>(normx, idx_wk, kib, S_LEN, IDM, D_MODEL);
    gemm64<<<g64(IH, S_LEN), blk256, 0, stream>>>(normx, idx_ww, wib, S_LEN, IH, D_MODEL);
    // 7. RoPE on q,k
    rope_apply_kernel<<<S_LEN, dim3(512), 0, stream>>>(qkvb, ctab, stab);
    // 8. indexer scores
    scores_kernel<<<dim3(64, 64), blk256, 0, stream>>>(qib, kib, wib, scoresb);
    // 9. top-64 per row
    topk_kernel<<<S_LEN, blk256, 0, stream>>>(scoresb, topidx, topcnt);
    // 10. sparse attention -> bf16
    attn_kernel<<<S_LEN, blk256, 0, stream>>>(qkvb, topidx, topcnt, attno_bf);
    // 11. x1 = x + attn_out @ w_o  (bf16 MFMA, fused residual)
    gemm_bf16<<<g128(D_MODEL, S_LEN), blk256, 0, stream>>>(attno_bf, wo_t,
        outp, nullptr, nullptr, x, S_LEN, D_MODEL, D_MODEL, 0);
    // 12. h = LN2(x1) -> bf16 only
    ln_kernel<<<S_LEN, blk256, 0, stream>>>(outp, ln2_g, ln2_b, nullptr, h2_bf);
    // 13. ffn1 = gelu(h @ w1 + b1) -> bf16 only
    gemm_bf16<<<g128(DFF, S_LEN), blk256, 0, stream>>>(h2_bf, w1_t,
        nullptr, ffn1_bf, ffn_b1, nullptr, S_LEN, DFF, D_MODEL, 1);
    // 14. out = x1 + ffn1 @ w2 + b2  (bf16 MFMA, fused residual)
    gemm_bf16<<<g128(D_MODEL, S_LEN), blk256, 0, stream>>>(ffn1_bf, w2_t,
        outp, nullptr, ffn_b2, outp, S_LEN, D_MODEL, DFF, 0);
}

// Round 3
// 601.606 us; speedup vs baseline: 2.2479x; 1.3717x over previous
//
#include <hip/hip_runtime.h>
#include <math.h>

#define S_LEN 2048
#define D_MODEL 1024
#define NHEAD 16
#define HDIM 64
#define DFF 4096
#define IH 4
#define IDM 64
#define TOPK 64
#define NIDX 336   // 256 qi + 64 ki + 4 wi + 12 pad

typedef float f32x4 __attribute__((ext_vector_type(4)));
typedef short bf16x8 __attribute__((ext_vector_type(8)));

__device__ __forceinline__ unsigned short f2bf(float f) {
    unsigned u = __builtin_bit_cast(unsigned, f);
    u += 0x7fff + ((u >> 16) & 1);
    return (unsigned short)(u >> 16);
}
__device__ __forceinline__ float bf2f(unsigned short us) {
    return __builtin_bit_cast(float, (unsigned)us << 16);
}

__device__ __forceinline__ float gelu_exact(float v) {
    return 0.5f * v * (1.f + erff(v * 0.70710678118654752f));
}

__device__ __forceinline__ void gl_lds16(const void* g, void* l) {
    __builtin_amdgcn_global_load_lds(
        (const __attribute__((address_space(1))) void*)g,
        (__attribute__((address_space(3))) void*)l, 16, 0, 0);
}

// ---------------- LayerNorm: fp32 out (optional) + bf16 out (optional) ----------------
__global__ __launch_bounds__(256) void ln_kernel(const float* __restrict__ x,
    const float* __restrict__ g, const float* __restrict__ b,
    float* __restrict__ outf, unsigned short* __restrict__ outb)
{
    int row = blockIdx.x, tid = threadIdx.x;
    const float4 v = *(const float4*)(x + (size_t)row * D_MODEL + tid * 4);
    float s = v.x + v.y + v.z + v.w;
    float ss = v.x * v.x + v.y * v.y + v.z * v.z + v.w * v.w;
    int lane = tid & 63, wv = tid >> 6;
    for (int o = 32; o; o >>= 1) { s += __shfl_xor(s, o); ss += __shfl_xor(ss, o); }
    __shared__ float rs[4], rss[4];
    if (lane == 0) { rs[wv] = s; rss[wv] = ss; }
    __syncthreads();
    float S = rs[0] + rs[1] + rs[2] + rs[3];
    float SS = rss[0] + rss[1] + rss[2] + rss[3];
    float mean = S * (1.f / D_MODEL);
    float var = SS * (1.f / D_MODEL) - mean * mean;
    float r = rsqrtf(var + 1e-5f);
    float4 gv = *(const float4*)(g + tid * 4);
    float4 bv = *(const float4*)(b + tid * 4);
    float4 o4;
    o4.x = (v.x - mean) * r * gv.x + bv.x;
    o4.y = (v.y - mean) * r * gv.y + bv.y;
    o4.z = (v.z - mean) * r * gv.z + bv.z;
    o4.w = (v.w - mean) * r * gv.w + bv.w;
    if (outf) *(float4*)(outf + (size_t)row * D_MODEL + tid * 4) = o4;
    if (outb) {
        ushort4 u4 = { f2bf(o4.x), f2bf(o4.y), f2bf(o4.z), f2bf(o4.w) };
        *(ushort4*)(outb + (size_t)row * D_MODEL + tid * 4) = u4;
    }
}

// ---------------- Weight convert + transpose: fp32 [K][N] -> bf16 [N][K] ----------------
__global__ __launch_bounds__(256) void wtrans_kernel(const float* __restrict__ in,
    unsigned short* __restrict__ out, int K, int N)
{
    __shared__ float t[32][33];
    int k0 = blockIdx.y * 32, n0 = blockIdx.x * 32;
    int tid = threadIdx.x;
    int r = tid >> 5, c = tid & 31;
#pragma unroll
    for (int p = 0; p < 4; ++p)
        t[r + p * 8][c] = in[(size_t)(k0 + r + p * 8) * N + n0 + c];
    __syncthreads();
#pragma unroll
    for (int p = 0; p < 4; ++p)
        out[(size_t)(n0 + r + p * 8) * K + k0 + c] = f2bf(t[c][r + p * 8]);
}

// ---------------- Pack indexer weights into one fp32 [1024][336] ----------------
__global__ __launch_bounds__(256) void wpack_kernel(const float* __restrict__ wq,
    const float* __restrict__ wk, const float* __restrict__ ww, float* __restrict__ Wc)
{
    int idx = blockIdx.x * 256 + threadIdx.x;
    if (idx >= D_MODEL * NIDX) return;
    int r = idx / NIDX, c = idx % NIDX;
    float v = 0.f;
    if (c < 256) v = wq[r * 256 + c];
    else if (c < 320) v = wk[r * 64 + (c - 256)];
    else if (c < 324) v = ww[r * 4 + (c - 320)];
    Wc[idx] = v;
}

// ---------------- bf16 MFMA GEMM (m97 structure): C = act(A @ Bt^T + bias) + R ----------------
__global__ __launch_bounds__(256) void gemm_bf16(
    const unsigned short* __restrict__ A, const unsigned short* __restrict__ Bt,
    float* __restrict__ C, unsigned short* __restrict__ Cb,
    const float* __restrict__ bias, const float* __restrict__ R,
    int M, int N, int K, int act)
{
    __shared__ __attribute__((aligned(16))) unsigned short As[128 * 32];
    __shared__ __attribute__((aligned(16))) unsigned short Bs[128 * 32];
    int tid = threadIdx.x;
    int bm = blockIdx.y * 128, bn = blockIdx.x * 128;
    int wid = tid >> 6, lane = tid & 63;
    int wm = (wid >> 1) * 64, wn = (wid & 1) * 64;
    const unsigned short* Ab = A + (size_t)bm * K;
    const unsigned short* Bb = Bt + (size_t)bn * K;
    f32x4 acc[4][4];
#pragma unroll
    for (int i = 0; i < 4; ++i)
#pragma unroll
        for (int j = 0; j < 4; ++j)
            acc[i][j] = (f32x4){0.f, 0.f, 0.f, 0.f};

    int fr = lane & 15, fk = (lane >> 4) * 8;
    for (int k0 = 0; k0 < K; k0 += 32) {
#pragma unroll
        for (int i = 0; i < 2; ++i) {
            int e = (i * 256 + tid) * 8;
            int r = e >> 5, c = e & 31;
            gl_lds16(Ab + (size_t)r * K + k0 + c, As + e);
            gl_lds16(Bb + (size_t)r * K + k0 + c, Bs + e);
        }
        __syncthreads();
        bf16x8 af[4], bfv[4];
#pragma unroll
        for (int mi = 0; mi < 4; ++mi)
            af[mi] = *(const bf16x8*)&As[(wm + mi * 16 + fr) * 32 + fk];
#pragma unroll
        for (int ni = 0; ni < 4; ++ni)
            bfv[ni] = *(const bf16x8*)&Bs[(wn + ni * 16 + fr) * 32 + fk];
#pragma unroll
        for (int mi = 0; mi < 4; ++mi)
#pragma unroll
            for (int ni = 0; ni < 4; ++ni)
                acc[mi][ni] = __builtin_amdgcn_mfma_f32_16x16x32_bf16(
                    af[mi], bfv[ni], acc[mi][ni], 0, 0, 0);
        __syncthreads();
    }
    int cl = lane & 15, rh = (lane >> 4) * 4;
#pragma unroll
    for (int mi = 0; mi < 4; ++mi) {
#pragma unroll
        for (int ni = 0; ni < 4; ++ni) {
            int col = bn + wn + ni * 16 + cl;
            float bv = bias ? bias[col] : 0.f;
#pragma unroll
            for (int r = 0; r < 4; ++r) {
                int row = bm + wm + mi * 16 + rh + r;
                float v = acc[mi][ni][r] + bv;
                if (act) v = gelu_exact(v);
                size_t off = (size_t)row * N + col;
                if (R) v += R[off];
                if (C) C[off] = v;
                if (Cb) Cb[off] = f2bf(v);
            }
        }
    }
}

// ---------------- Generic fp32 GEMM (indexer path): C[M,N] = A[M,K]@B[K,N] ----------------
__global__ __launch_bounds__(256) void gemm64(const float* __restrict__ A,
    const float* __restrict__ B, float* __restrict__ C,
    int M, int N, int K)
{
    __shared__ float As[16][68];
    __shared__ float Bs[16][68];
    int tid = threadIdx.x;
    int bm = blockIdx.y, bn = blockIdx.x;
    int tx = tid & 15, ty = tid >> 4;
    int arow = tid >> 2;
    int acol = (tid & 3) << 2;
    int brow = tid >> 4;
    int bcol = (tid & 15) << 2;
    const float* Abase = A + (size_t)(bm * 64 + arow) * K + acol;
    float c[4][4] = {};
    for (int k0 = 0; k0 < K; k0 += 16) {
        float4 av = *(const float4*)(Abase + k0);
        As[acol + 0][arow] = av.x;
        As[acol + 1][arow] = av.y;
        As[acol + 2][arow] = av.z;
        As[acol + 3][arow] = av.w;
        int gcol = bn * 64 + bcol;
        const float* Bb = B + (size_t)(k0 + brow) * N;
        float4 bv;
        if (gcol + 3 < N) {
            bv = *(const float4*)(Bb + gcol);
        } else {
            bv.x = (gcol + 0 < N) ? Bb[gcol + 0] : 0.f;
            bv.y = (gcol + 1 < N) ? Bb[gcol + 1] : 0.f;
            bv.z = (gcol + 2 < N) ? Bb[gcol + 2] : 0.f;
            bv.w = (gcol + 3 < N) ? Bb[gcol + 3] : 0.f;
        }
        *(float4*)&Bs[brow][bcol] = bv;
        __syncthreads();
#pragma unroll
        for (int kk = 0; kk < 16; ++kk) {
            float4 a4 = *(const float4*)&As[kk][ty * 4];
            float4 b4 = *(const float4*)&Bs[kk][tx * 4];
            float av4[4] = { a4.x, a4.y, a4.z, a4.w };
            float bv4[4] = { b4.x, b4.y, b4.z, b4.w };
#pragma unroll
            for (int i = 0; i < 4; ++i)
#pragma unroll
                for (int j = 0; j < 4; ++j)
                    c[i][j] += av4[i] * bv4[j];
        }
        __syncthreads();
    }
#pragma unroll
    for (int i = 0; i < 4; ++i) {
        int row = bm * 64 + ty * 4 + i;
#pragma unroll
        for (int j = 0; j < 4; ++j) {
            int col = bn * 64 + tx * 4 + j;
            if (col < N)
                C[(size_t)row * N + col] = c[i][j];
        }
    }
}

// ---------------- RoPE table ----------------
__global__ __launch_bounds__(256) void rope_table_kernel(float* __restrict__ ct, float* __restrict__ st)
{
    int g = blockIdx.x * 256 + threadIdx.x;
    int t = g >> 5, i = g & 31;
    float theta = powf(10000.f, -(float)i / 32.f);
    float ang = (float)t * theta;
    ct[g] = cosf(ang);
    st[g] = sinf(ang);
}

// ---------------- RoPE + pack: qkv bf16 [S][3072] -> Qb [S][1024], Kb/Vb [H][S][64] ----------------
__global__ __launch_bounds__(512) void rope_pack_kernel(
    const unsigned short* __restrict__ qkvb,
    const float* __restrict__ ct, const float* __restrict__ st,
    unsigned short* __restrict__ Qb, unsigned short* __restrict__ Kb,
    unsigned short* __restrict__ Vb)
{
    int t = blockIdx.x, tid = threadIdx.x;
    int h = tid >> 5, i = tid & 31;
    float c = ct[t * 32 + i], s = st[t * 32 + i];
    const unsigned short* base = qkvb + (size_t)t * (3 * D_MODEL);
    // Q (rope, token-major)
    ushort2 q2 = *(const ushort2*)(base + h * HDIM + 2 * i);
    float q0 = bf2f(q2.x), q1 = bf2f(q2.y);
    ushort2 qo = { f2bf(q0 * c - q1 * s), f2bf(q1 * c + q0 * s) };
    *(ushort2*)(Qb + (size_t)t * D_MODEL + h * HDIM + 2 * i) = qo;
    // K (rope, head-major)
    ushort2 k2 = *(const ushort2*)(base + D_MODEL + h * HDIM + 2 * i);
    float k0 = bf2f(k2.x), k1 = bf2f(k2.y);
    ushort2 ko = { f2bf(k0 * c - k1 * s), f2bf(k1 * c + k0 * s) };
    *(ushort2*)(Kb + ((size_t)h * S_LEN + t) * HDIM + 2 * i) = ko;
    // V (copy, head-major)
    ushort2 v2 = *(const ushort2*)(base + 2 * D_MODEL + 2 * tid);
    int vh = tid >> 5, vd = (2 * tid) & 63;
    *(ushort2*)(Vb + ((size_t)vh * S_LEN + t) * HDIM + vd) = v2;
}

// ---------------- Indexer scores (fp32, fused QIW layout, stride 336) ----------------
__global__ __launch_bounds__(256) void scores_kernel(const float* __restrict__ QIW,
    float* __restrict__ scores)
{
    int t0 = blockIdx.y * 32, s0 = blockIdx.x * 32;
    if (s0 > t0 + 31) return;
    __shared__ float qis[32][256];
    __shared__ float kis[32][65];
    __shared__ float wis[32][4];
    int tid = threadIdx.x;
#pragma unroll
    for (int l = 0; l < 8; ++l) {
        int idx = l * 256 + tid;
        int r = idx >> 6, c = (idx & 63) << 2;
        *(float4*)&qis[r][c] = *(const float4*)(QIW + (size_t)(t0 + r) * NIDX + c);
    }
#pragma unroll
    for (int l = 0; l < 8; ++l) {
        int idx = l * 256 + tid;
        int r = idx >> 6, c = idx & 63;
        kis[r][c] = QIW[(size_t)(s0 + r) * NIDX + 256 + c];
    }
    if (tid < 32) *(float4*)&wis[tid][0] = *(const float4*)(QIW + (size_t)(t0 + tid) * NIDX + 320);
    __syncthreads();
    int sl = tid & 31;
    int tb = (tid >> 5) * 4;
    float acc[4] = { 0.f, 0.f, 0.f, 0.f };
#pragma unroll
    for (int h = 0; h < 4; ++h) {
        float dots[4] = { 0.f, 0.f, 0.f, 0.f };
        for (int d = 0; d < 64; ++d) {
            float kv = kis[sl][d];
#pragma unroll
            for (int i = 0; i < 4; ++i)
                dots[i] += qis[tb + i][h * 64 + d] * kv;
        }
#pragma unroll
        for (int i = 0; i < 4; ++i)
            acc[i] += wis[tb + i][h] * fmaxf(dots[i], 0.f);
    }
#pragma unroll
    for (int i = 0; i < 4; ++i)
        scores[(size_t)(t0 + tb + i) * S_LEN + s0 + sl] = acc[i];
}

// ---------------- Top-K (iterative max-extract, ties -> lowest index) ----------------
__global__ __launch_bounds__(256) void topk_kernel(const float* __restrict__ scores,
    int* __restrict__ topidx, int* __restrict__ topcnt)
{
    int t = blockIdx.x, tid = threadIdx.x;
    __shared__ float sc[S_LEN];
    __shared__ float wmax[4];
    __shared__ int widx[4];
    int n = t + 1;
    for (int j = tid; j < n; j += 256) sc[j] = scores[(size_t)t * S_LEN + j];
    __syncthreads();
    int kmax = n < TOPK ? n : TOPK;
    int lane = tid & 63, wv = tid >> 6;
    for (int it = 0; it < kmax; ++it) {
        float best = -INFINITY;
        int bidx = 0x7fffffff;
        for (int j = tid; j < n; j += 256) {
            float v = sc[j];
            if (v > best || (v == best && j < bidx)) { best = v; bidx = j; }
        }
        for (int o = 32; o; o >>= 1) {
            float ov = __shfl_xor(best, o);
            int oi = __shfl_xor(bidx, o);
            if (ov > best || (ov == best && oi < bidx)) { best = ov; bidx = oi; }
        }
        if (lane == 0) { wmax[wv] = best; widx[wv] = bidx; }
        __syncthreads();
        if (tid == 0) {
            float bb = wmax[0]; int bi = widx[0];
#pragma unroll
            for (int w = 1; w < 4; ++w)
                if (wmax[w] > bb || (wmax[w] == bb && widx[w] < bi)) { bb = wmax[w]; bi = widx[w]; }
            topidx[t * TOPK + it] = bi;
            sc[bi] = -INFINITY;
        }
        __syncthreads();
    }
    if (tid == 0) topcnt[t] = kmax;
}

// ---------------- Sparse SDPA v2: bf16 head-major gather, LDS p ----------------
__global__ __launch_bounds__(256) void attn_kernel(
    const unsigned short* __restrict__ Qb, const unsigned short* __restrict__ Kb,
    const unsigned short* __restrict__ Vb,
    const int* __restrict__ topidx, const int* __restrict__ topcnt,
    unsigned short* __restrict__ out)
{
    int t = blockIdx.x, tid = threadIdx.x;
    __shared__ unsigned short qls[D_MODEL];
    __shared__ int sel[TOPK];
    __shared__ float pl[NHEAD][TOPK];
    *(ushort4*)(qls + tid * 4) = *(const ushort4*)(Qb + (size_t)t * D_MODEL + tid * 4);
    if (tid < TOPK) sel[tid] = topidx[t * TOPK + tid];
    __syncthreads();
    int cnt = topcnt[t];
    int lane = tid & 63, wv = tid >> 6;
    int s_l = sel[(lane < cnt) ? lane : 0];
#pragma unroll
    for (int hh = 0; hh < 4; ++hh) {
        int h = wv * 4 + hh;
        const unsigned short* kp = Kb + ((size_t)h * S_LEN + s_l) * HDIM;
        float dot = 0.f;
#pragma unroll
        for (int j = 0; j < 8; ++j) {
            bf16x8 kf = *(const bf16x8*)(kp + j * 8);
            bf16x8 qf = *(const bf16x8*)(qls + h * HDIM + j * 8);
#pragma unroll
            for (int e = 0; e < 8; ++e)
                dot += bf2f((unsigned short)kf[e]) * bf2f((unsigned short)qf[e]);
        }
        float logit = (lane < cnt) ? dot * 0.125f : -INFINITY;
        float m = logit;
        for (int o = 32; o; o >>= 1) m = fmaxf(m, __shfl_xor(m, o));
        float p = (lane < cnt) ? __expf(logit - m) : 0.f;
        float sum = p;
        for (int o = 32; o; o >>= 1) sum += __shfl_xor(sum, o);
        pl[h][lane] = p / sum;
    }
    // each wave reads only its own heads' pl -> no barrier needed
#pragma unroll
    for (int hh = 0; hh < 4; ++hh) {
        int h = wv * 4 + hh;
        const unsigned short* vp = Vb + (size_t)h * S_LEN * HDIM + lane;
        float acc = 0.f;
        if (cnt == TOPK) {
#pragma unroll 8
            for (int si = 0; si < TOPK; ++si)
                acc += pl[h][si] * bf2f(vp[(size_t)sel[si] * HDIM]);
        } else {
            for (int si = 0; si < cnt; ++si)
                acc += pl[h][si] * bf2f(vp[(size_t)sel[si] * HDIM]);
        }
        out[(size_t)t * D_MODEL + h * HDIM + lane] = f2bf(acc);
    }
}

extern "C" void kernel_launch(void* const* d_in, const int* in_sizes, int n_in,
                              void* d_out, int out_size, void* d_ws, size_t ws_size,
                              hipStream_t stream)
{
    const float* x      = (const float*)d_in[0];
    const float* w_qkv  = (const float*)d_in[1];
    const float* w_o    = (const float*)d_in[2];
    const float* ffn_w1 = (const float*)d_in[3];
    const float* ffn_b1 = (const float*)d_in[4];
    const float* ffn_w2 = (const float*)d_in[5];
    const float* ffn_b2 = (const float*)d_in[6];
    const float* ln1_g  = (const float*)d_in[7];
    const float* ln1_b  = (const float*)d_in[8];
    const float* ln2_g  = (const float*)d_in[9];
    const float* ln2_b  = (const float*)d_in[10];
    const float* idx_wq = (const float*)d_in[11];
    const float* idx_wk = (const float*)d_in[12];
    const float* idx_ww = (const float*)d_in[13];
    float* outp = (float*)d_out;

    const size_t MB = 1ull << 20;
    char* ws = (char*)d_ws;
    // [0,8)    normx fp32 (dead after indexer gemm) -> attno_bf (4MB)
    // [8,12)   normx_bf / h2_bf
    // [12,24)  qkv_bf [2048][3072] (dead after rope_pack) -> topidx/topcnt overlay
    // [24,30)  wqkv_t   [30,32) wo_t   [32,40) w1_t   [40,48) w2_t
    // [48,52)  Qb   [52,56) Kb   [56,60) Vb
    // [60,76)  ctab/stab (dead after rope_pack) -> scoresb -> ffn1_bf
    // [76,79)  QIW [2048][336] fp32
    // [79,80.5) Wc [1024][336] fp32
    float*          normx    = (float*)(ws + 0);
    unsigned short* attno_bf = (unsigned short*)(ws + 0);
    unsigned short* normx_bf = (unsigned short*)(ws + 8 * MB);
    unsigned short* h2_bf    = normx_bf;
    unsigned short* qkv_bf   = (unsigned short*)(ws + 12 * MB);
    int*            topidx   = (int*)(ws + 12 * MB);
    int*            topcnt   = (int*)(ws + 12 * MB + 512 * 1024);
    unsigned short* wqkv_t   = (unsigned short*)(ws + 24 * MB);
    unsigned short* wo_t     = (unsigned short*)(ws + 30 * MB);
    unsigned short* w1_t     = (unsigned short*)(ws + 32 * MB);
    unsigned short* w2_t     = (unsigned short*)(ws + 40 * MB);
    unsigned short* Qb       = (unsigned short*)(ws + 48 * MB);
    unsigned short* Kb       = (unsigned short*)(ws + 52 * MB);
    unsigned short* Vb       = (unsigned short*)(ws + 56 * MB);
    float*          ctab     = (float*)(ws + 60 * MB);
    float*          stab     = (float*)(ws + 60 * MB + 256 * 1024);
    float*          scoresb  = (float*)(ws + 60 * MB);
    unsigned short* ffn1_bf  = (unsigned short*)(ws + 60 * MB);
    float*          QIW      = (float*)(ws + 76 * MB);
    float*          Wc       = (float*)(ws + 79 * MB);

    dim3 blk256(256);
    auto g128 = [](int N, int M) { return dim3(N / 128, M / 128); };

    // 1. LN1 -> fp32 (indexer) + bf16 (qkv gemm)
    ln_kernel<<<S_LEN, blk256, 0, stream>>>(x, ln1_g, ln1_b, normx, normx_bf);
    // 2. rope tables + weight prep
    rope_table_kernel<<<(S_LEN * 32) / 256, blk256, 0, stream>>>(ctab, stab);
    wtrans_kernel<<<dim3(3 * D_MODEL / 32, D_MODEL / 32), blk256, 0, stream>>>(w_qkv, wqkv_t, D_MODEL, 3 * D_MODEL);
    wtrans_kernel<<<dim3(D_MODEL / 32, D_MODEL / 32), blk256, 0, stream>>>(w_o, wo_t, D_MODEL, D_MODEL);
    wtrans_kernel<<<dim3(DFF / 32, D_MODEL / 32), blk256, 0, stream>>>(ffn_w1, w1_t, D_MODEL, DFF);
    wtrans_kernel<<<dim3(D_MODEL / 32, DFF / 32), blk256, 0, stream>>>(ffn_w2, w2_t, DFF, D_MODEL);
    wpack_kernel<<<(D_MODEL * NIDX + 255) / 256, blk256, 0, stream>>>(idx_wq, idx_wk, idx_ww, Wc);
    // 3. qkv = norm_x @ w_qkv (bf16 out only)
    gemm_bf16<<<g128(3 * D_MODEL, S_LEN), blk256, 0, stream>>>(normx_bf, wqkv_t,
        nullptr, qkv_bf, nullptr, nullptr, S_LEN, 3 * D_MODEL, D_MODEL, 0);
    // 4. fused indexer projections (fp32 — feeds discrete top-k)
    gemm64<<<dim3((NIDX + 63) / 64, S_LEN / 64), blk256, 0, stream>>>(normx, Wc, QIW, S_LEN, NIDX, D_MODEL);
    // 5. RoPE + pack Q/K/V (bf16, K/V head-major)
    rope_pack_kernel<<<S_LEN, dim3(512), 0, stream>>>(qkv_bf, ctab, stab, Qb, Kb, Vb);
    // 6. indexer scores (overwrites ctab region — rope_pack already done)
    scores_kernel<<<dim3(64, 64), blk256, 0, stream>>>(QIW, scoresb);
    // 7. top-64 per row (topidx overlays dead qkv_bf)
    topk_kernel<<<S_LEN, blk256, 0, stream>>>(scoresb, topidx, topcnt);
    // 8. sparse attention -> bf16 (overlays dead normx)
    attn_kernel<<<S_LEN, blk256, 0, stream>>>(Qb, Kb, Vb, topidx, topcnt, attno_bf);
    // 9. x1 = x + attn_out @ w_o
    gemm_bf16<<<g128(D_MODEL, S_LEN), blk256, 0, stream>>>(attno_bf, wo_t,
        outp, nullptr, nullptr, x, S_LEN, D_MODEL, D_MODEL, 0);
    // 10. h = LN2(x1) -> bf16
    ln_kernel<<<S_LEN, blk256, 0, stream>>>(outp, ln2_g, ln2_b, nullptr, h2_bf);
    // 11. ffn1 = gelu(h @ w1 + b1) -> bf16 (overlays dead scoresb)
    gemm_bf16<<<g128(DFF, S_LEN), blk256, 0, stream>>>(h2_bf, w1_t,
        nullptr, ffn1_bf, ffn_b1, nullptr, S_LEN, DFF, D_MODEL, 1);
    // 12. out = x1 + ffn1 @ w2 + b2
    gemm_bf16<<<g128(D_MODEL, S_LEN), blk256, 0, stream>>>(ffn1_bf, w2_t,
        outp, nullptr, ffn_b2, outp, S_LEN, D_MODEL, DFF, 0);
}

// Round 4
// 463.187 us; speedup vs baseline: 2.9197x; 1.2988x over previous
//
#include <hip/hip_runtime.h>
#include <math.h>

#define S_LEN 2048
#define D_MODEL 1024
#define NHEAD 16
#define HDIM 64
#define DFF 4096
#define IH 4
#define IDM 64
#define TOPK 64
#define NIDX 336   // 256 qi + 64 ki + 4 wi + 12 pad

typedef float f32x4 __attribute__((ext_vector_type(4)));
typedef short bf16x8 __attribute__((ext_vector_type(8)));

__device__ __forceinline__ unsigned short f2bf(float f) {
    unsigned u = __builtin_bit_cast(unsigned, f);
    u += 0x7fff + ((u >> 16) & 1);
    return (unsigned short)(u >> 16);
}
__device__ __forceinline__ float bf2f(unsigned short us) {
    return __builtin_bit_cast(float, (unsigned)us << 16);
}

__device__ __forceinline__ float gelu_exact(float v) {
    return 0.5f * v * (1.f + erff(v * 0.70710678118654752f));
}

__device__ __forceinline__ void gl_lds16(const void* g, void* l) {
    __builtin_amdgcn_global_load_lds(
        (const __attribute__((address_space(1))) void*)g,
        (__attribute__((address_space(3))) void*)l, 16, 0, 0);
}

// ---------------- LayerNorm: fp32 out (optional) + bf16 out (optional) ----------------
__global__ __launch_bounds__(256) void ln_kernel(const float* __restrict__ x,
    const float* __restrict__ g, const float* __restrict__ b,
    float* __restrict__ outf, unsigned short* __restrict__ outb)
{
    int row = blockIdx.x, tid = threadIdx.x;
    const float4 v = *(const float4*)(x + (size_t)row * D_MODEL + tid * 4);
    float s = v.x + v.y + v.z + v.w;
    float ss = v.x * v.x + v.y * v.y + v.z * v.z + v.w * v.w;
    int lane = tid & 63, wv = tid >> 6;
    for (int o = 32; o; o >>= 1) { s += __shfl_xor(s, o); ss += __shfl_xor(ss, o); }
    __shared__ float rs[4], rss[4];
    if (lane == 0) { rs[wv] = s; rss[wv] = ss; }
    __syncthreads();
    float S = rs[0] + rs[1] + rs[2] + rs[3];
    float SS = rss[0] + rss[1] + rss[2] + rss[3];
    float mean = S * (1.f / D_MODEL);
    float var = SS * (1.f / D_MODEL) - mean * mean;
    float r = rsqrtf(var + 1e-5f);
    float4 gv = *(const float4*)(g + tid * 4);
    float4 bv = *(const float4*)(b + tid * 4);
    float4 o4;
    o4.x = (v.x - mean) * r * gv.x + bv.x;
    o4.y = (v.y - mean) * r * gv.y + bv.y;
    o4.z = (v.z - mean) * r * gv.z + bv.z;
    o4.w = (v.w - mean) * r * gv.w + bv.w;
    if (outf) *(float4*)(outf + (size_t)row * D_MODEL + tid * 4) = o4;
    if (outb) {
        ushort4 u4 = { f2bf(o4.x), f2bf(o4.y), f2bf(o4.z), f2bf(o4.w) };
        *(ushort4*)(outb + (size_t)row * D_MODEL + tid * 4) = u4;
    }
}

// ---------------- Weight convert + transpose: fp32 [K][N] -> bf16 [N][K] ----------------
__global__ __launch_bounds__(256) void wtrans_kernel(const float* __restrict__ in,
    unsigned short* __restrict__ out, int K, int N)
{
    __shared__ float t[32][33];
    int k0 = blockIdx.y * 32, n0 = blockIdx.x * 32;
    int tid = threadIdx.x;
    int r = tid >> 5, c = tid & 31;
#pragma unroll
    for (int p = 0; p < 4; ++p)
        t[r + p * 8][c] = in[(size_t)(k0 + r + p * 8) * N + n0 + c];
    __syncthreads();
#pragma unroll
    for (int p = 0; p < 4; ++p)
        out[(size_t)(n0 + r + p * 8) * K + k0 + c] = f2bf(t[c][r + p * 8]);
}

// ---------------- Pack indexer weights into one fp32 [1024][336] ----------------
__global__ __launch_bounds__(256) void wpack_kernel(const float* __restrict__ wq,
    const float* __restrict__ wk, const float* __restrict__ ww, float* __restrict__ Wc)
{
    int idx = blockIdx.x * 256 + threadIdx.x;
    if (idx >= D_MODEL * NIDX) return;
    int r = idx / NIDX, c = idx % NIDX;
    float v = 0.f;
    if (c < 256) v = wq[r * 256 + c];
    else if (c < 320) v = wk[r * 64 + (c - 256)];
    else if (c < 324) v = ww[r * 4 + (c - 320)];
    Wc[idx] = v;
}

// ---------------- bf16 MFMA GEMM (m97 structure): C = act(A @ Bt^T + bias) + R ----------------
__global__ __launch_bounds__(256) void gemm_bf16(
    const unsigned short* __restrict__ A, const unsigned short* __restrict__ Bt,
    float* __restrict__ C, unsigned short* __restrict__ Cb,
    const float* __restrict__ bias, const float* __restrict__ R,
    int M, int N, int K, int act)
{
    __shared__ __attribute__((aligned(16))) unsigned short As[128 * 32];
    __shared__ __attribute__((aligned(16))) unsigned short Bs[128 * 32];
    int tid = threadIdx.x;
    int bm = blockIdx.y * 128, bn = blockIdx.x * 128;
    int wid = tid >> 6, lane = tid & 63;
    int wm = (wid >> 1) * 64, wn = (wid & 1) * 64;
    const unsigned short* Ab = A + (size_t)bm * K;
    const unsigned short* Bb = Bt + (size_t)bn * K;
    f32x4 acc[4][4];
#pragma unroll
    for (int i = 0; i < 4; ++i)
#pragma unroll
        for (int j = 0; j < 4; ++j)
            acc[i][j] = (f32x4){0.f, 0.f, 0.f, 0.f};

    int fr = lane & 15, fk = (lane >> 4) * 8;
    for (int k0 = 0; k0 < K; k0 += 32) {
#pragma unroll
        for (int i = 0; i < 2; ++i) {
            int e = (i * 256 + tid) * 8;
            int r = e >> 5, c = e & 31;
            gl_lds16(Ab + (size_t)r * K + k0 + c, As + e);
            gl_lds16(Bb + (size_t)r * K + k0 + c, Bs + e);
        }
        __syncthreads();
        bf16x8 af[4], bfv[4];
#pragma unroll
        for (int mi = 0; mi < 4; ++mi)
            af[mi] = *(const bf16x8*)&As[(wm + mi * 16 + fr) * 32 + fk];
#pragma unroll
        for (int ni = 0; ni < 4; ++ni)
            bfv[ni] = *(const bf16x8*)&Bs[(wn + ni * 16 + fr) * 32 + fk];
#pragma unroll
        for (int mi = 0; mi < 4; ++mi)
#pragma unroll
            for (int ni = 0; ni < 4; ++ni)
                acc[mi][ni] = __builtin_amdgcn_mfma_f32_16x16x32_bf16(
                    af[mi], bfv[ni], acc[mi][ni], 0, 0, 0);
        __syncthreads();
    }
    int cl = lane & 15, rh = (lane >> 4) * 4;
#pragma unroll
    for (int mi = 0; mi < 4; ++mi) {
#pragma unroll
        for (int ni = 0; ni < 4; ++ni) {
            int col = bn + wn + ni * 16 + cl;
            float bv = bias ? bias[col] : 0.f;
#pragma unroll
            for (int r = 0; r < 4; ++r) {
                int row = bm + wm + mi * 16 + rh + r;
                float v = acc[mi][ni][r] + bv;
                if (act) v = gelu_exact(v);
                size_t off = (size_t)row * N + col;
                if (R) v += R[off];
                if (C) C[off] = v;
                if (Cb) Cb[off] = f2bf(v);
            }
        }
    }
}

// ---------------- Generic fp32 GEMM (indexer path): C[M,N] = A[M,K]@B[K,N] ----------------
__global__ __launch_bounds__(256) void gemm64(const float* __restrict__ A,
    const float* __restrict__ B, float* __restrict__ C,
    int M, int N, int K)
{
    __shared__ float As[16][68];
    __shared__ float Bs[16][68];
    int tid = threadIdx.x;
    int bm = blockIdx.y, bn = blockIdx.x;
    int tx = tid & 15, ty = tid >> 4;
    int arow = tid >> 2;
    int acol = (tid & 3) << 2;
    int brow = tid >> 4;
    int bcol = (tid & 15) << 2;
    const float* Abase = A + (size_t)(bm * 64 + arow) * K + acol;
    float c[4][4] = {};
    for (int k0 = 0; k0 < K; k0 += 16) {
        float4 av = *(const float4*)(Abase + k0);
        As[acol + 0][arow] = av.x;
        As[acol + 1][arow] = av.y;
        As[acol + 2][arow] = av.z;
        As[acol + 3][arow] = av.w;
        int gcol = bn * 64 + bcol;
        const float* Bb = B + (size_t)(k0 + brow) * N;
        float4 bv;
        if (gcol + 3 < N) {
            bv = *(const float4*)(Bb + gcol);
        } else {
            bv.x = (gcol + 0 < N) ? Bb[gcol + 0] : 0.f;
            bv.y = (gcol + 1 < N) ? Bb[gcol + 1] : 0.f;
            bv.z = (gcol + 2 < N) ? Bb[gcol + 2] : 0.f;
            bv.w = (gcol + 3 < N) ? Bb[gcol + 3] : 0.f;
        }
        *(float4*)&Bs[brow][bcol] = bv;
        __syncthreads();
#pragma unroll
        for (int kk = 0; kk < 16; ++kk) {
            float4 a4 = *(const float4*)&As[kk][ty * 4];
            float4 b4 = *(const float4*)&Bs[kk][tx * 4];
            float av4[4] = { a4.x, a4.y, a4.z, a4.w };
            float bv4[4] = { b4.x, b4.y, b4.z, b4.w };
#pragma unroll
            for (int i = 0; i < 4; ++i)
#pragma unroll
                for (int j = 0; j < 4; ++j)
                    c[i][j] += av4[i] * bv4[j];
        }
        __syncthreads();
    }
#pragma unroll
    for (int i = 0; i < 4; ++i) {
        int row = bm * 64 + ty * 4 + i;
#pragma unroll
        for (int j = 0; j < 4; ++j) {
            int col = bn * 64 + tx * 4 + j;
            if (col < N)
                C[(size_t)row * N + col] = c[i][j];
        }
    }
}

// ---------------- RoPE table ----------------
__global__ __launch_bounds__(256) void rope_table_kernel(float* __restrict__ ct, float* __restrict__ st)
{
    int g = blockIdx.x * 256 + threadIdx.x;
    int t = g >> 5, i = g & 31;
    float theta = powf(10000.f, -(float)i / 32.f);
    float ang = (float)t * theta;
    ct[g] = cosf(ang);
    st[g] = sinf(ang);
}

// ---------------- RoPE + pack: qkv bf16 [S][3072] -> Qb [S][1024], Kb/Vb [H][S][64] ----------------
__global__ __launch_bounds__(512) void rope_pack_kernel(
    const unsigned short* __restrict__ qkvb,
    const float* __restrict__ ct, const float* __restrict__ st,
    unsigned short* __restrict__ Qb, unsigned short* __restrict__ Kb,
    unsigned short* __restrict__ Vb)
{
    int t = blockIdx.x, tid = threadIdx.x;
    int h = tid >> 5, i = tid & 31;
    float c = ct[t * 32 + i], s = st[t * 32 + i];
    const unsigned short* base = qkvb + (size_t)t * (3 * D_MODEL);
    ushort2 q2 = *(const ushort2*)(base + h * HDIM + 2 * i);
    float q0 = bf2f(q2.x), q1 = bf2f(q2.y);
    ushort2 qo = { f2bf(q0 * c - q1 * s), f2bf(q1 * c + q0 * s) };
    *(ushort2*)(Qb + (size_t)t * D_MODEL + h * HDIM + 2 * i) = qo;
    ushort2 k2 = *(const ushort2*)(base + D_MODEL + h * HDIM + 2 * i);
    float k0 = bf2f(k2.x), k1 = bf2f(k2.y);
    ushort2 ko = { f2bf(k0 * c - k1 * s), f2bf(k1 * c + k0 * s) };
    *(ushort2*)(Kb + ((size_t)h * S_LEN + t) * HDIM + 2 * i) = ko;
    ushort2 v2 = *(const ushort2*)(base + 2 * D_MODEL + 2 * tid);
    int vh = tid >> 5, vd = (2 * tid) & 63;
    *(ushort2*)(Vb + ((size_t)vh * S_LEN + t) * HDIM + vd) = v2;
}

// ---------------- Indexer scores (fp32, fused QIW layout, stride 336) ----------------
__global__ __launch_bounds__(256) void scores_kernel(const float* __restrict__ QIW,
    float* __restrict__ scores)
{
    int t0 = blockIdx.y * 32, s0 = blockIdx.x * 32;
    if (s0 > t0 + 31) return;
    __shared__ float qis[32][256];
    __shared__ float kis[32][65];
    __shared__ float wis[32][4];
    int tid = threadIdx.x;
#pragma unroll
    for (int l = 0; l < 8; ++l) {
        int idx = l * 256 + tid;
        int r = idx >> 6, c = (idx & 63) << 2;
        *(float4*)&qis[r][c] = *(const float4*)(QIW + (size_t)(t0 + r) * NIDX + c);
    }
#pragma unroll
    for (int l = 0; l < 8; ++l) {
        int idx = l * 256 + tid;
        int r = idx >> 6, c = idx & 63;
        kis[r][c] = QIW[(size_t)(s0 + r) * NIDX + 256 + c];
    }
    if (tid < 32) *(float4*)&wis[tid][0] = *(const float4*)(QIW + (size_t)(t0 + tid) * NIDX + 320);
    __syncthreads();
    int sl = tid & 31;
    int tb = (tid >> 5) * 4;
    float acc[4] = { 0.f, 0.f, 0.f, 0.f };
#pragma unroll
    for (int h = 0; h < 4; ++h) {
        float dots[4] = { 0.f, 0.f, 0.f, 0.f };
        for (int d = 0; d < 64; ++d) {
            float kv = kis[sl][d];
#pragma unroll
            for (int i = 0; i < 4; ++i)
                dots[i] += qis[tb + i][h * 64 + d] * kv;
        }
#pragma unroll
        for (int i = 0; i < 4; ++i)
            acc[i] += wis[tb + i][h] * fmaxf(dots[i], 0.f);
    }
#pragma unroll
    for (int i = 0; i < 4; ++i)
        scores[(size_t)(t0 + tb + i) * S_LEN + s0 + sl] = acc[i];
}

// ---------------- Top-K via radix select (exact lax.top_k set semantics) ----------------
// Monotonic map: ord(f) = sign(f) ? ~bits : bits|0x80000000 (f1>f2 <=> ord1>ord2).
// 4 rounds x 8-bit histogram pin the 64th-largest value T; then append all >T and
// the kk lowest-index ties ==T. Output set is order-free (consumer builds a mask).
__global__ __launch_bounds__(256) void topk_kernel(const float* __restrict__ scores,
    int* __restrict__ topidx, int* __restrict__ topcnt)
{
    int t = blockIdx.x, tid = threadIdx.x;
    int n = t + 1;
    if (n <= TOPK) {
        if (tid < n) topidx[t * TOPK + tid] = tid;
        if (tid == 0) topcnt[t] = n;
        return;
    }
    __shared__ unsigned sc[S_LEN];
    __shared__ unsigned hist[256];
    __shared__ int selbin_s;
    __shared__ int cnt_out;
    __shared__ unsigned wsum[4];
    for (int j = tid; j < n; j += 256) {
        unsigned u = __builtin_bit_cast(unsigned, scores[(size_t)t * S_LEN + j]);
        sc[j] = (u & 0x80000000u) ? ~u : (u | 0x80000000u);
    }
    if (tid == 0) cnt_out = 0;
    int lane = tid & 63, wv = tid >> 6;
    unsigned prefix = 0;
    int kk = TOPK;
#pragma unroll
    for (int round = 0; round < 4; ++round) {
        int shift_pref = 32 - 8 * round;
        int shift_bin = 24 - 8 * round;
        hist[tid] = 0;
        __syncthreads();   // also covers sc[] ready on round 0
        for (int j = tid; j < n; j += 256) {
            unsigned v = sc[j];
            if ((((unsigned long long)(v ^ prefix)) >> shift_pref) == 0)
                atomicAdd(&hist[(v >> shift_bin) & 0xff], 1u);
        }
        __syncthreads();
        // suffix-sum hist (inclusive from top) using wave 0 only
        if (wv == 0) {
            unsigned h0 = hist[4 * lane], h1 = hist[4 * lane + 1];
            unsigned h2 = hist[4 * lane + 2], h3 = hist[4 * lane + 3];
            unsigned s3 = h3, s2 = h2 + s3, s1 = h1 + s2, s0 = h0 + s1;
            unsigned acc = s0;
            for (int off = 1; off < 64; off <<= 1) {
                unsigned o = __shfl_down(acc, off);
                if (lane + off < 64) acc += o;
            }
            unsigned above = acc - s0;
            hist[4 * lane]     = s0 + above;
            hist[4 * lane + 1] = s1 + above;
            hist[4 * lane + 2] = s2 + above;
            hist[4 * lane + 3] = s3 + above;
        }
        __syncthreads();
        {
            unsigned sufb = hist[tid];
            unsigned sufn = (tid < 255) ? hist[tid + 1] : 0u;
            if (sufb >= (unsigned)kk && sufn < (unsigned)kk)
                selbin_s = tid;   // exactly one thread matches
        }
        __syncthreads();
        int b = selbin_s;
        unsigned above = (b < 255) ? hist[b + 1] : 0u;
        kk -= (int)above;
        prefix |= ((unsigned)b) << shift_bin;
        __syncthreads();   // protect hist reads from next round's zeroing
    }
    unsigned T = prefix;   // exact ordered-bits of the 64th largest value
    // selection: contiguous chunks so tie ranks follow index order
    int chunk = (n + 255) >> 8;
    int jb = tid * chunk;
    int je = jb + chunk; if (je > n) je = n;
    int ties = 0;
    for (int j = jb; j < je; ++j) {
        unsigned v = sc[j];
        if (v > T) { int o = atomicAdd(&cnt_out, 1); topidx[t * TOPK + o] = j; }
        else if (v == T) ++ties;
    }
    // exclusive prefix of tie counts across 256 threads
    unsigned inc = (unsigned)ties;
    for (int off = 1; off < 64; off <<= 1) {
        unsigned o = __shfl_up(inc, off);
        if (lane >= off) inc += o;
    }
    if (lane == 63) wsum[wv] = inc;
    __syncthreads();
    unsigned woff = 0;
    for (int w = 0; w < wv; ++w) woff += wsum[w];
    int rank = (int)(woff + inc) - ties;   // this thread's first tie's global rank
    for (int j = jb; j < je && rank < kk; ++j) {
        if (sc[j] == T) {
            int o = atomicAdd(&cnt_out, 1);
            topidx[t * TOPK + o] = j;
            ++rank;
        }
    }
    if (tid == 0) topcnt[t] = TOPK;
}

// ---------------- Sparse SDPA v2: bf16 head-major gather, LDS p ----------------
__global__ __launch_bounds__(256) void attn_kernel(
    const unsigned short* __restrict__ Qb, const unsigned short* __restrict__ Kb,
    const unsigned short* __restrict__ Vb,
    const int* __restrict__ topidx, const int* __restrict__ topcnt,
    unsigned short* __restrict__ out)
{
    int t = blockIdx.x, tid = threadIdx.x;
    __shared__ unsigned short qls[D_MODEL];
    __shared__ int sel[TOPK];
    __shared__ float pl[NHEAD][TOPK];
    *(ushort4*)(qls + tid * 4) = *(const ushort4*)(Qb + (size_t)t * D_MODEL + tid * 4);
    if (tid < TOPK) sel[tid] = topidx[t * TOPK + tid];
    __syncthreads();
    int cnt = topcnt[t];
    int lane = tid & 63, wv = tid >> 6;
    int s_l = sel[(lane < cnt) ? lane : 0];
#pragma unroll
    for (int hh = 0; hh < 4; ++hh) {
        int h = wv * 4 + hh;
        const unsigned short* kp = Kb + ((size_t)h * S_LEN + s_l) * HDIM;
        float dot = 0.f;
#pragma unroll
        for (int j = 0; j < 8; ++j) {
            bf16x8 kf = *(const bf16x8*)(kp + j * 8);
            bf16x8 qf = *(const bf16x8*)(qls + h * HDIM + j * 8);
#pragma unroll
            for (int e = 0; e < 8; ++e)
                dot += bf2f((unsigned short)kf[e]) * bf2f((unsigned short)qf[e]);
        }
        float logit = (lane < cnt) ? dot * 0.125f : -INFINITY;
        float m = logit;
        for (int o = 32; o; o >>= 1) m = fmaxf(m, __shfl_xor(m, o));
        float p = (lane < cnt) ? __expf(logit - m) : 0.f;
        float sum = p;
        for (int o = 32; o; o >>= 1) sum += __shfl_xor(sum, o);
        pl[h][lane] = p / sum;
    }
#pragma unroll
    for (int hh = 0; hh < 4; ++hh) {
        int h = wv * 4 + hh;
        const unsigned short* vp = Vb + (size_t)h * S_LEN * HDIM + lane;
        float acc = 0.f;
        if (cnt == TOPK) {
#pragma unroll 8
            for (int si = 0; si < TOPK; ++si)
                acc += pl[h][si] * bf2f(vp[(size_t)sel[si] * HDIM]);
        } else {
            for (int si = 0; si < cnt; ++si)
                acc += pl[h][si] * bf2f(vp[(size_t)sel[si] * HDIM]);
        }
        out[(size_t)t * D_MODEL + h * HDIM + lane] = f2bf(acc);
    }
}

extern "C" void kernel_launch(void* const* d_in, const int* in_sizes, int n_in,
                              void* d_out, int out_size, void* d_ws, size_t ws_size,
                              hipStream_t stream)
{
    const float* x      = (const float*)d_in[0];
    const float* w_qkv  = (const float*)d_in[1];
    const float* w_o    = (const float*)d_in[2];
    const float* ffn_w1 = (const float*)d_in[3];
    const float* ffn_b1 = (const float*)d_in[4];
    const float* ffn_w2 = (const float*)d_in[5];
    const float* ffn_b2 = (const float*)d_in[6];
    const float* ln1_g  = (const float*)d_in[7];
    const float* ln1_b  = (const float*)d_in[8];
    const float* ln2_g  = (const float*)d_in[9];
    const float* ln2_b  = (const float*)d_in[10];
    const float* idx_wq = (const float*)d_in[11];
    const float* idx_wk = (const float*)d_in[12];
    const float* idx_ww = (const float*)d_in[13];
    float* outp = (float*)d_out;

    const size_t MB = 1ull << 20;
    char* ws = (char*)d_ws;
    float*          normx    = (float*)(ws + 0);
    unsigned short* attno_bf = (unsigned short*)(ws + 0);
    unsigned short* normx_bf = (unsigned short*)(ws + 8 * MB);
    unsigned short* h2_bf    = normx_bf;
    unsigned short* qkv_bf   = (unsigned short*)(ws + 12 * MB);
    int*            topidx   = (int*)(ws + 12 * MB);
    int*            topcnt   = (int*)(ws + 12 * MB + 512 * 1024);
    unsigned short* wqkv_t   = (unsigned short*)(ws + 24 * MB);
    unsigned short* wo_t     = (unsigned short*)(ws + 30 * MB);
    unsigned short* w1_t     = (unsigned short*)(ws + 32 * MB);
    unsigned short* w2_t     = (unsigned short*)(ws + 40 * MB);
    unsigned short* Qb       = (unsigned short*)(ws + 48 * MB);
    unsigned short* Kb       = (unsigned short*)(ws + 52 * MB);
    unsigned short* Vb       = (unsigned short*)(ws + 56 * MB);
    float*          ctab     = (float*)(ws + 60 * MB);
    float*          stab     = (float*)(ws + 60 * MB + 256 * 1024);
    float*          scoresb  = (float*)(ws + 60 * MB);
    unsigned short* ffn1_bf  = (unsigned short*)(ws + 60 * MB);
    float*          QIW      = (float*)(ws + 76 * MB);
    float*          Wc       = (float*)(ws + 79 * MB);

    dim3 blk256(256);
    auto g128 = [](int N, int M) { return dim3(N / 128, M / 128); };

    // 1. LN1 -> fp32 (indexer) + bf16 (qkv gemm)
    ln_kernel<<<S_LEN, blk256, 0, stream>>>(x, ln1_g, ln1_b, normx, normx_bf);
    // 2. rope tables + weight prep
    rope_table_kernel<<<(S_LEN * 32) / 256, blk256, 0, stream>>>(ctab, stab);
    wtrans_kernel<<<dim3(3 * D_MODEL / 32, D_MODEL / 32), blk256, 0, stream>>>(w_qkv, wqkv_t, D_MODEL, 3 * D_MODEL);
    wtrans_kernel<<<dim3(D_MODEL / 32, D_MODEL / 32), blk256, 0, stream>>>(w_o, wo_t, D_MODEL, D_MODEL);
    wtrans_kernel<<<dim3(DFF / 32, D_MODEL / 32), blk256, 0, stream>>>(ffn_w1, w1_t, D_MODEL, DFF);
    wtrans_kernel<<<dim3(D_MODEL / 32, DFF / 32), blk256, 0, stream>>>(ffn_w2, w2_t, DFF, D_MODEL);
    wpack_kernel<<<(D_MODEL * NIDX + 255) / 256, blk256, 0, stream>>>(idx_wq, idx_wk, idx_ww, Wc);
    // 3. qkv = norm_x @ w_qkv (bf16 out only)
    gemm_bf16<<<g128(3 * D_MODEL, S_LEN), blk256, 0, stream>>>(normx_bf, wqkv_t,
        nullptr, qkv_bf, nullptr, nullptr, S_LEN, 3 * D_MODEL, D_MODEL, 0);
    // 4. fused indexer projections (fp32 — feeds discrete top-k)
    gemm64<<<dim3((NIDX + 63) / 64, S_LEN / 64), blk256, 0, stream>>>(normx, Wc, QIW, S_LEN, NIDX, D_MODEL);
    // 5. RoPE + pack Q/K/V (bf16, K/V head-major)
    rope_pack_kernel<<<S_LEN, dim3(512), 0, stream>>>(qkv_bf, ctab, stab, Qb, Kb, Vb);
    // 6. indexer scores (overwrites ctab region — rope_pack already done)
    scores_kernel<<<dim3(64, 64), blk256, 0, stream>>>(QIW, scoresb);
    // 7. top-64 per row (radix select; topidx overlays dead qkv_bf)
    topk_kernel<<<S_LEN, blk256, 0, stream>>>(scoresb, topidx, topcnt);
    // 8. sparse attention -> bf16 (overlays dead normx)
    attn_kernel<<<S_LEN, blk256, 0, stream>>>(Qb, Kb, Vb, topidx, topcnt, attno_bf);
    // 9. x1 = x + attn_out @ w_o
    gemm_bf16<<<g128(D_MODEL, S_LEN), blk256, 0, stream>>>(attno_bf, wo_t,
        outp, nullptr, nullptr, x, S_LEN, D_MODEL, D_MODEL, 0);
    // 10. h = LN2(x1) -> bf16
    ln_kernel<<<S_LEN, blk256, 0, stream>>>(outp, ln2_g, ln2_b, nullptr, h2_bf);
    // 11. ffn1 = gelu(h @ w1 + b1) -> bf16 (overlays dead scoresb)
    gemm_bf16<<<g128(DFF, S_LEN), blk256, 0, stream>>>(h2_bf, w1_t,
        nullptr, ffn1_bf, ffn_b1, nullptr, S_LEN, DFF, D_MODEL, 1);
    // 12. out = x1 + ffn1 @ w2 + b2
    gemm_bf16<<<g128(D_MODEL, S_LEN), blk256, 0, stream>>>(ffn1_bf, w2_t,
        outp, nullptr, ffn_b2, outp, S_LEN, D_MODEL, DFF, 0);
}

// Round 5
// 395.496 us; speedup vs baseline: 3.4194x; 1.1712x over previous
//
#include <hip/hip_runtime.h>
#include <math.h>

#define S_LEN 2048
#define D_MODEL 1024
#define NHEAD 16
#define HDIM 64
#define DFF 4096
#define IH 4
#define IDM 64
#define TOPK 64
#define NIDX 336   // 256 qi + 64 ki + 4 wi + 12 pad

typedef float f32x4 __attribute__((ext_vector_type(4)));
typedef short bf16x8 __attribute__((ext_vector_type(8)));

__device__ __forceinline__ unsigned short f2bf(float f) {
    unsigned u = __builtin_bit_cast(unsigned, f);
    u += 0x7fff + ((u >> 16) & 1);
    return (unsigned short)(u >> 16);
}
__device__ __forceinline__ float bf2f(unsigned short us) {
    return __builtin_bit_cast(float, (unsigned)us << 16);
}

__device__ __forceinline__ float gelu_exact(float v) {
    return 0.5f * v * (1.f + erff(v * 0.70710678118654752f));
}

__device__ __forceinline__ void gl_lds16(const void* g, void* l) {
    __builtin_amdgcn_global_load_lds(
        (const __attribute__((address_space(1))) void*)g,
        (__attribute__((address_space(3))) void*)l, 16, 0, 0);
}

// ---------------- LayerNorm: fp32 out (optional) + bf16 out (optional) ----------------
__global__ __launch_bounds__(256) void ln_kernel(const float* __restrict__ x,
    const float* __restrict__ g, const float* __restrict__ b,
    float* __restrict__ outf, unsigned short* __restrict__ outb)
{
    int row = blockIdx.x, tid = threadIdx.x;
    const float4 v = *(const float4*)(x + (size_t)row * D_MODEL + tid * 4);
    float s = v.x + v.y + v.z + v.w;
    float ss = v.x * v.x + v.y * v.y + v.z * v.z + v.w * v.w;
    int lane = tid & 63, wv = tid >> 6;
    for (int o = 32; o; o >>= 1) { s += __shfl_xor(s, o); ss += __shfl_xor(ss, o); }
    __shared__ float rs[4], rss[4];
    if (lane == 0) { rs[wv] = s; rss[wv] = ss; }
    __syncthreads();
    float S = rs[0] + rs[1] + rs[2] + rs[3];
    float SS = rss[0] + rss[1] + rss[2] + rss[3];
    float mean = S * (1.f / D_MODEL);
    float var = SS * (1.f / D_MODEL) - mean * mean;
    float r = rsqrtf(var + 1e-5f);
    float4 gv = *(const float4*)(g + tid * 4);
    float4 bv = *(const float4*)(b + tid * 4);
    float4 o4;
    o4.x = (v.x - mean) * r * gv.x + bv.x;
    o4.y = (v.y - mean) * r * gv.y + bv.y;
    o4.z = (v.z - mean) * r * gv.z + bv.z;
    o4.w = (v.w - mean) * r * gv.w + bv.w;
    if (outf) *(float4*)(outf + (size_t)row * D_MODEL + tid * 4) = o4;
    if (outb) {
        ushort4 u4 = { f2bf(o4.x), f2bf(o4.y), f2bf(o4.z), f2bf(o4.w) };
        *(ushort4*)(outb + (size_t)row * D_MODEL + tid * 4) = u4;
    }
}

// ---------------- Weight convert + transpose: fp32 [K][N] -> bf16 [N][K] ----------------
__global__ __launch_bounds__(256) void wtrans_kernel(const float* __restrict__ in,
    unsigned short* __restrict__ out, int K, int N)
{
    __shared__ float t[32][33];
    int k0 = blockIdx.y * 32, n0 = blockIdx.x * 32;
    int tid = threadIdx.x;
    int r = tid >> 5, c = tid & 31;
#pragma unroll
    for (int p = 0; p < 4; ++p)
        t[r + p * 8][c] = in[(size_t)(k0 + r + p * 8) * N + n0 + c];
    __syncthreads();
#pragma unroll
    for (int p = 0; p < 4; ++p)
        out[(size_t)(n0 + r + p * 8) * K + k0 + c] = f2bf(t[c][r + p * 8]);
}

// ---------------- Pack indexer weights into one fp32 [1024][336] ----------------
__global__ __launch_bounds__(256) void wpack_kernel(const float* __restrict__ wq,
    const float* __restrict__ wk, const float* __restrict__ ww, float* __restrict__ Wc)
{
    int idx = blockIdx.x * 256 + threadIdx.x;
    if (idx >= D_MODEL * NIDX) return;
    int r = idx / NIDX, c = idx % NIDX;
    float v = 0.f;
    if (c < 256) v = wq[r * 256 + c];
    else if (c < 320) v = wk[r * 64 + (c - 256)];
    else if (c < 324) v = ww[r * 4 + (c - 320)];
    Wc[idx] = v;
}

// ---------------- bf16 MFMA GEMM (m97 structure): C = act(A @ Bt^T + bias) + R ----------------
// Split-K mode: if P != nullptr, block z computes K-chunk [z*kchunk, z*kchunk+kchunk)
// and writes raw fp32 partials to P + z*M*N (no epilogue).
__global__ __launch_bounds__(256) void gemm_bf16(
    const unsigned short* __restrict__ A, const unsigned short* __restrict__ Bt,
    float* __restrict__ C, unsigned short* __restrict__ Cb,
    const float* __restrict__ bias, const float* __restrict__ R,
    int M, int N, int K, int act,
    float* __restrict__ P, int kchunk)
{
    __shared__ __attribute__((aligned(16))) unsigned short As[128 * 32];
    __shared__ __attribute__((aligned(16))) unsigned short Bs[128 * 32];
    int tid = threadIdx.x;
    int bm = blockIdx.y * 128, bn = blockIdx.x * 128;
    int wid = tid >> 6, lane = tid & 63;
    int wm = (wid >> 1) * 64, wn = (wid & 1) * 64;
    const unsigned short* Ab = A + (size_t)bm * K;
    const unsigned short* Bb = Bt + (size_t)bn * K;
    f32x4 acc[4][4];
#pragma unroll
    for (int i = 0; i < 4; ++i)
#pragma unroll
        for (int j = 0; j < 4; ++j)
            acc[i][j] = (f32x4){0.f, 0.f, 0.f, 0.f};

    int kbeg = blockIdx.z * kchunk;
    int kend = kbeg + kchunk;
    int fr = lane & 15, fk = (lane >> 4) * 8;
    for (int k0 = kbeg; k0 < kend; k0 += 32) {
#pragma unroll
        for (int i = 0; i < 2; ++i) {
            int e = (i * 256 + tid) * 8;
            int r = e >> 5, c = e & 31;
            gl_lds16(Ab + (size_t)r * K + k0 + c, As + e);
            gl_lds16(Bb + (size_t)r * K + k0 + c, Bs + e);
        }
        __syncthreads();
        bf16x8 af[4], bfv[4];
#pragma unroll
        for (int mi = 0; mi < 4; ++mi)
            af[mi] = *(const bf16x8*)&As[(wm + mi * 16 + fr) * 32 + fk];
#pragma unroll
        for (int ni = 0; ni < 4; ++ni)
            bfv[ni] = *(const bf16x8*)&Bs[(wn + ni * 16 + fr) * 32 + fk];
#pragma unroll
        for (int mi = 0; mi < 4; ++mi)
#pragma unroll
            for (int ni = 0; ni < 4; ++ni)
                acc[mi][ni] = __builtin_amdgcn_mfma_f32_16x16x32_bf16(
                    af[mi], bfv[ni], acc[mi][ni], 0, 0, 0);
        __syncthreads();
    }
    int cl = lane & 15, rh = (lane >> 4) * 4;
    if (P) {
        float* Pz = P + (size_t)blockIdx.z * M * N;
#pragma unroll
        for (int mi = 0; mi < 4; ++mi)
#pragma unroll
            for (int ni = 0; ni < 4; ++ni) {
                int col = bn + wn + ni * 16 + cl;
#pragma unroll
                for (int r = 0; r < 4; ++r) {
                    int row = bm + wm + mi * 16 + rh + r;
                    Pz[(size_t)row * N + col] = acc[mi][ni][r];
                }
            }
        return;
    }
#pragma unroll
    for (int mi = 0; mi < 4; ++mi) {
#pragma unroll
        for (int ni = 0; ni < 4; ++ni) {
            int col = bn + wn + ni * 16 + cl;
            float bv = bias ? bias[col] : 0.f;
#pragma unroll
            for (int r = 0; r < 4; ++r) {
                int row = bm + wm + mi * 16 + rh + r;
                float v = acc[mi][ni][r] + bv;
                if (act) v = gelu_exact(v);
                size_t off = (size_t)row * N + col;
                if (R) v += R[off];
                if (C) C[off] = v;
                if (Cb) Cb[off] = f2bf(v);
            }
        }
    }
}

// ---------------- Split-K reduce: C = sum_z P[z] + bias + R (float4 vectorized) ----------------
__global__ __launch_bounds__(256) void kreduce_kernel(const float* __restrict__ P,
    int nslice, float* __restrict__ C, const float* __restrict__ bias,
    const float* __restrict__ R, int M, int N)
{
    size_t total4 = (size_t)M * N / 4;
    size_t stride = (size_t)gridDim.x * 256;
    for (size_t i4 = blockIdx.x * 256 + threadIdx.x; i4 < total4; i4 += stride) {
        size_t off = i4 * 4;
        float4 v = *(const float4*)(P + off);
        for (int z = 1; z < nslice; ++z) {
            float4 p = *(const float4*)(P + (size_t)z * M * N + off);
            v.x += p.x; v.y += p.y; v.z += p.z; v.w += p.w;
        }
        if (bias) {
            float4 b4 = *(const float4*)(bias + (off % N));
            v.x += b4.x; v.y += b4.y; v.z += b4.z; v.w += b4.w;
        }
        if (R) {
            float4 r4 = *(const float4*)(R + off);
            v.x += r4.x; v.y += r4.y; v.z += r4.z; v.w += r4.w;
        }
        *(float4*)(C + off) = v;
    }
}

// ---------------- Generic fp32 GEMM (indexer path): C[M,N] = A[M,K]@B[K,N] ----------------
__global__ __launch_bounds__(256) void gemm64(const float* __restrict__ A,
    const float* __restrict__ B, float* __restrict__ C,
    int M, int N, int K)
{
    __shared__ float As[16][68];
    __shared__ float Bs[16][68];
    int tid = threadIdx.x;
    int bm = blockIdx.y, bn = blockIdx.x;
    int tx = tid & 15, ty = tid >> 4;
    int arow = tid >> 2;
    int acol = (tid & 3) << 2;
    int brow = tid >> 4;
    int bcol = (tid & 15) << 2;
    const float* Abase = A + (size_t)(bm * 64 + arow) * K + acol;
    float c[4][4] = {};
    for (int k0 = 0; k0 < K; k0 += 16) {
        float4 av = *(const float4*)(Abase + k0);
        As[acol + 0][arow] = av.x;
        As[acol + 1][arow] = av.y;
        As[acol + 2][arow] = av.z;
        As[acol + 3][arow] = av.w;
        int gcol = bn * 64 + bcol;
        const float* Bb = B + (size_t)(k0 + brow) * N;
        float4 bv;
        if (gcol + 3 < N) {
            bv = *(const float4*)(Bb + gcol);
        } else {
            bv.x = (gcol + 0 < N) ? Bb[gcol + 0] : 0.f;
            bv.y = (gcol + 1 < N) ? Bb[gcol + 1] : 0.f;
            bv.z = (gcol + 2 < N) ? Bb[gcol + 2] : 0.f;
            bv.w = (gcol + 3 < N) ? Bb[gcol + 3] : 0.f;
        }
        *(float4*)&Bs[brow][bcol] = bv;
        __syncthreads();
#pragma unroll
        for (int kk = 0; kk < 16; ++kk) {
            float4 a4 = *(const float4*)&As[kk][ty * 4];
            float4 b4 = *(const float4*)&Bs[kk][tx * 4];
            float av4[4] = { a4.x, a4.y, a4.z, a4.w };
            float bv4[4] = { b4.x, b4.y, b4.z, b4.w };
#pragma unroll
            for (int i = 0; i < 4; ++i)
#pragma unroll
                for (int j = 0; j < 4; ++j)
                    c[i][j] += av4[i] * bv4[j];
        }
        __syncthreads();
    }
#pragma unroll
    for (int i = 0; i < 4; ++i) {
        int row = bm * 64 + ty * 4 + i;
#pragma unroll
        for (int j = 0; j < 4; ++j) {
            int col = bn * 64 + tx * 4 + j;
            if (col < N)
                C[(size_t)row * N + col] = c[i][j];
        }
    }
}

// ---------------- RoPE table ----------------
__global__ __launch_bounds__(256) void rope_table_kernel(float* __restrict__ ct, float* __restrict__ st)
{
    int g = blockIdx.x * 256 + threadIdx.x;
    int t = g >> 5, i = g & 31;
    float theta = powf(10000.f, -(float)i / 32.f);
    float ang = (float)t * theta;
    ct[g] = cosf(ang);
    st[g] = sinf(ang);
}

// ---------------- RoPE + pack: qkv bf16 [S][3072] -> Qb [S][1024], Kb/Vb [H][S][64] ----------------
__global__ __launch_bounds__(512) void rope_pack_kernel(
    const unsigned short* __restrict__ qkvb,
    const float* __restrict__ ct, const float* __restrict__ st,
    unsigned short* __restrict__ Qb, unsigned short* __restrict__ Kb,
    unsigned short* __restrict__ Vb)
{
    int t = blockIdx.x, tid = threadIdx.x;
    int h = tid >> 5, i = tid & 31;
    float c = ct[t * 32 + i], s = st[t * 32 + i];
    const unsigned short* base = qkvb + (size_t)t * (3 * D_MODEL);
    ushort2 q2 = *(const ushort2*)(base + h * HDIM + 2 * i);
    float q0 = bf2f(q2.x), q1 = bf2f(q2.y);
    ushort2 qo = { f2bf(q0 * c - q1 * s), f2bf(q1 * c + q0 * s) };
    *(ushort2*)(Qb + (size_t)t * D_MODEL + h * HDIM + 2 * i) = qo;
    ushort2 k2 = *(const ushort2*)(base + D_MODEL + h * HDIM + 2 * i);
    float k0 = bf2f(k2.x), k1 = bf2f(k2.y);
    ushort2 ko = { f2bf(k0 * c - k1 * s), f2bf(k1 * c + k0 * s) };
    *(ushort2*)(Kb + ((size_t)h * S_LEN + t) * HDIM + 2 * i) = ko;
    ushort2 v2 = *(const ushort2*)(base + 2 * D_MODEL + 2 * tid);
    int vh = tid >> 5, vd = (2 * tid) & 63;
    *(ushort2*)(Vb + ((size_t)vh * S_LEN + t) * HDIM + vd) = v2;
}

// ---------------- Indexer scores (fp32, fused QIW layout, stride 336) ----------------
__global__ __launch_bounds__(256) void scores_kernel(const float* __restrict__ QIW,
    float* __restrict__ scores)
{
    int t0 = blockIdx.y * 32, s0 = blockIdx.x * 32;
    if (s0 > t0 + 31) return;
    __shared__ float qis[32][256];
    __shared__ float kis[32][65];
    __shared__ float wis[32][4];
    int tid = threadIdx.x;
#pragma unroll
    for (int l = 0; l < 8; ++l) {
        int idx = l * 256 + tid;
        int r = idx >> 6, c = (idx & 63) << 2;
        *(float4*)&qis[r][c] = *(const float4*)(QIW + (size_t)(t0 + r) * NIDX + c);
    }
#pragma unroll
    for (int l = 0; l < 8; ++l) {
        int idx = l * 256 + tid;
        int r = idx >> 6, c = idx & 63;
        kis[r][c] = QIW[(size_t)(s0 + r) * NIDX + 256 + c];
    }
    if (tid < 32) *(float4*)&wis[tid][0] = *(const float4*)(QIW + (size_t)(t0 + tid) * NIDX + 320);
    __syncthreads();
    int sl = tid & 31;
    int tb = (tid >> 5) * 4;
    float acc[4] = { 0.f, 0.f, 0.f, 0.f };
#pragma unroll
    for (int h = 0; h < 4; ++h) {
        float dots[4] = { 0.f, 0.f, 0.f, 0.f };
        for (int d = 0; d < 64; ++d) {
            float kv = kis[sl][d];
#pragma unroll
            for (int i = 0; i < 4; ++i)
                dots[i] += qis[tb + i][h * 64 + d] * kv;
        }
#pragma unroll
        for (int i = 0; i < 4; ++i)
            acc[i] += wis[tb + i][h] * fmaxf(dots[i], 0.f);
    }
#pragma unroll
    for (int i = 0; i < 4; ++i)
        scores[(size_t)(t0 + tb + i) * S_LEN + s0 + sl] = acc[i];
}

// ---------------- Top-K via radix select (exact lax.top_k set semantics) ----------------
__global__ __launch_bounds__(256) void topk_kernel(const float* __restrict__ scores,
    int* __restrict__ topidx, int* __restrict__ topcnt)
{
    int t = blockIdx.x, tid = threadIdx.x;
    int n = t + 1;
    if (n <= TOPK) {
        if (tid < n) topidx[t * TOPK + tid] = tid;
        if (tid == 0) topcnt[t] = n;
        return;
    }
    __shared__ unsigned sc[S_LEN];
    __shared__ unsigned hist[256];
    __shared__ int selbin_s;
    __shared__ int cnt_out;
    __shared__ unsigned wsum[4];
    for (int j = tid; j < n; j += 256) {
        unsigned u = __builtin_bit_cast(unsigned, scores[(size_t)t * S_LEN + j]);
        sc[j] = (u & 0x80000000u) ? ~u : (u | 0x80000000u);
    }
    if (tid == 0) cnt_out = 0;
    int lane = tid & 63, wv = tid >> 6;
    unsigned prefix = 0;
    int kk = TOPK;
#pragma unroll
    for (int round = 0; round < 4; ++round) {
        int shift_pref = 32 - 8 * round;
        int shift_bin = 24 - 8 * round;
        hist[tid] = 0;
        __syncthreads();
        for (int j = tid; j < n; j += 256) {
            unsigned v = sc[j];
            if ((((unsigned long long)(v ^ prefix)) >> shift_pref) == 0)
                atomicAdd(&hist[(v >> shift_bin) & 0xff], 1u);
        }
        __syncthreads();
        if (wv == 0) {
            unsigned h0 = hist[4 * lane], h1 = hist[4 * lane + 1];
            unsigned h2 = hist[4 * lane + 2], h3 = hist[4 * lane + 3];
            unsigned s3 = h3, s2 = h2 + s3, s1 = h1 + s2, s0 = h0 + s1;
            unsigned acc = s0;
            for (int off = 1; off < 64; off <<= 1) {
                unsigned o = __shfl_down(acc, off);
                if (lane + off < 64) acc += o;
            }
            unsigned above = acc - s0;
            hist[4 * lane]     = s0 + above;
            hist[4 * lane + 1] = s1 + above;
            hist[4 * lane + 2] = s2 + above;
            hist[4 * lane + 3] = s3 + above;
        }
        __syncthreads();
        {
            unsigned sufb = hist[tid];
            unsigned sufn = (tid < 255) ? hist[tid + 1] : 0u;
            if (sufb >= (unsigned)kk && sufn < (unsigned)kk)
                selbin_s = tid;
        }
        __syncthreads();
        int b = selbin_s;
        unsigned above = (b < 255) ? hist[b + 1] : 0u;
        kk -= (int)above;
        prefix |= ((unsigned)b) << shift_bin;
        __syncthreads();
    }
    unsigned T = prefix;
    int chunk = (n + 255) >> 8;
    int jb = tid * chunk;
    int je = jb + chunk; if (je > n) je = n;
    int ties = 0;
    for (int j = jb; j < je; ++j) {
        unsigned v = sc[j];
        if (v > T) { int o = atomicAdd(&cnt_out, 1); topidx[t * TOPK + o] = j; }
        else if (v == T) ++ties;
    }
    unsigned inc = (unsigned)ties;
    for (int off = 1; off < 64; off <<= 1) {
        unsigned o = __shfl_up(inc, off);
        if (lane >= off) inc += o;
    }
    if (lane == 63) wsum[wv] = inc;
    __syncthreads();
    unsigned woff = 0;
    for (int w = 0; w < wv; ++w) woff += wsum[w];
    int rank = (int)(woff + inc) - ties;
    for (int j = jb; j < je && rank < kk; ++j) {
        if (sc[j] == T) {
            int o = atomicAdd(&cnt_out, 1);
            topidx[t * TOPK + o] = j;
            ++rank;
        }
    }
    if (tid == 0) topcnt[t] = TOPK;
}

// ---------------- Sparse SDPA v2: bf16 head-major gather, LDS p ----------------
__global__ __launch_bounds__(256) void attn_kernel(
    const unsigned short* __restrict__ Qb, const unsigned short* __restrict__ Kb,
    const unsigned short* __restrict__ Vb,
    const int* __restrict__ topidx, const int* __restrict__ topcnt,
    unsigned short* __restrict__ out)
{
    int t = blockIdx.x, tid = threadIdx.x;
    __shared__ unsigned short qls[D_MODEL];
    __shared__ int sel[TOPK];
    __shared__ float pl[NHEAD][TOPK];
    *(ushort4*)(qls + tid * 4) = *(const ushort4*)(Qb + (size_t)t * D_MODEL + tid * 4);
    if (tid < TOPK) sel[tid] = topidx[t * TOPK + tid];
    __syncthreads();
    int cnt = topcnt[t];
    int lane = tid & 63, wv = tid >> 6;
    int s_l = sel[(lane < cnt) ? lane : 0];
#pragma unroll
    for (int hh = 0; hh < 4; ++hh) {
        int h = wv * 4 + hh;
        const unsigned short* kp = Kb + ((size_t)h * S_LEN + s_l) * HDIM;
        float dot = 0.f;
#pragma unroll
        for (int j = 0; j < 8; ++j) {
            bf16x8 kf = *(const bf16x8*)(kp + j * 8);
            bf16x8 qf = *(const bf16x8*)(qls + h * HDIM + j * 8);
#pragma unroll
            for (int e = 0; e < 8; ++e)
                dot += bf2f((unsigned short)kf[e]) * bf2f((unsigned short)qf[e]);
        }
        float logit = (lane < cnt) ? dot * 0.125f : -INFINITY;
        float m = logit;
        for (int o = 32; o; o >>= 1) m = fmaxf(m, __shfl_xor(m, o));
        float p = (lane < cnt) ? __expf(logit - m) : 0.f;
        float sum = p;
        for (int o = 32; o; o >>= 1) sum += __shfl_xor(sum, o);
        pl[h][lane] = p / sum;
    }
#pragma unroll
    for (int hh = 0; hh < 4; ++hh) {
        int h = wv * 4 + hh;
        const unsigned short* vp = Vb + (size_t)h * S_LEN * HDIM + lane;
        float acc = 0.f;
        if (cnt == TOPK) {
#pragma unroll 8
            for (int si = 0; si < TOPK; ++si)
                acc += pl[h][si] * bf2f(vp[(size_t)sel[si] * HDIM]);
        } else {
            for (int si = 0; si < cnt; ++si)
                acc += pl[h][si] * bf2f(vp[(size_t)sel[si] * HDIM]);
        }
        out[(size_t)t * D_MODEL + h * HDIM + lane] = f2bf(acc);
    }
}

extern "C" void kernel_launch(void* const* d_in, const int* in_sizes, int n_in,
                              void* d_out, int out_size, void* d_ws, size_t ws_size,
                              hipStream_t stream)
{
    const float* x      = (const float*)d_in[0];
    const float* w_qkv  = (const float*)d_in[1];
    const float* w_o    = (const float*)d_in[2];
    const float* ffn_w1 = (const float*)d_in[3];
    const float* ffn_b1 = (const float*)d_in[4];
    const float* ffn_w2 = (const float*)d_in[5];
    const float* ffn_b2 = (const float*)d_in[6];
    const float* ln1_g  = (const float*)d_in[7];
    const float* ln1_b  = (const float*)d_in[8];
    const float* ln2_g  = (const float*)d_in[9];
    const float* ln2_b  = (const float*)d_in[10];
    const float* idx_wq = (const float*)d_in[11];
    const float* idx_wk = (const float*)d_in[12];
    const float* idx_ww = (const float*)d_in[13];
    float* outp = (float*)d_out;

    const size_t MB = 1ull << 20;
    char* ws = (char*)d_ws;
    // [0,8)    normx fp32 -> attno_bf (4MB) -> Pf2 slice0
    // [8,12)   normx_bf / h2_bf    (dead after ffn1 -> Pf2)
    // [12,24)  qkv_bf -> topidx/topcnt  (dead after attn -> Pf2)
    // [24,32)  wqkv_t/wo_t  (dead after w_o gemm -> Pf2)
    // [32,40)  w1_t   [40,48) w2_t
    // [48,60)  Qb/Kb/Vb  (dead after attn)
    // [60,76)  ctab/stab -> scoresb -> Pwo (w_o partials, 16MB) -> ffn1_bf
    // [76,79)  QIW   [79,80.5) Wc
    float*          normx    = (float*)(ws + 0);
    unsigned short* attno_bf = (unsigned short*)(ws + 0);
    float*          Pf2      = (float*)(ws + 0);            // 32MB ffn2 partials (4 slices)
    unsigned short* normx_bf = (unsigned short*)(ws + 8 * MB);
    unsigned short* h2_bf    = normx_bf;
    unsigned short* qkv_bf   = (unsigned short*)(ws + 12 * MB);
    int*            topidx   = (int*)(ws + 12 * MB);
    int*            topcnt   = (int*)(ws + 12 * MB + 512 * 1024);
    unsigned short* wqkv_t   = (unsigned short*)(ws + 24 * MB);
    unsigned short* wo_t     = (unsigned short*)(ws + 30 * MB);
    unsigned short* w1_t     = (unsigned short*)(ws + 32 * MB);
    unsigned short* w2_t     = (unsigned short*)(ws + 40 * MB);
    unsigned short* Qb       = (unsigned short*)(ws + 48 * MB);
    unsigned short* Kb       = (unsigned short*)(ws + 52 * MB);
    unsigned short* Vb       = (unsigned short*)(ws + 56 * MB);
    float*          ctab     = (float*)(ws + 60 * MB);
    float*          stab     = (float*)(ws + 60 * MB + 256 * 1024);
    float*          scoresb  = (float*)(ws + 60 * MB);
    float*          Pwo      = (float*)(ws + 60 * MB);      // 16MB w_o partials (2 slices)
    unsigned short* ffn1_bf  = (unsigned short*)(ws + 60 * MB);
    float*          QIW      = (float*)(ws + 76 * MB);
    float*          Wc       = (float*)(ws + 79 * MB);

    dim3 blk256(256);
    auto g128 = [](int N, int M) { return dim3(N / 128, M / 128); };

    // 1. LN1 -> fp32 (indexer) + bf16 (qkv gemm)
    ln_kernel<<<S_LEN, blk256, 0, stream>>>(x, ln1_g, ln1_b, normx, normx_bf);
    // 2. rope tables + weight prep
    rope_table_kernel<<<(S_LEN * 32) / 256, blk256, 0, stream>>>(ctab, stab);
    wtrans_kernel<<<dim3(3 * D_MODEL / 32, D_MODEL / 32), blk256, 0, stream>>>(w_qkv, wqkv_t, D_MODEL, 3 * D_MODEL);
    wtrans_kernel<<<dim3(D_MODEL / 32, D_MODEL / 32), blk256, 0, stream>>>(w_o, wo_t, D_MODEL, D_MODEL);
    wtrans_kernel<<<dim3(DFF / 32, D_MODEL / 32), blk256, 0, stream>>>(ffn_w1, w1_t, D_MODEL, DFF);
    wtrans_kernel<<<dim3(D_MODEL / 32, DFF / 32), blk256, 0, stream>>>(ffn_w2, w2_t, DFF, D_MODEL);
    wpack_kernel<<<(D_MODEL * NIDX + 255) / 256, blk256, 0, stream>>>(idx_wq, idx_wk, idx_ww, Wc);
    // 3. qkv = norm_x @ w_qkv (bf16 out only; 384 blocks)
    gemm_bf16<<<g128(3 * D_MODEL, S_LEN), blk256, 0, stream>>>(normx_bf, wqkv_t,
        nullptr, qkv_bf, nullptr, nullptr, S_LEN, 3 * D_MODEL, D_MODEL, 0, nullptr, D_MODEL);
    // 4. fused indexer projections (fp32 — feeds discrete top-k)
    gemm64<<<dim3((NIDX + 63) / 64, S_LEN / 64), blk256, 0, stream>>>(normx, Wc, QIW, S_LEN, NIDX, D_MODEL);
    // 5. RoPE + pack Q/K/V (bf16, K/V head-major)
    rope_pack_kernel<<<S_LEN, dim3(512), 0, stream>>>(qkv_bf, ctab, stab, Qb, Kb, Vb);
    // 6. indexer scores (overwrites ctab region — rope_pack already done)
    scores_kernel<<<dim3(64, 64), blk256, 0, stream>>>(QIW, scoresb);
    // 7. top-64 per row (radix select; topidx overlays dead qkv_bf)
    topk_kernel<<<S_LEN, blk256, 0, stream>>>(scoresb, topidx, topcnt);
    // 8. sparse attention -> bf16 (overlays dead normx)
    attn_kernel<<<S_LEN, blk256, 0, stream>>>(Qb, Kb, Vb, topidx, topcnt, attno_bf);
    // 9. x1 = x + attn_out @ w_o  — split-K=2 (256 blocks) into Pwo, then reduce
    gemm_bf16<<<dim3(D_MODEL / 128, S_LEN / 128, 2), blk256, 0, stream>>>(attno_bf, wo_t,
        nullptr, nullptr, nullptr, nullptr, S_LEN, D_MODEL, D_MODEL, 0, Pwo, D_MODEL / 2);
    kreduce_kernel<<<1024, blk256, 0, stream>>>(Pwo, 2, outp, nullptr, x, S_LEN, D_MODEL);
    // 10. h = LN2(x1) -> bf16
    ln_kernel<<<S_LEN, blk256, 0, stream>>>(outp, ln2_g, ln2_b, nullptr, h2_bf);
    // 11. ffn1 = gelu(h @ w1 + b1) -> bf16 (overlays dead Pwo/scoresb; 512 blocks)
    gemm_bf16<<<g128(DFF, S_LEN), blk256, 0, stream>>>(h2_bf, w1_t,
        nullptr, ffn1_bf, ffn_b1, nullptr, S_LEN, DFF, D_MODEL, 1, nullptr, D_MODEL);
    // 12. out = x1 + ffn1 @ w2 + b2 — split-K=4 (512 blocks) into Pf2, then reduce
    gemm_bf16<<<dim3(D_MODEL / 128, S_LEN / 128, 4), blk256, 0, stream>>>(ffn1_bf, w2_t,
        nullptr, nullptr, nullptr, nullptr, S_LEN, D_MODEL, DFF, 0, Pf2, DFF / 4);
    kreduce_kernel<<<1024, blk256, 0, stream>>>(Pf2, 4, outp, ffn_b2, outp, S_LEN, D_MODEL);
}

// Round 6
// 357.139 us; speedup vs baseline: 3.7866x; 1.1074x over previous
//
#include <hip/hip_runtime.h>
#include <math.h>

#define S_LEN 2048
#define D_MODEL 1024
#define NHEAD 16
#define HDIM 64
#define DFF 4096
#define IH 4
#define IDM 64
#define TOPK 64
#define NIDX 336   // 256 qi + 64 ki + 4 wi + 12 pad

typedef float f32x4 __attribute__((ext_vector_type(4)));
typedef short bf16x8 __attribute__((ext_vector_type(8)));

__device__ __forceinline__ unsigned short f2bf(float f) {
    unsigned u = __builtin_bit_cast(unsigned, f);
    u += 0x7fff + ((u >> 16) & 1);
    return (unsigned short)(u >> 16);
}
__device__ __forceinline__ float bf2f(unsigned short us) {
    return __builtin_bit_cast(float, (unsigned)us << 16);
}

__device__ __forceinline__ float gelu_exact(float v) {
    return 0.5f * v * (1.f + erff(v * 0.70710678118654752f));
}

__device__ __forceinline__ void gl_lds16(const void* g, void* l) {
    __builtin_amdgcn_global_load_lds(
        (const __attribute__((address_space(1))) void*)g,
        (__attribute__((address_space(3))) void*)l, 16, 0, 0);
}

// ---------------- LayerNorm: fp32 out (optional) + bf16 out (optional) ----------------
__global__ __launch_bounds__(256) void ln_kernel(const float* __restrict__ x,
    const float* __restrict__ g, const float* __restrict__ b,
    float* __restrict__ outf, unsigned short* __restrict__ outb)
{
    int row = blockIdx.x, tid = threadIdx.x;
    const float4 v = *(const float4*)(x + (size_t)row * D_MODEL + tid * 4);
    float s = v.x + v.y + v.z + v.w;
    float ss = v.x * v.x + v.y * v.y + v.z * v.z + v.w * v.w;
    int lane = tid & 63, wv = tid >> 6;
    for (int o = 32; o; o >>= 1) { s += __shfl_xor(s, o); ss += __shfl_xor(ss, o); }
    __shared__ float rs[4], rss[4];
    if (lane == 0) { rs[wv] = s; rss[wv] = ss; }
    __syncthreads();
    float S = rs[0] + rs[1] + rs[2] + rs[3];
    float SS = rss[0] + rss[1] + rss[2] + rss[3];
    float mean = S * (1.f / D_MODEL);
    float var = SS * (1.f / D_MODEL) - mean * mean;
    float r = rsqrtf(var + 1e-5f);
    float4 gv = *(const float4*)(g + tid * 4);
    float4 bv = *(const float4*)(b + tid * 4);
    float4 o4;
    o4.x = (v.x - mean) * r * gv.x + bv.x;
    o4.y = (v.y - mean) * r * gv.y + bv.y;
    o4.z = (v.z - mean) * r * gv.z + bv.z;
    o4.w = (v.w - mean) * r * gv.w + bv.w;
    if (outf) *(float4*)(outf + (size_t)row * D_MODEL + tid * 4) = o4;
    if (outb) {
        ushort4 u4 = { f2bf(o4.x), f2bf(o4.y), f2bf(o4.z), f2bf(o4.w) };
        *(ushort4*)(outb + (size_t)row * D_MODEL + tid * 4) = u4;
    }
}

// ---------------- Weight convert + transpose: fp32 [K][N] -> bf16 [N][K] ----------------
__global__ __launch_bounds__(256) void wtrans_kernel(const float* __restrict__ in,
    unsigned short* __restrict__ out, int K, int N)
{
    __shared__ float t[32][33];
    int k0 = blockIdx.y * 32, n0 = blockIdx.x * 32;
    int tid = threadIdx.x;
    int r = tid >> 5, c = tid & 31;
#pragma unroll
    for (int p = 0; p < 4; ++p)
        t[r + p * 8][c] = in[(size_t)(k0 + r + p * 8) * N + n0 + c];
    __syncthreads();
#pragma unroll
    for (int p = 0; p < 4; ++p)
        out[(size_t)(n0 + r + p * 8) * K + k0 + c] = f2bf(t[c][r + p * 8]);
}

// ---------------- Pack indexer weights into one fp32 [1024][336] ----------------
__global__ __launch_bounds__(256) void wpack_kernel(const float* __restrict__ wq,
    const float* __restrict__ wk, const float* __restrict__ ww, float* __restrict__ Wc)
{
    int idx = blockIdx.x * 256 + threadIdx.x;
    if (idx >= D_MODEL * NIDX) return;
    int r = idx / NIDX, c = idx % NIDX;
    float v = 0.f;
    if (c < 256) v = wq[r * 256 + c];
    else if (c < 320) v = wk[r * 64 + (c - 256)];
    else if (c < 324) v = ww[r * 4 + (c - 320)];
    Wc[idx] = v;
}

// ---------------- bf16 MFMA GEMM (m97 structure): C = act(A @ Bt^T + bias) + R ----------------
// Split-K mode: if P != nullptr, block z computes K-chunk [z*kchunk, z*kchunk+kchunk)
// and writes raw fp32 partials to P + z*M*N (no epilogue).
__global__ __launch_bounds__(256) void gemm_bf16(
    const unsigned short* __restrict__ A, const unsigned short* __restrict__ Bt,
    float* __restrict__ C, unsigned short* __restrict__ Cb,
    const float* __restrict__ bias, const float* __restrict__ R,
    int M, int N, int K, int act,
    float* __restrict__ P, int kchunk)
{
    __shared__ __attribute__((aligned(16))) unsigned short As[128 * 32];
    __shared__ __attribute__((aligned(16))) unsigned short Bs[128 * 32];
    int tid = threadIdx.x;
    int bm = blockIdx.y * 128, bn = blockIdx.x * 128;
    int wid = tid >> 6, lane = tid & 63;
    int wm = (wid >> 1) * 64, wn = (wid & 1) * 64;
    const unsigned short* Ab = A + (size_t)bm * K;
    const unsigned short* Bb = Bt + (size_t)bn * K;
    f32x4 acc[4][4];
#pragma unroll
    for (int i = 0; i < 4; ++i)
#pragma unroll
        for (int j = 0; j < 4; ++j)
            acc[i][j] = (f32x4){0.f, 0.f, 0.f, 0.f};

    int kbeg = blockIdx.z * kchunk;
    int kend = kbeg + kchunk;
    int fr = lane & 15, fk = (lane >> 4) * 8;
    for (int k0 = kbeg; k0 < kend; k0 += 32) {
#pragma unroll
        for (int i = 0; i < 2; ++i) {
            int e = (i * 256 + tid) * 8;
            int r = e >> 5, c = e & 31;
            gl_lds16(Ab + (size_t)r * K + k0 + c, As + e);
            gl_lds16(Bb + (size_t)r * K + k0 + c, Bs + e);
        }
        __syncthreads();
        bf16x8 af[4], bfv[4];
#pragma unroll
        for (int mi = 0; mi < 4; ++mi)
            af[mi] = *(const bf16x8*)&As[(wm + mi * 16 + fr) * 32 + fk];
#pragma unroll
        for (int ni = 0; ni < 4; ++ni)
            bfv[ni] = *(const bf16x8*)&Bs[(wn + ni * 16 + fr) * 32 + fk];
#pragma unroll
        for (int mi = 0; mi < 4; ++mi)
#pragma unroll
            for (int ni = 0; ni < 4; ++ni)
                acc[mi][ni] = __builtin_amdgcn_mfma_f32_16x16x32_bf16(
                    af[mi], bfv[ni], acc[mi][ni], 0, 0, 0);
        __syncthreads();
    }
    int cl = lane & 15, rh = (lane >> 4) * 4;
    if (P) {
        float* Pz = P + (size_t)blockIdx.z * M * N;
#pragma unroll
        for (int mi = 0; mi < 4; ++mi)
#pragma unroll
            for (int ni = 0; ni < 4; ++ni) {
                int col = bn + wn + ni * 16 + cl;
#pragma unroll
                for (int r = 0; r < 4; ++r) {
                    int row = bm + wm + mi * 16 + rh + r;
                    Pz[(size_t)row * N + col] = acc[mi][ni][r];
                }
            }
        return;
    }
#pragma unroll
    for (int mi = 0; mi < 4; ++mi) {
#pragma unroll
        for (int ni = 0; ni < 4; ++ni) {
            int col = bn + wn + ni * 16 + cl;
            float bv = bias ? bias[col] : 0.f;
#pragma unroll
            for (int r = 0; r < 4; ++r) {
                int row = bm + wm + mi * 16 + rh + r;
                float v = acc[mi][ni][r] + bv;
                if (act) v = gelu_exact(v);
                size_t off = (size_t)row * N + col;
                if (R) v += R[off];
                if (C) C[off] = v;
                if (Cb) Cb[off] = f2bf(v);
            }
        }
    }
}

// ---------------- Split-K reduce: C = sum_z P[z] + bias + R (float4 vectorized) ----------------
__global__ __launch_bounds__(256) void kreduce_kernel(const float* __restrict__ P,
    int nslice, float* __restrict__ C, const float* __restrict__ bias,
    const float* __restrict__ R, int M, int N)
{
    size_t total4 = (size_t)M * N / 4;
    size_t stride = (size_t)gridDim.x * 256;
    for (size_t i4 = blockIdx.x * 256 + threadIdx.x; i4 < total4; i4 += stride) {
        size_t off = i4 * 4;
        float4 v = *(const float4*)(P + off);
        for (int z = 1; z < nslice; ++z) {
            float4 p = *(const float4*)(P + (size_t)z * M * N + off);
            v.x += p.x; v.y += p.y; v.z += p.z; v.w += p.w;
        }
        if (bias) {
            float4 b4 = *(const float4*)(bias + (off % N));
            v.x += b4.x; v.y += b4.y; v.z += b4.z; v.w += b4.w;
        }
        if (R) {
            float4 r4 = *(const float4*)(R + off);
            v.x += r4.x; v.y += r4.y; v.z += r4.z; v.w += r4.w;
        }
        *(float4*)(C + off) = v;
    }
}

// ---------------- Generic fp32 GEMM (indexer path): C[M,N] = A[M,K]@B[K,N] ----------------
__global__ __launch_bounds__(256) void gemm64(const float* __restrict__ A,
    const float* __restrict__ B, float* __restrict__ C,
    int M, int N, int K)
{
    __shared__ float As[16][68];
    __shared__ float Bs[16][68];
    int tid = threadIdx.x;
    int bm = blockIdx.y, bn = blockIdx.x;
    int tx = tid & 15, ty = tid >> 4;
    int arow = tid >> 2;
    int acol = (tid & 3) << 2;
    int brow = tid >> 4;
    int bcol = (tid & 15) << 2;
    const float* Abase = A + (size_t)(bm * 64 + arow) * K + acol;
    float c[4][4] = {};
    for (int k0 = 0; k0 < K; k0 += 16) {
        float4 av = *(const float4*)(Abase + k0);
        As[acol + 0][arow] = av.x;
        As[acol + 1][arow] = av.y;
        As[acol + 2][arow] = av.z;
        As[acol + 3][arow] = av.w;
        int gcol = bn * 64 + bcol;
        const float* Bb = B + (size_t)(k0 + brow) * N;
        float4 bv;
        if (gcol + 3 < N) {
            bv = *(const float4*)(Bb + gcol);
        } else {
            bv.x = (gcol + 0 < N) ? Bb[gcol + 0] : 0.f;
            bv.y = (gcol + 1 < N) ? Bb[gcol + 1] : 0.f;
            bv.z = (gcol + 2 < N) ? Bb[gcol + 2] : 0.f;
            bv.w = (gcol + 3 < N) ? Bb[gcol + 3] : 0.f;
        }
        *(float4*)&Bs[brow][bcol] = bv;
        __syncthreads();
#pragma unroll
        for (int kk = 0; kk < 16; ++kk) {
            float4 a4 = *(const float4*)&As[kk][ty * 4];
            float4 b4 = *(const float4*)&Bs[kk][tx * 4];
            float av4[4] = { a4.x, a4.y, a4.z, a4.w };
            float bv4[4] = { b4.x, b4.y, b4.z, b4.w };
#pragma unroll
            for (int i = 0; i < 4; ++i)
#pragma unroll
                for (int j = 0; j < 4; ++j)
                    c[i][j] += av4[i] * bv4[j];
        }
        __syncthreads();
    }
#pragma unroll
    for (int i = 0; i < 4; ++i) {
        int row = bm * 64 + ty * 4 + i;
#pragma unroll
        for (int j = 0; j < 4; ++j) {
            int col = bn * 64 + tx * 4 + j;
            if (col < N)
                C[(size_t)row * N + col] = c[i][j];
        }
    }
}

// ---------------- RoPE table ----------------
__global__ __launch_bounds__(256) void rope_table_kernel(float* __restrict__ ct, float* __restrict__ st)
{
    int g = blockIdx.x * 256 + threadIdx.x;
    int t = g >> 5, i = g & 31;
    float theta = powf(10000.f, -(float)i / 32.f);
    float ang = (float)t * theta;
    ct[g] = cosf(ang);
    st[g] = sinf(ang);
}

// ---------------- RoPE + pack: qkv bf16 [S][3072] -> Qb [S][1024], Kb/Vb [H][S][64] ----------------
__global__ __launch_bounds__(512) void rope_pack_kernel(
    const unsigned short* __restrict__ qkvb,
    const float* __restrict__ ct, const float* __restrict__ st,
    unsigned short* __restrict__ Qb, unsigned short* __restrict__ Kb,
    unsigned short* __restrict__ Vb)
{
    int t = blockIdx.x, tid = threadIdx.x;
    int h = tid >> 5, i = tid & 31;
    float c = ct[t * 32 + i], s = st[t * 32 + i];
    const unsigned short* base = qkvb + (size_t)t * (3 * D_MODEL);
    ushort2 q2 = *(const ushort2*)(base + h * HDIM + 2 * i);
    float q0 = bf2f(q2.x), q1 = bf2f(q2.y);
    ushort2 qo = { f2bf(q0 * c - q1 * s), f2bf(q1 * c + q0 * s) };
    *(ushort2*)(Qb + (size_t)t * D_MODEL + h * HDIM + 2 * i) = qo;
    ushort2 k2 = *(const ushort2*)(base + D_MODEL + h * HDIM + 2 * i);
    float k0 = bf2f(k2.x), k1 = bf2f(k2.y);
    ushort2 ko = { f2bf(k0 * c - k1 * s), f2bf(k1 * c + k0 * s) };
    *(ushort2*)(Kb + ((size_t)h * S_LEN + t) * HDIM + 2 * i) = ko;
    ushort2 v2 = *(const ushort2*)(base + 2 * D_MODEL + 2 * tid);
    int vh = tid >> 5, vd = (2 * tid) & 63;
    *(ushort2*)(Vb + ((size_t)vh * S_LEN + t) * HDIM + vd) = v2;
}

// ---------------- Indexer scores (fp32, fused QIW layout, stride 336) ----------------
__global__ __launch_bounds__(256) void scores_kernel(const float* __restrict__ QIW,
    float* __restrict__ scores)
{
    int t0 = blockIdx.y * 32, s0 = blockIdx.x * 32;
    if (s0 > t0 + 31) return;
    __shared__ float qis[32][256];
    __shared__ float kis[32][65];
    __shared__ float wis[32][4];
    int tid = threadIdx.x;
#pragma unroll
    for (int l = 0; l < 8; ++l) {
        int idx = l * 256 + tid;
        int r = idx >> 6, c = (idx & 63) << 2;
        *(float4*)&qis[r][c] = *(const float4*)(QIW + (size_t)(t0 + r) * NIDX + c);
    }
#pragma unroll
    for (int l = 0; l < 8; ++l) {
        int idx = l * 256 + tid;
        int r = idx >> 6, c = idx & 63;
        kis[r][c] = QIW[(size_t)(s0 + r) * NIDX + 256 + c];
    }
    if (tid < 32) *(float4*)&wis[tid][0] = *(const float4*)(QIW + (size_t)(t0 + tid) * NIDX + 320);
    __syncthreads();
    int sl = tid & 31;
    int tb = (tid >> 5) * 4;
    float acc[4] = { 0.f, 0.f, 0.f, 0.f };
#pragma unroll
    for (int h = 0; h < 4; ++h) {
        float dots[4] = { 0.f, 0.f, 0.f, 0.f };
        for (int d = 0; d < 64; ++d) {
            float kv = kis[sl][d];
#pragma unroll
            for (int i = 0; i < 4; ++i)
                dots[i] += qis[tb + i][h * 64 + d] * kv;
        }
#pragma unroll
        for (int i = 0; i < 4; ++i)
            acc[i] += wis[tb + i][h] * fmaxf(dots[i], 0.f);
    }
#pragma unroll
    for (int i = 0; i < 4; ++i)
        scores[(size_t)(t0 + tb + i) * S_LEN + s0 + sl] = acc[i];
}

// ---------------- Top-K via radix select (exact lax.top_k set semantics) ----------------
__global__ __launch_bounds__(256) void topk_kernel(const float* __restrict__ scores,
    int* __restrict__ topidx, int* __restrict__ topcnt)
{
    int t = blockIdx.x, tid = threadIdx.x;
    int n = t + 1;
    if (n <= TOPK) {
        if (tid < n) topidx[t * TOPK + tid] = tid;
        if (tid == 0) topcnt[t] = n;
        return;
    }
    __shared__ unsigned sc[S_LEN];
    __shared__ unsigned hist[256];
    __shared__ int selbin_s;
    __shared__ int cnt_out;
    __shared__ unsigned wsum[4];
    for (int j = tid; j < n; j += 256) {
        unsigned u = __builtin_bit_cast(unsigned, scores[(size_t)t * S_LEN + j]);
        sc[j] = (u & 0x80000000u) ? ~u : (u | 0x80000000u);
    }
    if (tid == 0) cnt_out = 0;
    int lane = tid & 63, wv = tid >> 6;
    unsigned prefix = 0;
    int kk = TOPK;
#pragma unroll
    for (int round = 0; round < 4; ++round) {
        int shift_pref = 32 - 8 * round;
        int shift_bin = 24 - 8 * round;
        hist[tid] = 0;
        __syncthreads();
        for (int j = tid; j < n; j += 256) {
            unsigned v = sc[j];
            if ((((unsigned long long)(v ^ prefix)) >> shift_pref) == 0)
                atomicAdd(&hist[(v >> shift_bin) & 0xff], 1u);
        }
        __syncthreads();
        if (wv == 0) {
            unsigned h0 = hist[4 * lane], h1 = hist[4 * lane + 1];
            unsigned h2 = hist[4 * lane + 2], h3 = hist[4 * lane + 3];
            unsigned s3 = h3, s2 = h2 + s3, s1 = h1 + s2, s0 = h0 + s1;
            unsigned acc = s0;
            for (int off = 1; off < 64; off <<= 1) {
                unsigned o = __shfl_down(acc, off);
                if (lane + off < 64) acc += o;
            }
            unsigned above = acc - s0;
            hist[4 * lane]     = s0 + above;
            hist[4 * lane + 1] = s1 + above;
            hist[4 * lane + 2] = s2 + above;
            hist[4 * lane + 3] = s3 + above;
        }
        __syncthreads();
        {
            unsigned sufb = hist[tid];
            unsigned sufn = (tid < 255) ? hist[tid + 1] : 0u;
            if (sufb >= (unsigned)kk && sufn < (unsigned)kk)
                selbin_s = tid;
        }
        __syncthreads();
        int b = selbin_s;
        unsigned above = (b < 255) ? hist[b + 1] : 0u;
        kk -= (int)above;
        prefix |= ((unsigned)b) << shift_bin;
        __syncthreads();
    }
    unsigned T = prefix;
    int chunk = (n + 255) >> 8;
    int jb = tid * chunk;
    int je = jb + chunk; if (je > n) je = n;
    int ties = 0;
    for (int j = jb; j < je; ++j) {
        unsigned v = sc[j];
        if (v > T) { int o = atomicAdd(&cnt_out, 1); topidx[t * TOPK + o] = j; }
        else if (v == T) ++ties;
    }
    unsigned inc = (unsigned)ties;
    for (int off = 1; off < 64; off <<= 1) {
        unsigned o = __shfl_up(inc, off);
        if (lane >= off) inc += o;
    }
    if (lane == 63) wsum[wv] = inc;
    __syncthreads();
    unsigned woff = 0;
    for (int w = 0; w < wv; ++w) woff += wsum[w];
    int rank = (int)(woff + inc) - ties;
    for (int j = jb; j < je && rank < kk; ++j) {
        if (sc[j] == T) {
            int o = atomicAdd(&cnt_out, 1);
            topidx[t * TOPK + o] = j;
            ++rank;
        }
    }
    if (tid == 0) topcnt[t] = TOPK;
}

// ---------------- Sparse SDPA v3: lane = (key, dim-octet) -> coalesced 8-row gathers ----------------
// Each gather instruction loads 8 full contiguous K/V rows (1KB, 16 lines) instead of
// 64 scattered 16B slices (64 lines). Dot reduce over oct (xor 1,2,4); softmax over
// klo (xor 8,16,32); PV accumulates f32x8 per lane then reduces over klo.
__global__ __launch_bounds__(256) void attn_kernel(
    const unsigned short* __restrict__ Qb, const unsigned short* __restrict__ Kb,
    const unsigned short* __restrict__ Vb,
    const int* __restrict__ topidx, const int* __restrict__ topcnt,
    unsigned short* __restrict__ out)
{
    int t = blockIdx.x, tid = threadIdx.x;
    __shared__ unsigned short qls[D_MODEL];
    __shared__ int sel[TOPK];
    *(ushort4*)(qls + tid * 4) = *(const ushort4*)(Qb + (size_t)t * D_MODEL + tid * 4);
    if (tid < TOPK) sel[tid] = topidx[t * TOPK + tid];
    __syncthreads();
    int cnt = topcnt[t];
    int lane = tid & 63, wv = tid >> 6;
    int klo = lane >> 3, oct = lane & 7;
    // this lane's key row per key-group (shared by dot & PV phases)
    int rows[8];
    bool valid[8];
#pragma unroll
    for (int kg = 0; kg < 8; ++kg) {
        int k = kg * 8 + klo;
        valid[kg] = (k < cnt);
        rows[kg] = sel[valid[kg] ? k : 0];
    }
#pragma unroll
    for (int hh = 0; hh < 4; ++hh) {
        int h = wv * 4 + hh;
        bf16x8 q8 = *(const bf16x8*)(qls + h * HDIM + oct * 8);
        const unsigned short* kbase = Kb + (size_t)h * S_LEN * HDIM + oct * 8;
        float p[8];
#pragma unroll
        for (int kg = 0; kg < 8; ++kg) {
            bf16x8 k8 = *(const bf16x8*)(kbase + (size_t)rows[kg] * HDIM);
            float d = 0.f;
#pragma unroll
            for (int e = 0; e < 8; ++e)
                d += bf2f((unsigned short)k8[e]) * bf2f((unsigned short)q8[e]);
            d += __shfl_xor(d, 1);
            d += __shfl_xor(d, 2);
            d += __shfl_xor(d, 4);
            p[kg] = valid[kg] ? d * 0.125f : -INFINITY;
        }
        float m = p[0];
#pragma unroll
        for (int kg = 1; kg < 8; ++kg) m = fmaxf(m, p[kg]);
        m = fmaxf(m, __shfl_xor(m, 8));
        m = fmaxf(m, __shfl_xor(m, 16));
        m = fmaxf(m, __shfl_xor(m, 32));
        float sum = 0.f;
#pragma unroll
        for (int kg = 0; kg < 8; ++kg) { p[kg] = __expf(p[kg] - m); sum += p[kg]; }
        sum += __shfl_xor(sum, 8);
        sum += __shfl_xor(sum, 16);
        sum += __shfl_xor(sum, 32);
        float rs = 1.f / sum;
        const unsigned short* vbase = Vb + (size_t)h * S_LEN * HDIM + oct * 8;
        float facc[8] = {};
#pragma unroll
        for (int kg = 0; kg < 8; ++kg) {
            bf16x8 v8 = *(const bf16x8*)(vbase + (size_t)rows[kg] * HDIM);
            float pw = p[kg] * rs;
#pragma unroll
            for (int e = 0; e < 8; ++e)
                facc[e] += pw * bf2f((unsigned short)v8[e]);
        }
#pragma unroll
        for (int e = 0; e < 8; ++e) {
            facc[e] += __shfl_xor(facc[e], 8);
            facc[e] += __shfl_xor(facc[e], 16);
            facc[e] += __shfl_xor(facc[e], 32);
        }
        if (klo == 0) {
            ushort4 o0 = { f2bf(facc[0]), f2bf(facc[1]), f2bf(facc[2]), f2bf(facc[3]) };
            ushort4 o1 = { f2bf(facc[4]), f2bf(facc[5]), f2bf(facc[6]), f2bf(facc[7]) };
            *(ushort4*)(out + (size_t)t * D_MODEL + h * HDIM + oct * 8) = o0;
            *(ushort4*)(out + (size_t)t * D_MODEL + h * HDIM + oct * 8 + 4) = o1;
        }
    }
}

extern "C" void kernel_launch(void* const* d_in, const int* in_sizes, int n_in,
                              void* d_out, int out_size, void* d_ws, size_t ws_size,
                              hipStream_t stream)
{
    const float* x      = (const float*)d_in[0];
    const float* w_qkv  = (const float*)d_in[1];
    const float* w_o    = (const float*)d_in[2];
    const float* ffn_w1 = (const float*)d_in[3];
    const float* ffn_b1 = (const float*)d_in[4];
    const float* ffn_w2 = (const float*)d_in[5];
    const float* ffn_b2 = (const float*)d_in[6];
    const float* ln1_g  = (const float*)d_in[7];
    const float* ln1_b  = (const float*)d_in[8];
    const float* ln2_g  = (const float*)d_in[9];
    const float* ln2_b  = (const float*)d_in[10];
    const float* idx_wq = (const float*)d_in[11];
    const float* idx_wk = (const float*)d_in[12];
    const float* idx_ww = (const float*)d_in[13];
    float* outp = (float*)d_out;

    const size_t MB = 1ull << 20;
    char* ws = (char*)d_ws;
    float*          normx    = (float*)(ws + 0);
    unsigned short* attno_bf = (unsigned short*)(ws + 0);
    float*          Pf2      = (float*)(ws + 0);            // 32MB ffn2 partials (4 slices)
    unsigned short* normx_bf = (unsigned short*)(ws + 8 * MB);
    unsigned short* h2_bf    = normx_bf;
    unsigned short* qkv_bf   = (unsigned short*)(ws + 12 * MB);
    int*            topidx   = (int*)(ws + 12 * MB);
    int*            topcnt   = (int*)(ws + 12 * MB + 512 * 1024);
    unsigned short* wqkv_t   = (unsigned short*)(ws + 24 * MB);
    unsigned short* wo_t     = (unsigned short*)(ws + 30 * MB);
    unsigned short* w1_t     = (unsigned short*)(ws + 32 * MB);
    unsigned short* w2_t     = (unsigned short*)(ws + 40 * MB);
    unsigned short* Qb       = (unsigned short*)(ws + 48 * MB);
    unsigned short* Kb       = (unsigned short*)(ws + 52 * MB);
    unsigned short* Vb       = (unsigned short*)(ws + 56 * MB);
    float*          ctab     = (float*)(ws + 60 * MB);
    float*          stab     = (float*)(ws + 60 * MB + 256 * 1024);
    float*          scoresb  = (float*)(ws + 60 * MB);
    float*          Pwo      = (float*)(ws + 60 * MB);      // 16MB w_o partials (2 slices)
    unsigned short* ffn1_bf  = (unsigned short*)(ws + 60 * MB);
    float*          QIW      = (float*)(ws + 76 * MB);
    float*          Wc       = (float*)(ws + 79 * MB);

    dim3 blk256(256);
    auto g128 = [](int N, int M) { return dim3(N / 128, M / 128); };

    // 1. LN1 -> fp32 (indexer) + bf16 (qkv gemm)
    ln_kernel<<<S_LEN, blk256, 0, stream>>>(x, ln1_g, ln1_b, normx, normx_bf);
    // 2. rope tables + weight prep
    rope_table_kernel<<<(S_LEN * 32) / 256, blk256, 0, stream>>>(ctab, stab);
    wtrans_kernel<<<dim3(3 * D_MODEL / 32, D_MODEL / 32), blk256, 0, stream>>>(w_qkv, wqkv_t, D_MODEL, 3 * D_MODEL);
    wtrans_kernel<<<dim3(D_MODEL / 32, D_MODEL / 32), blk256, 0, stream>>>(w_o, wo_t, D_MODEL, D_MODEL);
    wtrans_kernel<<<dim3(DFF / 32, D_MODEL / 32), blk256, 0, stream>>>(ffn_w1, w1_t, D_MODEL, DFF);
    wtrans_kernel<<<dim3(D_MODEL / 32, DFF / 32), blk256, 0, stream>>>(ffn_w2, w2_t, DFF, D_MODEL);
    wpack_kernel<<<(D_MODEL * NIDX + 255) / 256, blk256, 0, stream>>>(idx_wq, idx_wk, idx_ww, Wc);
    // 3. qkv = norm_x @ w_qkv (bf16 out only; 384 blocks)
    gemm_bf16<<<g128(3 * D_MODEL, S_LEN), blk256, 0, stream>>>(normx_bf, wqkv_t,
        nullptr, qkv_bf, nullptr, nullptr, S_LEN, 3 * D_MODEL, D_MODEL, 0, nullptr, D_MODEL);
    // 4. fused indexer projections (fp32 — feeds discrete top-k)
    gemm64<<<dim3((NIDX + 63) / 64, S_LEN / 64), blk256, 0, stream>>>(normx, Wc, QIW, S_LEN, NIDX, D_MODEL);
    // 5. RoPE + pack Q/K/V (bf16, K/V head-major)
    rope_pack_kernel<<<S_LEN, dim3(512), 0, stream>>>(qkv_bf, ctab, stab, Qb, Kb, Vb);
    // 6. indexer scores (overwrites ctab region — rope_pack already done)
    scores_kernel<<<dim3(64, 64), blk256, 0, stream>>>(QIW, scoresb);
    // 7. top-64 per row (radix select; topidx overlays dead qkv_bf)
    topk_kernel<<<S_LEN, blk256, 0, stream>>>(scoresb, topidx, topcnt);
    // 8. sparse attention -> bf16 (overlays dead normx)
    attn_kernel<<<S_LEN, blk256, 0, stream>>>(Qb, Kb, Vb, topidx, topcnt, attno_bf);
    // 9. x1 = x + attn_out @ w_o  — split-K=2 (256 blocks) into Pwo, then reduce
    gemm_bf16<<<dim3(D_MODEL / 128, S_LEN / 128, 2), blk256, 0, stream>>>(attno_bf, wo_t,
        nullptr, nullptr, nullptr, nullptr, S_LEN, D_MODEL, D_MODEL, 0, Pwo, D_MODEL / 2);
    kreduce_kernel<<<1024, blk256, 0, stream>>>(Pwo, 2, outp, nullptr, x, S_LEN, D_MODEL);
    // 10. h = LN2(x1) -> bf16
    ln_kernel<<<S_LEN, blk256, 0, stream>>>(outp, ln2_g, ln2_b, nullptr, h2_bf);
    // 11. ffn1 = gelu(h @ w1 + b1) -> bf16 (overlays dead Pwo/scoresb; 512 blocks)
    gemm_bf16<<<g128(DFF, S_LEN), blk256, 0, stream>>>(h2_bf, w1_t,
        nullptr, ffn1_bf, ffn_b1, nullptr, S_LEN, DFF, D_MODEL, 1, nullptr, D_MODEL);
    // 12. out = x1 + ffn1 @ w2 + b2 — split-K=4 (512 blocks) into Pf2, then reduce
    gemm_bf16<<<dim3(D_MODEL / 128, S_LEN / 128, 4), blk256, 0, stream>>>(ffn1_bf, w2_t,
        nullptr, nullptr, nullptr, nullptr, S_LEN, D_MODEL, DFF, 0, Pf2, DFF / 4);
    kreduce_kernel<<<1024, blk256, 0, stream>>>(Pf2, 4, outp, ffn_b2, outp, S_LEN, D_MODEL);
}

// Round 7
// 324.795 us; speedup vs baseline: 4.1637x; 1.0996x over previous
//
#include <hip/hip_runtime.h>
#include <math.h>

#define S_LEN 2048
#define D_MODEL 1024
#define NHEAD 16
#define HDIM 64
#define DFF 4096
#define IH 4
#define IDM 64
#define TOPK 64
#define NIDX 336   // 256 qi + 64 ki + 4 wi + 12 pad

typedef float f32x4 __attribute__((ext_vector_type(4)));
typedef short bf16x8 __attribute__((ext_vector_type(8)));

__device__ __forceinline__ unsigned short f2bf(float f) {
    unsigned u = __builtin_bit_cast(unsigned, f);
    u += 0x7fff + ((u >> 16) & 1);
    return (unsigned short)(u >> 16);
}
__device__ __forceinline__ float bf2f(unsigned short us) {
    return __builtin_bit_cast(float, (unsigned)us << 16);
}

__device__ __forceinline__ float gelu_exact(float v) {
    return 0.5f * v * (1.f + erff(v * 0.70710678118654752f));
}

__device__ __forceinline__ void gl_lds16(const void* g, void* l) {
    __builtin_amdgcn_global_load_lds(
        (const __attribute__((address_space(1))) void*)g,
        (__attribute__((address_space(3))) void*)l, 16, 0, 0);
}

// ---------------- LayerNorm: fp32 out (optional) + bf16 out (optional) ----------------
__global__ __launch_bounds__(256) void ln_kernel(const float* __restrict__ x,
    const float* __restrict__ g, const float* __restrict__ b,
    float* __restrict__ outf, unsigned short* __restrict__ outb)
{
    int row = blockIdx.x, tid = threadIdx.x;
    const float4 v = *(const float4*)(x + (size_t)row * D_MODEL + tid * 4);
    float s = v.x + v.y + v.z + v.w;
    float ss = v.x * v.x + v.y * v.y + v.z * v.z + v.w * v.w;
    int lane = tid & 63, wv = tid >> 6;
    for (int o = 32; o; o >>= 1) { s += __shfl_xor(s, o); ss += __shfl_xor(ss, o); }
    __shared__ float rs[4], rss[4];
    if (lane == 0) { rs[wv] = s; rss[wv] = ss; }
    __syncthreads();
    float S = rs[0] + rs[1] + rs[2] + rs[3];
    float SS = rss[0] + rss[1] + rss[2] + rss[3];
    float mean = S * (1.f / D_MODEL);
    float var = SS * (1.f / D_MODEL) - mean * mean;
    float r = rsqrtf(var + 1e-5f);
    float4 gv = *(const float4*)(g + tid * 4);
    float4 bv = *(const float4*)(b + tid * 4);
    float4 o4;
    o4.x = (v.x - mean) * r * gv.x + bv.x;
    o4.y = (v.y - mean) * r * gv.y + bv.y;
    o4.z = (v.z - mean) * r * gv.z + bv.z;
    o4.w = (v.w - mean) * r * gv.w + bv.w;
    if (outf) *(float4*)(outf + (size_t)row * D_MODEL + tid * 4) = o4;
    if (outb) {
        ushort4 u4 = { f2bf(o4.x), f2bf(o4.y), f2bf(o4.z), f2bf(o4.w) };
        *(ushort4*)(outb + (size_t)row * D_MODEL + tid * 4) = u4;
    }
}

// ---------------- Weight convert + transpose: fp32 [K][N] -> bf16 [N][K] ----------------
__global__ __launch_bounds__(256) void wtrans_kernel(const float* __restrict__ in,
    unsigned short* __restrict__ out, int K, int N)
{
    __shared__ float t[32][33];
    int k0 = blockIdx.y * 32, n0 = blockIdx.x * 32;
    int tid = threadIdx.x;
    int r = tid >> 5, c = tid & 31;
#pragma unroll
    for (int p = 0; p < 4; ++p)
        t[r + p * 8][c] = in[(size_t)(k0 + r + p * 8) * N + n0 + c];
    __syncthreads();
#pragma unroll
    for (int p = 0; p < 4; ++p)
        out[(size_t)(n0 + r + p * 8) * K + k0 + c] = f2bf(t[c][r + p * 8]);
}

// ---------------- Pack indexer weights into one fp32 [1024][336] ----------------
__global__ __launch_bounds__(256) void wpack_kernel(const float* __restrict__ wq,
    const float* __restrict__ wk, const float* __restrict__ ww, float* __restrict__ Wc)
{
    int idx = blockIdx.x * 256 + threadIdx.x;
    if (idx >= D_MODEL * NIDX) return;
    int r = idx / NIDX, c = idx % NIDX;
    float v = 0.f;
    if (c < 256) v = wq[r * 256 + c];
    else if (c < 320) v = wk[r * 64 + (c - 256)];
    else if (c < 324) v = ww[r * 4 + (c - 320)];
    Wc[idx] = v;
}

// ---------------- bf16 MFMA GEMM (m97 structure): C = act(A @ Bt^T + bias) + R ----------------
// Split-K mode: if P != nullptr, block z computes K-chunk [z*kchunk, z*kchunk+kchunk)
// and writes raw fp32 partials to P + z*M*N (no epilogue).
__global__ __launch_bounds__(256) void gemm_bf16(
    const unsigned short* __restrict__ A, const unsigned short* __restrict__ Bt,
    float* __restrict__ C, unsigned short* __restrict__ Cb,
    const float* __restrict__ bias, const float* __restrict__ R,
    int M, int N, int K, int act,
    float* __restrict__ P, int kchunk)
{
    __shared__ __attribute__((aligned(16))) unsigned short As[128 * 32];
    __shared__ __attribute__((aligned(16))) unsigned short Bs[128 * 32];
    int tid = threadIdx.x;
    int bm = blockIdx.y * 128, bn = blockIdx.x * 128;
    int wid = tid >> 6, lane = tid & 63;
    int wm = (wid >> 1) * 64, wn = (wid & 1) * 64;
    const unsigned short* Ab = A + (size_t)bm * K;
    const unsigned short* Bb = Bt + (size_t)bn * K;
    f32x4 acc[4][4];
#pragma unroll
    for (int i = 0; i < 4; ++i)
#pragma unroll
        for (int j = 0; j < 4; ++j)
            acc[i][j] = (f32x4){0.f, 0.f, 0.f, 0.f};

    int kbeg = blockIdx.z * kchunk;
    int kend = kbeg + kchunk;
    int fr = lane & 15, fk = (lane >> 4) * 8;
    for (int k0 = kbeg; k0 < kend; k0 += 32) {
#pragma unroll
        for (int i = 0; i < 2; ++i) {
            int e = (i * 256 + tid) * 8;
            int r = e >> 5, c = e & 31;
            gl_lds16(Ab + (size_t)r * K + k0 + c, As + e);
            gl_lds16(Bb + (size_t)r * K + k0 + c, Bs + e);
        }
        __syncthreads();
        bf16x8 af[4], bfv[4];
#pragma unroll
        for (int mi = 0; mi < 4; ++mi)
            af[mi] = *(const bf16x8*)&As[(wm + mi * 16 + fr) * 32 + fk];
#pragma unroll
        for (int ni = 0; ni < 4; ++ni)
            bfv[ni] = *(const bf16x8*)&Bs[(wn + ni * 16 + fr) * 32 + fk];
#pragma unroll
        for (int mi = 0; mi < 4; ++mi)
#pragma unroll
            for (int ni = 0; ni < 4; ++ni)
                acc[mi][ni] = __builtin_amdgcn_mfma_f32_16x16x32_bf16(
                    af[mi], bfv[ni], acc[mi][ni], 0, 0, 0);
        __syncthreads();
    }
    int cl = lane & 15, rh = (lane >> 4) * 4;
    if (P) {
        float* Pz = P + (size_t)blockIdx.z * M * N;
#pragma unroll
        for (int mi = 0; mi < 4; ++mi)
#pragma unroll
            for (int ni = 0; ni < 4; ++ni) {
                int col = bn + wn + ni * 16 + cl;
#pragma unroll
                for (int r = 0; r < 4; ++r) {
                    int row = bm + wm + mi * 16 + rh + r;
                    Pz[(size_t)row * N + col] = acc[mi][ni][r];
                }
            }
        return;
    }
#pragma unroll
    for (int mi = 0; mi < 4; ++mi) {
#pragma unroll
        for (int ni = 0; ni < 4; ++ni) {
            int col = bn + wn + ni * 16 + cl;
            float bv = bias ? bias[col] : 0.f;
#pragma unroll
            for (int r = 0; r < 4; ++r) {
                int row = bm + wm + mi * 16 + rh + r;
                float v = acc[mi][ni][r] + bv;
                if (act) v = gelu_exact(v);
                size_t off = (size_t)row * N + col;
                if (R) v += R[off];
                if (C) C[off] = v;
                if (Cb) Cb[off] = f2bf(v);
            }
        }
    }
}

// ---------------- Split-K reduce: C = sum_z P[z] + bias + R (float4 vectorized) ----------------
__global__ __launch_bounds__(256) void kreduce_kernel(const float* __restrict__ P,
    int nslice, float* __restrict__ C, const float* __restrict__ bias,
    const float* __restrict__ R, int M, int N)
{
    size_t total4 = (size_t)M * N / 4;
    size_t stride = (size_t)gridDim.x * 256;
    for (size_t i4 = blockIdx.x * 256 + threadIdx.x; i4 < total4; i4 += stride) {
        size_t off = i4 * 4;
        float4 v = *(const float4*)(P + off);
        for (int z = 1; z < nslice; ++z) {
            float4 p = *(const float4*)(P + (size_t)z * M * N + off);
            v.x += p.x; v.y += p.y; v.z += p.z; v.w += p.w;
        }
        if (bias) {
            float4 b4 = *(const float4*)(bias + (off % N));
            v.x += b4.x; v.y += b4.y; v.z += b4.z; v.w += b4.w;
        }
        if (R) {
            float4 r4 = *(const float4*)(R + off);
            v.x += r4.x; v.y += r4.y; v.z += r4.z; v.w += r4.w;
        }
        *(float4*)(C + off) = v;
    }
}

// ---------------- Generic fp32 GEMM (indexer path): C[M,N] = A[M,K]@B[K,N] ----------------
// Split-K: if P != nullptr, block z does K-chunk [z*kchunk, (z+1)*kchunk) -> P + z*M*N.
__global__ __launch_bounds__(256) void gemm64(const float* __restrict__ A,
    const float* __restrict__ B, float* __restrict__ C,
    int M, int N, int K,
    float* __restrict__ P, int kchunk)
{
    __shared__ float As[16][68];
    __shared__ float Bs[16][68];
    int tid = threadIdx.x;
    int bm = blockIdx.y, bn = blockIdx.x;
    int tx = tid & 15, ty = tid >> 4;
    int arow = tid >> 2;
    int acol = (tid & 3) << 2;
    int brow = tid >> 4;
    int bcol = (tid & 15) << 2;
    const float* Abase = A + (size_t)(bm * 64 + arow) * K + acol;
    float c[4][4] = {};
    int kbeg = blockIdx.z * kchunk;
    int kend = kbeg + kchunk;
    for (int k0 = kbeg; k0 < kend; k0 += 16) {
        float4 av = *(const float4*)(Abase + k0);
        As[acol + 0][arow] = av.x;
        As[acol + 1][arow] = av.y;
        As[acol + 2][arow] = av.z;
        As[acol + 3][arow] = av.w;
        int gcol = bn * 64 + bcol;
        const float* Bb = B + (size_t)(k0 + brow) * N;
        float4 bv;
        if (gcol + 3 < N) {
            bv = *(const float4*)(Bb + gcol);
        } else {
            bv.x = (gcol + 0 < N) ? Bb[gcol + 0] : 0.f;
            bv.y = (gcol + 1 < N) ? Bb[gcol + 1] : 0.f;
            bv.z = (gcol + 2 < N) ? Bb[gcol + 2] : 0.f;
            bv.w = (gcol + 3 < N) ? Bb[gcol + 3] : 0.f;
        }
        *(float4*)&Bs[brow][bcol] = bv;
        __syncthreads();
#pragma unroll
        for (int kk = 0; kk < 16; ++kk) {
            float4 a4 = *(const float4*)&As[kk][ty * 4];
            float4 b4 = *(const float4*)&Bs[kk][tx * 4];
            float av4[4] = { a4.x, a4.y, a4.z, a4.w };
            float bv4[4] = { b4.x, b4.y, b4.z, b4.w };
#pragma unroll
            for (int i = 0; i < 4; ++i)
#pragma unroll
                for (int j = 0; j < 4; ++j)
                    c[i][j] += av4[i] * bv4[j];
        }
        __syncthreads();
    }
    float* Out = P ? (P + (size_t)blockIdx.z * M * N) : C;
#pragma unroll
    for (int i = 0; i < 4; ++i) {
        int row = bm * 64 + ty * 4 + i;
#pragma unroll
        for (int j = 0; j < 4; ++j) {
            int col = bn * 64 + tx * 4 + j;
            if (col < N)
                Out[(size_t)row * N + col] = c[i][j];
        }
    }
}

// ---------------- RoPE table ----------------
__global__ __launch_bounds__(256) void rope_table_kernel(float* __restrict__ ct, float* __restrict__ st)
{
    int g = blockIdx.x * 256 + threadIdx.x;
    int t = g >> 5, i = g & 31;
    float theta = powf(10000.f, -(float)i / 32.f);
    float ang = (float)t * theta;
    ct[g] = cosf(ang);
    st[g] = sinf(ang);
}

// ---------------- RoPE + pack: qkv bf16 [S][3072] -> Qb [S][1024], Kb/Vb [H][S][64] ----------------
__global__ __launch_bounds__(512) void rope_pack_kernel(
    const unsigned short* __restrict__ qkvb,
    const float* __restrict__ ct, const float* __restrict__ st,
    unsigned short* __restrict__ Qb, unsigned short* __restrict__ Kb,
    unsigned short* __restrict__ Vb)
{
    int t = blockIdx.x, tid = threadIdx.x;
    int h = tid >> 5, i = tid & 31;
    float c = ct[t * 32 + i], s = st[t * 32 + i];
    const unsigned short* base = qkvb + (size_t)t * (3 * D_MODEL);
    ushort2 q2 = *(const ushort2*)(base + h * HDIM + 2 * i);
    float q0 = bf2f(q2.x), q1 = bf2f(q2.y);
    ushort2 qo = { f2bf(q0 * c - q1 * s), f2bf(q1 * c + q0 * s) };
    *(ushort2*)(Qb + (size_t)t * D_MODEL + h * HDIM + 2 * i) = qo;
    ushort2 k2 = *(const ushort2*)(base + D_MODEL + h * HDIM + 2 * i);
    float k0 = bf2f(k2.x), k1 = bf2f(k2.y);
    ushort2 ko = { f2bf(k0 * c - k1 * s), f2bf(k1 * c + k0 * s) };
    *(ushort2*)(Kb + ((size_t)h * S_LEN + t) * HDIM + 2 * i) = ko;
    ushort2 v2 = *(const ushort2*)(base + 2 * D_MODEL + 2 * tid);
    int vh = tid >> 5, vd = (2 * tid) & 63;
    *(ushort2*)(Vb + ((size_t)vh * S_LEN + t) * HDIM + vd) = v2;
}

// ---------------- Indexer scores (fp32, fused QIW layout, stride 336) ----------------
__global__ __launch_bounds__(256) void scores_kernel(const float* __restrict__ QIW,
    float* __restrict__ scores)
{
    int t0 = blockIdx.y * 32, s0 = blockIdx.x * 32;
    if (s0 > t0 + 31) return;
    __shared__ float qis[32][256];
    __shared__ float kis[32][65];
    __shared__ float wis[32][4];
    int tid = threadIdx.x;
#pragma unroll
    for (int l = 0; l < 8; ++l) {
        int idx = l * 256 + tid;
        int r = idx >> 6, c = (idx & 63) << 2;
        *(float4*)&qis[r][c] = *(const float4*)(QIW + (size_t)(t0 + r) * NIDX + c);
    }
#pragma unroll
    for (int l = 0; l < 8; ++l) {
        int idx = l * 256 + tid;
        int r = idx >> 6, c = idx & 63;
        kis[r][c] = QIW[(size_t)(s0 + r) * NIDX + 256 + c];
    }
    if (tid < 32) *(float4*)&wis[tid][0] = *(const float4*)(QIW + (size_t)(t0 + tid) * NIDX + 320);
    __syncthreads();
    int sl = tid & 31;
    int tb = (tid >> 5) * 4;
    float acc[4] = { 0.f, 0.f, 0.f, 0.f };
#pragma unroll
    for (int h = 0; h < 4; ++h) {
        float dots[4] = { 0.f, 0.f, 0.f, 0.f };
        for (int d = 0; d < 64; ++d) {
            float kv = kis[sl][d];
#pragma unroll
            for (int i = 0; i < 4; ++i)
                dots[i] += qis[tb + i][h * 64 + d] * kv;
        }
#pragma unroll
        for (int i = 0; i < 4; ++i)
            acc[i] += wis[tb + i][h] * fmaxf(dots[i], 0.f);
    }
#pragma unroll
    for (int i = 0; i < 4; ++i)
        scores[(size_t)(t0 + tb + i) * S_LEN + s0 + sl] = acc[i];
}

// ---------------- Top-K via radix select (exact lax.top_k set semantics) ----------------
__global__ __launch_bounds__(256) void topk_kernel(const float* __restrict__ scores,
    int* __restrict__ topidx, int* __restrict__ topcnt)
{
    int t = blockIdx.x, tid = threadIdx.x;
    int n = t + 1;
    if (n <= TOPK) {
        if (tid < n) topidx[t * TOPK + tid] = tid;
        if (tid == 0) topcnt[t] = n;
        return;
    }
    __shared__ unsigned sc[S_LEN];
    __shared__ unsigned hist[256];
    __shared__ int selbin_s;
    __shared__ int cnt_out;
    __shared__ unsigned wsum[4];
    for (int j = tid; j < n; j += 256) {
        unsigned u = __builtin_bit_cast(unsigned, scores[(size_t)t * S_LEN + j]);
        sc[j] = (u & 0x80000000u) ? ~u : (u | 0x80000000u);
    }
    if (tid == 0) cnt_out = 0;
    int lane = tid & 63, wv = tid >> 6;
    unsigned prefix = 0;
    int kk = TOPK;
#pragma unroll
    for (int round = 0; round < 4; ++round) {
        int shift_pref = 32 - 8 * round;
        int shift_bin = 24 - 8 * round;
        hist[tid] = 0;
        __syncthreads();
        for (int j = tid; j < n; j += 256) {
            unsigned v = sc[j];
            if ((((unsigned long long)(v ^ prefix)) >> shift_pref) == 0)
                atomicAdd(&hist[(v >> shift_bin) & 0xff], 1u);
        }
        __syncthreads();
        if (wv == 0) {
            unsigned h0 = hist[4 * lane], h1 = hist[4 * lane + 1];
            unsigned h2 = hist[4 * lane + 2], h3 = hist[4 * lane + 3];
            unsigned s3 = h3, s2 = h2 + s3, s1 = h1 + s2, s0 = h0 + s1;
            unsigned acc = s0;
            for (int off = 1; off < 64; off <<= 1) {
                unsigned o = __shfl_down(acc, off);
                if (lane + off < 64) acc += o;
            }
            unsigned above = acc - s0;
            hist[4 * lane]     = s0 + above;
            hist[4 * lane + 1] = s1 + above;
            hist[4 * lane + 2] = s2 + above;
            hist[4 * lane + 3] = s3 + above;
        }
        __syncthreads();
        {
            unsigned sufb = hist[tid];
            unsigned sufn = (tid < 255) ? hist[tid + 1] : 0u;
            if (sufb >= (unsigned)kk && sufn < (unsigned)kk)
                selbin_s = tid;
        }
        __syncthreads();
        int b = selbin_s;
        unsigned above = (b < 255) ? hist[b + 1] : 0u;
        kk -= (int)above;
        prefix |= ((unsigned)b) << shift_bin;
        __syncthreads();
    }
    unsigned T = prefix;
    int chunk = (n + 255) >> 8;
    int jb = tid * chunk;
    int je = jb + chunk; if (je > n) je = n;
    int ties = 0;
    for (int j = jb; j < je; ++j) {
        unsigned v = sc[j];
        if (v > T) { int o = atomicAdd(&cnt_out, 1); topidx[t * TOPK + o] = j; }
        else if (v == T) ++ties;
    }
    unsigned inc = (unsigned)ties;
    for (int off = 1; off < 64; off <<= 1) {
        unsigned o = __shfl_up(inc, off);
        if (lane >= off) inc += o;
    }
    if (lane == 63) wsum[wv] = inc;
    __syncthreads();
    unsigned woff = 0;
    for (int w = 0; w < wv; ++w) woff += wsum[w];
    int rank = (int)(woff + inc) - ties;
    for (int j = jb; j < je && rank < kk; ++j) {
        if (sc[j] == T) {
            int o = atomicAdd(&cnt_out, 1);
            topidx[t * TOPK + o] = j;
            ++rank;
        }
    }
    if (tid == 0) topcnt[t] = TOPK;
}

// ---------------- Sparse SDPA v3: lane = (key, dim-octet) -> coalesced 8-row gathers ----------------
__global__ __launch_bounds__(256) void attn_kernel(
    const unsigned short* __restrict__ Qb, const unsigned short* __restrict__ Kb,
    const unsigned short* __restrict__ Vb,
    const int* __restrict__ topidx, const int* __restrict__ topcnt,
    unsigned short* __restrict__ out)
{
    int t = blockIdx.x, tid = threadIdx.x;
    __shared__ unsigned short qls[D_MODEL];
    __shared__ int sel[TOPK];
    *(ushort4*)(qls + tid * 4) = *(const ushort4*)(Qb + (size_t)t * D_MODEL + tid * 4);
    if (tid < TOPK) sel[tid] = topidx[t * TOPK + tid];
    __syncthreads();
    int cnt = topcnt[t];
    int lane = tid & 63, wv = tid >> 6;
    int klo = lane >> 3, oct = lane & 7;
    int rows[8];
    bool valid[8];
#pragma unroll
    for (int kg = 0; kg < 8; ++kg) {
        int k = kg * 8 + klo;
        valid[kg] = (k < cnt);
        rows[kg] = sel[valid[kg] ? k : 0];
    }
#pragma unroll
    for (int hh = 0; hh < 4; ++hh) {
        int h = wv * 4 + hh;
        bf16x8 q8 = *(const bf16x8*)(qls + h * HDIM + oct * 8);
        const unsigned short* kbase = Kb + (size_t)h * S_LEN * HDIM + oct * 8;
        float p[8];
#pragma unroll
        for (int kg = 0; kg < 8; ++kg) {
            bf16x8 k8 = *(const bf16x8*)(kbase + (size_t)rows[kg] * HDIM);
            float d = 0.f;
#pragma unroll
            for (int e = 0; e < 8; ++e)
                d += bf2f((unsigned short)k8[e]) * bf2f((unsigned short)q8[e]);
            d += __shfl_xor(d, 1);
            d += __shfl_xor(d, 2);
            d += __shfl_xor(d, 4);
            p[kg] = valid[kg] ? d * 0.125f : -INFINITY;
        }
        float m = p[0];
#pragma unroll
        for (int kg = 1; kg < 8; ++kg) m = fmaxf(m, p[kg]);
        m = fmaxf(m, __shfl_xor(m, 8));
        m = fmaxf(m, __shfl_xor(m, 16));
        m = fmaxf(m, __shfl_xor(m, 32));
        float sum = 0.f;
#pragma unroll
        for (int kg = 0; kg < 8; ++kg) { p[kg] = __expf(p[kg] - m); sum += p[kg]; }
        sum += __shfl_xor(sum, 8);
        sum += __shfl_xor(sum, 16);
        sum += __shfl_xor(sum, 32);
        float rs = 1.f / sum;
        const unsigned short* vbase = Vb + (size_t)h * S_LEN * HDIM + oct * 8;
        float facc[8] = {};
#pragma unroll
        for (int kg = 0; kg < 8; ++kg) {
            bf16x8 v8 = *(const bf16x8*)(vbase + (size_t)rows[kg] * HDIM);
            float pw = p[kg] * rs;
#pragma unroll
            for (int e = 0; e < 8; ++e)
                facc[e] += pw * bf2f((unsigned short)v8[e]);
        }
#pragma unroll
        for (int e = 0; e < 8; ++e) {
            facc[e] += __shfl_xor(facc[e], 8);
            facc[e] += __shfl_xor(facc[e], 16);
            facc[e] += __shfl_xor(facc[e], 32);
        }
        if (klo == 0) {
            ushort4 o0 = { f2bf(facc[0]), f2bf(facc[1]), f2bf(facc[2]), f2bf(facc[3]) };
            ushort4 o1 = { f2bf(facc[4]), f2bf(facc[5]), f2bf(facc[6]), f2bf(facc[7]) };
            *(ushort4*)(out + (size_t)t * D_MODEL + h * HDIM + oct * 8) = o0;
            *(ushort4*)(out + (size_t)t * D_MODEL + h * HDIM + oct * 8 + 4) = o1;
        }
    }
}

extern "C" void kernel_launch(void* const* d_in, const int* in_sizes, int n_in,
                              void* d_out, int out_size, void* d_ws, size_t ws_size,
                              hipStream_t stream)
{
    const float* x      = (const float*)d_in[0];
    const float* w_qkv  = (const float*)d_in[1];
    const float* w_o    = (const float*)d_in[2];
    const float* ffn_w1 = (const float*)d_in[3];
    const float* ffn_b1 = (const float*)d_in[4];
    const float* ffn_w2 = (const float*)d_in[5];
    const float* ffn_b2 = (const float*)d_in[6];
    const float* ln1_g  = (const float*)d_in[7];
    const float* ln1_b  = (const float*)d_in[8];
    const float* ln2_g  = (const float*)d_in[9];
    const float* ln2_b  = (const float*)d_in[10];
    const float* idx_wq = (const float*)d_in[11];
    const float* idx_wk = (const float*)d_in[12];
    const float* idx_ww = (const float*)d_in[13];
    float* outp = (float*)d_out;

    const size_t MB = 1ull << 20;
    char* ws = (char*)d_ws;
    // [0,8)    normx fp32 -> attno_bf (4MB) -> Pf2 (32MB ffn2 partials)
    // [8,12)   normx_bf / h2_bf
    // [12,24)  qkv_bf (dead after rope_pack) -> topidx/topcnt
    // [24,32)  wqkv_t/wo_t    [32,40) w1_t   [40,48) w2_t
    // [48,60)  Qb/Kb/Vb
    // [60,76)  ctab/stab (dead after rope_pack) -> P_idx (11MB) -> scoresb -> Pwo -> ffn1_bf
    // [76,79)  QIW   [79,80.5) Wc
    float*          normx    = (float*)(ws + 0);
    unsigned short* attno_bf = (unsigned short*)(ws + 0);
    float*          Pf2      = (float*)(ws + 0);
    unsigned short* normx_bf = (unsigned short*)(ws + 8 * MB);
    unsigned short* h2_bf    = normx_bf;
    unsigned short* qkv_bf   = (unsigned short*)(ws + 12 * MB);
    int*            topidx   = (int*)(ws + 12 * MB);
    int*            topcnt   = (int*)(ws + 12 * MB + 512 * 1024);
    unsigned short* wqkv_t   = (unsigned short*)(ws + 24 * MB);
    unsigned short* wo_t     = (unsigned short*)(ws + 30 * MB);
    unsigned short* w1_t     = (unsigned short*)(ws + 32 * MB);
    unsigned short* w2_t     = (unsigned short*)(ws + 40 * MB);
    unsigned short* Qb       = (unsigned short*)(ws + 48 * MB);
    unsigned short* Kb       = (unsigned short*)(ws + 52 * MB);
    unsigned short* Vb       = (unsigned short*)(ws + 56 * MB);
    float*          ctab     = (float*)(ws + 60 * MB);
    float*          stab     = (float*)(ws + 60 * MB + 256 * 1024);
    float*          P_idx    = (float*)(ws + 60 * MB);      // 4 x 2048*336*4B = 11MB
    float*          scoresb  = (float*)(ws + 60 * MB);
    float*          Pwo      = (float*)(ws + 60 * MB);      // 16MB w_o partials (2 slices)
    unsigned short* ffn1_bf  = (unsigned short*)(ws + 60 * MB);
    float*          QIW      = (float*)(ws + 76 * MB);
    float*          Wc       = (float*)(ws + 79 * MB);

    dim3 blk256(256);
    auto g128 = [](int N, int M) { return dim3(N / 128, M / 128); };

    // 1. LN1 -> fp32 (indexer) + bf16 (qkv gemm)
    ln_kernel<<<S_LEN, blk256, 0, stream>>>(x, ln1_g, ln1_b, normx, normx_bf);
    // 2. rope tables + weight prep
    rope_table_kernel<<<(S_LEN * 32) / 256, blk256, 0, stream>>>(ctab, stab);
    wtrans_kernel<<<dim3(3 * D_MODEL / 32, D_MODEL / 32), blk256, 0, stream>>>(w_qkv, wqkv_t, D_MODEL, 3 * D_MODEL);
    wtrans_kernel<<<dim3(D_MODEL / 32, D_MODEL / 32), blk256, 0, stream>>>(w_o, wo_t, D_MODEL, D_MODEL);
    wtrans_kernel<<<dim3(DFF / 32, D_MODEL / 32), blk256, 0, stream>>>(ffn_w1, w1_t, D_MODEL, DFF);
    wtrans_kernel<<<dim3(D_MODEL / 32, DFF / 32), blk256, 0, stream>>>(ffn_w2, w2_t, DFF, D_MODEL);
    wpack_kernel<<<(D_MODEL * NIDX + 255) / 256, blk256, 0, stream>>>(idx_wq, idx_wk, idx_ww, Wc);
    // 3. qkv = norm_x @ w_qkv (bf16 out only; 384 blocks)
    gemm_bf16<<<g128(3 * D_MODEL, S_LEN), blk256, 0, stream>>>(normx_bf, wqkv_t,
        nullptr, qkv_bf, nullptr, nullptr, S_LEN, 3 * D_MODEL, D_MODEL, 0, nullptr, D_MODEL);
    // 4. RoPE + pack Q/K/V (frees qkv_bf + ctab/stab for P_idx)
    rope_pack_kernel<<<S_LEN, dim3(512), 0, stream>>>(qkv_bf, ctab, stab, Qb, Kb, Vb);
    // 5. fused indexer projections (fp32, split-K=4 -> 768 blocks; feeds discrete top-k)
    gemm64<<<dim3((NIDX + 63) / 64, S_LEN / 64, 4), blk256, 0, stream>>>(normx, Wc,
        nullptr, S_LEN, NIDX, D_MODEL, P_idx, D_MODEL / 4);
    kreduce_kernel<<<1024, blk256, 0, stream>>>(P_idx, 4, QIW, nullptr, nullptr, S_LEN, NIDX);
    // 6. indexer scores (overwrites dead P_idx region)
    scores_kernel<<<dim3(64, 64), blk256, 0, stream>>>(QIW, scoresb);
    // 7. top-64 per row (radix select; topidx overlays dead qkv_bf)
    topk_kernel<<<S_LEN, blk256, 0, stream>>>(scoresb, topidx, topcnt);
    // 8. sparse attention -> bf16 (overlays dead normx)
    attn_kernel<<<S_LEN, blk256, 0, stream>>>(Qb, Kb, Vb, topidx, topcnt, attno_bf);
    // 9. x1 = x + attn_out @ w_o  — split-K=2 (256 blocks) into Pwo, then reduce
    gemm_bf16<<<dim3(D_MODEL / 128, S_LEN / 128, 2), blk256, 0, stream>>>(attno_bf, wo_t,
        nullptr, nullptr, nullptr, nullptr, S_LEN, D_MODEL, D_MODEL, 0, Pwo, D_MODEL / 2);
    kreduce_kernel<<<1024, blk256, 0, stream>>>(Pwo, 2, outp, nullptr, x, S_LEN, D_MODEL);
    // 10. h = LN2(x1) -> bf16
    ln_kernel<<<S_LEN, blk256, 0, stream>>>(outp, ln2_g, ln2_b, nullptr, h2_bf);
    // 11. ffn1 = gelu(h @ w1 + b1) -> bf16 (overlays dead Pwo/scoresb; 512 blocks)
    gemm_bf16<<<g128(DFF, S_LEN), blk256, 0, stream>>>(h2_bf, w1_t,
        nullptr, ffn1_bf, ffn_b1, nullptr, S_LEN, DFF, D_MODEL, 1, nullptr, D_MODEL);
    // 12. out = x1 + ffn1 @ w2 + b2 — split-K=4 (512 blocks) into Pf2, then reduce
    gemm_bf16<<<dim3(D_MODEL / 128, S_LEN / 128, 4), blk256, 0, stream>>>(ffn1_bf, w2_t,
        nullptr, nullptr, nullptr, nullptr, S_LEN, D_MODEL, DFF, 0, Pf2, DFF / 4);
    kreduce_kernel<<<1024, blk256, 0, stream>>>(Pf2, 4, outp, ffn_b2, outp, S_LEN, D_MODEL);
}

// Round 8
// 300.387 us; speedup vs baseline: 4.5020x; 1.0813x over previous
//
#include <hip/hip_runtime.h>
#include <math.h>

#define S_LEN 2048
#define D_MODEL 1024
#define NHEAD 16
#define HDIM 64
#define DFF 4096
#define IH 4
#define IDM 64
#define TOPK 64
#define NIDX 336   // 256 qi + 64 ki + 4 wi + 12 pad

typedef float f32x4 __attribute__((ext_vector_type(4)));
typedef short bf16x8 __attribute__((ext_vector_type(8)));

__device__ __forceinline__ unsigned short f2bf(float f) {
    unsigned u = __builtin_bit_cast(unsigned, f);
    u += 0x7fff + ((u >> 16) & 1);
    return (unsigned short)(u >> 16);
}
__device__ __forceinline__ float bf2f(unsigned short us) {
    return __builtin_bit_cast(float, (unsigned)us << 16);
}

__device__ __forceinline__ float gelu_exact(float v) {
    return 0.5f * v * (1.f + erff(v * 0.70710678118654752f));
}

__device__ __forceinline__ void gl_lds16(const void* g, void* l) {
    __builtin_amdgcn_global_load_lds(
        (const __attribute__((address_space(1))) void*)g,
        (__attribute__((address_space(3))) void*)l, 16, 0, 0);
}

// ---------------- LayerNorm: fp32 out (optional) + bf16 out (optional) ----------------
__global__ __launch_bounds__(256) void ln_kernel(const float* __restrict__ x,
    const float* __restrict__ g, const float* __restrict__ b,
    float* __restrict__ outf, unsigned short* __restrict__ outb)
{
    int row = blockIdx.x, tid = threadIdx.x;
    const float4 v = *(const float4*)(x + (size_t)row * D_MODEL + tid * 4);
    float s = v.x + v.y + v.z + v.w;
    float ss = v.x * v.x + v.y * v.y + v.z * v.z + v.w * v.w;
    int lane = tid & 63, wv = tid >> 6;
    for (int o = 32; o; o >>= 1) { s += __shfl_xor(s, o); ss += __shfl_xor(ss, o); }
    __shared__ float rs[4], rss[4];
    if (lane == 0) { rs[wv] = s; rss[wv] = ss; }
    __syncthreads();
    float S = rs[0] + rs[1] + rs[2] + rs[3];
    float SS = rss[0] + rss[1] + rss[2] + rss[3];
    float mean = S * (1.f / D_MODEL);
    float var = SS * (1.f / D_MODEL) - mean * mean;
    float r = rsqrtf(var + 1e-5f);
    float4 gv = *(const float4*)(g + tid * 4);
    float4 bv = *(const float4*)(b + tid * 4);
    float4 o4;
    o4.x = (v.x - mean) * r * gv.x + bv.x;
    o4.y = (v.y - mean) * r * gv.y + bv.y;
    o4.z = (v.z - mean) * r * gv.z + bv.z;
    o4.w = (v.w - mean) * r * gv.w + bv.w;
    if (outf) *(float4*)(outf + (size_t)row * D_MODEL + tid * 4) = o4;
    if (outb) {
        ushort4 u4 = { f2bf(o4.x), f2bf(o4.y), f2bf(o4.z), f2bf(o4.w) };
        *(ushort4*)(outb + (size_t)row * D_MODEL + tid * 4) = u4;
    }
}

// ---------------- Weight convert + transpose: fp32 [K][N] -> bf16 [N][K] ----------------
__global__ __launch_bounds__(256) void wtrans_kernel(const float* __restrict__ in,
    unsigned short* __restrict__ out, int K, int N)
{
    __shared__ float t[32][33];
    int k0 = blockIdx.y * 32, n0 = blockIdx.x * 32;
    int tid = threadIdx.x;
    int r = tid >> 5, c = tid & 31;
#pragma unroll
    for (int p = 0; p < 4; ++p)
        t[r + p * 8][c] = in[(size_t)(k0 + r + p * 8) * N + n0 + c];
    __syncthreads();
#pragma unroll
    for (int p = 0; p < 4; ++p)
        out[(size_t)(n0 + r + p * 8) * K + k0 + c] = f2bf(t[c][r + p * 8]);
}

// ---------------- Pack indexer weights into one fp32 [1024][336] ----------------
__global__ __launch_bounds__(256) void wpack_kernel(const float* __restrict__ wq,
    const float* __restrict__ wk, const float* __restrict__ ww, float* __restrict__ Wc)
{
    int idx = blockIdx.x * 256 + threadIdx.x;
    if (idx >= D_MODEL * NIDX) return;
    int r = idx / NIDX, c = idx % NIDX;
    float v = 0.f;
    if (c < 256) v = wq[r * 256 + c];
    else if (c < 320) v = wk[r * 64 + (c - 256)];
    else if (c < 324) v = ww[r * 4 + (c - 320)];
    Wc[idx] = v;
}

// ---------------- bf16 MFMA GEMM, 128x64 tile (grid-doubling variant) ----------------
// 4 waves; wave w computes rows [bm+32w, bm+32w+32) x all 64 cols. acc[2][4].
// Split-K: if P != nullptr, block z does K-chunk -> raw fp32 partials at P + z*M*N.
__global__ __launch_bounds__(256) void gemm_bf16_n64(
    const unsigned short* __restrict__ A, const unsigned short* __restrict__ Bt,
    float* __restrict__ C, unsigned short* __restrict__ Cb,
    const float* __restrict__ bias, const float* __restrict__ R,
    int M, int N, int K, int act,
    float* __restrict__ P, int kchunk)
{
    __shared__ __attribute__((aligned(16))) unsigned short As[128 * 32];
    __shared__ __attribute__((aligned(16))) unsigned short Bs[64 * 32];
    int tid = threadIdx.x;
    int bm = blockIdx.y * 128, bn = blockIdx.x * 64;
    int wid = tid >> 6, lane = tid & 63;
    int wm = wid * 32;
    const unsigned short* Ab = A + (size_t)bm * K;
    const unsigned short* Bb = Bt + (size_t)bn * K;
    f32x4 acc[2][4];
#pragma unroll
    for (int i = 0; i < 2; ++i)
#pragma unroll
        for (int j = 0; j < 4; ++j)
            acc[i][j] = (f32x4){0.f, 0.f, 0.f, 0.f};

    int kbeg = blockIdx.z * kchunk;
    int kend = kbeg + kchunk;
    int fr = lane & 15, fk = (lane >> 4) * 8;
    int e0 = tid * 8;                 // 2048 elems per pass
    int r0 = e0 >> 5, c0 = e0 & 31;
    for (int k0 = kbeg; k0 < kend; k0 += 32) {
        gl_lds16(Ab + (size_t)r0 * K + k0 + c0, As + e0);
        gl_lds16(Ab + (size_t)(r0 + 64) * K + k0 + c0, As + e0 + 2048);
        gl_lds16(Bb + (size_t)r0 * K + k0 + c0, Bs + e0);
        __syncthreads();
        bf16x8 af[2], bfv[4];
#pragma unroll
        for (int mi = 0; mi < 2; ++mi)
            af[mi] = *(const bf16x8*)&As[(wm + mi * 16 + fr) * 32 + fk];
#pragma unroll
        for (int ni = 0; ni < 4; ++ni)
            bfv[ni] = *(const bf16x8*)&Bs[(ni * 16 + fr) * 32 + fk];
#pragma unroll
        for (int mi = 0; mi < 2; ++mi)
#pragma unroll
            for (int ni = 0; ni < 4; ++ni)
                acc[mi][ni] = __builtin_amdgcn_mfma_f32_16x16x32_bf16(
                    af[mi], bfv[ni], acc[mi][ni], 0, 0, 0);
        __syncthreads();
    }
    int cl = lane & 15, rh = (lane >> 4) * 4;
    if (P) {
        float* Pz = P + (size_t)blockIdx.z * M * N;
#pragma unroll
        for (int mi = 0; mi < 2; ++mi)
#pragma unroll
            for (int ni = 0; ni < 4; ++ni) {
                int col = bn + ni * 16 + cl;
#pragma unroll
                for (int r = 0; r < 4; ++r) {
                    int row = bm + wm + mi * 16 + rh + r;
                    Pz[(size_t)row * N + col] = acc[mi][ni][r];
                }
            }
        return;
    }
#pragma unroll
    for (int mi = 0; mi < 2; ++mi) {
#pragma unroll
        for (int ni = 0; ni < 4; ++ni) {
            int col = bn + ni * 16 + cl;
            float bv = bias ? bias[col] : 0.f;
#pragma unroll
            for (int r = 0; r < 4; ++r) {
                int row = bm + wm + mi * 16 + rh + r;
                float v = acc[mi][ni][r] + bv;
                if (act) v = gelu_exact(v);
                size_t off = (size_t)row * N + col;
                if (R) v += R[off];
                if (C) C[off] = v;
                if (Cb) Cb[off] = f2bf(v);
            }
        }
    }
}

// ---------------- Split-K reduce: C = sum_z P[z] + bias + R (float4 vectorized) ----------------
__global__ __launch_bounds__(256) void kreduce_kernel(const float* __restrict__ P,
    int nslice, float* __restrict__ C, const float* __restrict__ bias,
    const float* __restrict__ R, int M, int N)
{
    size_t total4 = (size_t)M * N / 4;
    size_t stride = (size_t)gridDim.x * 256;
    for (size_t i4 = blockIdx.x * 256 + threadIdx.x; i4 < total4; i4 += stride) {
        size_t off = i4 * 4;
        float4 v = *(const float4*)(P + off);
        for (int z = 1; z < nslice; ++z) {
            float4 p = *(const float4*)(P + (size_t)z * M * N + off);
            v.x += p.x; v.y += p.y; v.z += p.z; v.w += p.w;
        }
        if (bias) {
            float4 b4 = *(const float4*)(bias + (off % N));
            v.x += b4.x; v.y += b4.y; v.z += b4.z; v.w += b4.w;
        }
        if (R) {
            float4 r4 = *(const float4*)(R + off);
            v.x += r4.x; v.y += r4.y; v.z += r4.z; v.w += r4.w;
        }
        *(float4*)(C + off) = v;
    }
}

// ---------------- Generic fp32 GEMM (indexer path): C[M,N] = A[M,K]@B[K,N] ----------------
// Split-K: if P != nullptr, block z does K-chunk [z*kchunk, (z+1)*kchunk) -> P + z*M*N.
__global__ __launch_bounds__(256) void gemm64(const float* __restrict__ A,
    const float* __restrict__ B, float* __restrict__ C,
    int M, int N, int K,
    float* __restrict__ P, int kchunk)
{
    __shared__ float As[16][68];
    __shared__ float Bs[16][68];
    int tid = threadIdx.x;
    int bm = blockIdx.y, bn = blockIdx.x;
    int tx = tid & 15, ty = tid >> 4;
    int arow = tid >> 2;
    int acol = (tid & 3) << 2;
    int brow = tid >> 4;
    int bcol = (tid & 15) << 2;
    const float* Abase = A + (size_t)(bm * 64 + arow) * K + acol;
    float c[4][4] = {};
    int kbeg = blockIdx.z * kchunk;
    int kend = kbeg + kchunk;
    for (int k0 = kbeg; k0 < kend; k0 += 16) {
        float4 av = *(const float4*)(Abase + k0);
        As[acol + 0][arow] = av.x;
        As[acol + 1][arow] = av.y;
        As[acol + 2][arow] = av.z;
        As[acol + 3][arow] = av.w;
        int gcol = bn * 64 + bcol;
        const float* Bb = B + (size_t)(k0 + brow) * N;
        float4 bv;
        if (gcol + 3 < N) {
            bv = *(const float4*)(Bb + gcol);
        } else {
            bv.x = (gcol + 0 < N) ? Bb[gcol + 0] : 0.f;
            bv.y = (gcol + 1 < N) ? Bb[gcol + 1] : 0.f;
            bv.z = (gcol + 2 < N) ? Bb[gcol + 2] : 0.f;
            bv.w = (gcol + 3 < N) ? Bb[gcol + 3] : 0.f;
        }
        *(float4*)&Bs[brow][bcol] = bv;
        __syncthreads();
#pragma unroll
        for (int kk = 0; kk < 16; ++kk) {
            float4 a4 = *(const float4*)&As[kk][ty * 4];
            float4 b4 = *(const float4*)&Bs[kk][tx * 4];
            float av4[4] = { a4.x, a4.y, a4.z, a4.w };
            float bv4[4] = { b4.x, b4.y, b4.z, b4.w };
#pragma unroll
            for (int i = 0; i < 4; ++i)
#pragma unroll
                for (int j = 0; j < 4; ++j)
                    c[i][j] += av4[i] * bv4[j];
        }
        __syncthreads();
    }
    float* Out = P ? (P + (size_t)blockIdx.z * M * N) : C;
#pragma unroll
    for (int i = 0; i < 4; ++i) {
        int row = bm * 64 + ty * 4 + i;
#pragma unroll
        for (int j = 0; j < 4; ++j) {
            int col = bn * 64 + tx * 4 + j;
            if (col < N)
                Out[(size_t)row * N + col] = c[i][j];
        }
    }
}

// ---------------- RoPE table ----------------
__global__ __launch_bounds__(256) void rope_table_kernel(float* __restrict__ ct, float* __restrict__ st)
{
    int g = blockIdx.x * 256 + threadIdx.x;
    int t = g >> 5, i = g & 31;
    float theta = powf(10000.f, -(float)i / 32.f);
    float ang = (float)t * theta;
    ct[g] = cosf(ang);
    st[g] = sinf(ang);
}

// ---------------- RoPE + pack: qkv bf16 [S][3072] -> Qb [S][1024], Kb/Vb [H][S][64] ----------------
__global__ __launch_bounds__(512) void rope_pack_kernel(
    const unsigned short* __restrict__ qkvb,
    const float* __restrict__ ct, const float* __restrict__ st,
    unsigned short* __restrict__ Qb, unsigned short* __restrict__ Kb,
    unsigned short* __restrict__ Vb)
{
    int t = blockIdx.x, tid = threadIdx.x;
    int h = tid >> 5, i = tid & 31;
    float c = ct[t * 32 + i], s = st[t * 32 + i];
    const unsigned short* base = qkvb + (size_t)t * (3 * D_MODEL);
    ushort2 q2 = *(const ushort2*)(base + h * HDIM + 2 * i);
    float q0 = bf2f(q2.x), q1 = bf2f(q2.y);
    ushort2 qo = { f2bf(q0 * c - q1 * s), f2bf(q1 * c + q0 * s) };
    *(ushort2*)(Qb + (size_t)t * D_MODEL + h * HDIM + 2 * i) = qo;
    ushort2 k2 = *(const ushort2*)(base + D_MODEL + h * HDIM + 2 * i);
    float k0 = bf2f(k2.x), k1 = bf2f(k2.y);
    ushort2 ko = { f2bf(k0 * c - k1 * s), f2bf(k1 * c + k0 * s) };
    *(ushort2*)(Kb + ((size_t)h * S_LEN + t) * HDIM + 2 * i) = ko;
    ushort2 v2 = *(const ushort2*)(base + 2 * D_MODEL + 2 * tid);
    int vh = tid >> 5, vd = (2 * tid) & 63;
    *(ushort2*)(Vb + ((size_t)vh * S_LEN + t) * HDIM + vd) = v2;
}

// ---------------- Indexer scores (fp32, fused QIW layout, stride 336) ----------------
__global__ __launch_bounds__(256) void scores_kernel(const float* __restrict__ QIW,
    float* __restrict__ scores)
{
    int t0 = blockIdx.y * 32, s0 = blockIdx.x * 32;
    if (s0 > t0 + 31) return;
    __shared__ float qis[32][256];
    __shared__ float kis[32][65];
    __shared__ float wis[32][4];
    int tid = threadIdx.x;
#pragma unroll
    for (int l = 0; l < 8; ++l) {
        int idx = l * 256 + tid;
        int r = idx >> 6, c = (idx & 63) << 2;
        *(float4*)&qis[r][c] = *(const float4*)(QIW + (size_t)(t0 + r) * NIDX + c);
    }
#pragma unroll
    for (int l = 0; l < 8; ++l) {
        int idx = l * 256 + tid;
        int r = idx >> 6, c = idx & 63;
        kis[r][c] = QIW[(size_t)(s0 + r) * NIDX + 256 + c];
    }
    if (tid < 32) *(float4*)&wis[tid][0] = *(const float4*)(QIW + (size_t)(t0 + tid) * NIDX + 320);
    __syncthreads();
    int sl = tid & 31;
    int tb = (tid >> 5) * 4;
    float acc[4] = { 0.f, 0.f, 0.f, 0.f };
#pragma unroll
    for (int h = 0; h < 4; ++h) {
        float dots[4] = { 0.f, 0.f, 0.f, 0.f };
        for (int d = 0; d < 64; ++d) {
            float kv = kis[sl][d];
#pragma unroll
            for (int i = 0; i < 4; ++i)
                dots[i] += qis[tb + i][h * 64 + d] * kv;
        }
#pragma unroll
        for (int i = 0; i < 4; ++i)
            acc[i] += wis[tb + i][h] * fmaxf(dots[i], 0.f);
    }
#pragma unroll
    for (int i = 0; i < 4; ++i)
        scores[(size_t)(t0 + tb + i) * S_LEN + s0 + sl] = acc[i];
}

// ---------------- Top-K via radix select (exact lax.top_k set semantics) ----------------
__global__ __launch_bounds__(256) void topk_kernel(const float* __restrict__ scores,
    int* __restrict__ topidx, int* __restrict__ topcnt)
{
    int t = blockIdx.x, tid = threadIdx.x;
    int n = t + 1;
    if (n <= TOPK) {
        if (tid < n) topidx[t * TOPK + tid] = tid;
        if (tid == 0) topcnt[t] = n;
        return;
    }
    __shared__ unsigned sc[S_LEN];
    __shared__ unsigned hist[256];
    __shared__ int selbin_s;
    __shared__ int cnt_out;
    __shared__ unsigned wsum[4];
    for (int j = tid; j < n; j += 256) {
        unsigned u = __builtin_bit_cast(unsigned, scores[(size_t)t * S_LEN + j]);
        sc[j] = (u & 0x80000000u) ? ~u : (u | 0x80000000u);
    }
    if (tid == 0) cnt_out = 0;
    int lane = tid & 63, wv = tid >> 6;
    unsigned prefix = 0;
    int kk = TOPK;
#pragma unroll
    for (int round = 0; round < 4; ++round) {
        int shift_pref = 32 - 8 * round;
        int shift_bin = 24 - 8 * round;
        hist[tid] = 0;
        __syncthreads();
        for (int j = tid; j < n; j += 256) {
            unsigned v = sc[j];
            if ((((unsigned long long)(v ^ prefix)) >> shift_pref) == 0)
                atomicAdd(&hist[(v >> shift_bin) & 0xff], 1u);
        }
        __syncthreads();
        if (wv == 0) {
            unsigned h0 = hist[4 * lane], h1 = hist[4 * lane + 1];
            unsigned h2 = hist[4 * lane + 2], h3 = hist[4 * lane + 3];
            unsigned s3 = h3, s2 = h2 + s3, s1 = h1 + s2, s0 = h0 + s1;
            unsigned acc = s0;
            for (int off = 1; off < 64; off <<= 1) {
                unsigned o = __shfl_down(acc, off);
                if (lane + off < 64) acc += o;
            }
            unsigned above = acc - s0;
            hist[4 * lane]     = s0 + above;
            hist[4 * lane + 1] = s1 + above;
            hist[4 * lane + 2] = s2 + above;
            hist[4 * lane + 3] = s3 + above;
        }
        __syncthreads();
        {
            unsigned sufb = hist[tid];
            unsigned sufn = (tid < 255) ? hist[tid + 1] : 0u;
            if (sufb >= (unsigned)kk && sufn < (unsigned)kk)
                selbin_s = tid;
        }
        __syncthreads();
        int b = selbin_s;
        unsigned above = (b < 255) ? hist[b + 1] : 0u;
        kk -= (int)above;
        prefix |= ((unsigned)b) << shift_bin;
        __syncthreads();
    }
    unsigned T = prefix;
    int chunk = (n + 255) >> 8;
    int jb = tid * chunk;
    int je = jb + chunk; if (je > n) je = n;
    int ties = 0;
    for (int j = jb; j < je; ++j) {
        unsigned v = sc[j];
        if (v > T) { int o = atomicAdd(&cnt_out, 1); topidx[t * TOPK + o] = j; }
        else if (v == T) ++ties;
    }
    unsigned inc = (unsigned)ties;
    for (int off = 1; off < 64; off <<= 1) {
        unsigned o = __shfl_up(inc, off);
        if (lane >= off) inc += o;
    }
    if (lane == 63) wsum[wv] = inc;
    __syncthreads();
    unsigned woff = 0;
    for (int w = 0; w < wv; ++w) woff += wsum[w];
    int rank = (int)(woff + inc) - ties;
    for (int j = jb; j < je && rank < kk; ++j) {
        if (sc[j] == T) {
            int o = atomicAdd(&cnt_out, 1);
            topidx[t * TOPK + o] = j;
            ++rank;
        }
    }
    if (tid == 0) topcnt[t] = TOPK;
}

// ---------------- Sparse SDPA v3: lane = (key, dim-octet) -> coalesced 8-row gathers ----------------
__global__ __launch_bounds__(256) void attn_kernel(
    const unsigned short* __restrict__ Qb, const unsigned short* __restrict__ Kb,
    const unsigned short* __restrict__ Vb,
    const int* __restrict__ topidx, const int* __restrict__ topcnt,
    unsigned short* __restrict__ out)
{
    int t = blockIdx.x, tid = threadIdx.x;
    __shared__ unsigned short qls[D_MODEL];
    __shared__ int sel[TOPK];
    *(ushort4*)(qls + tid * 4) = *(const ushort4*)(Qb + (size_t)t * D_MODEL + tid * 4);
    if (tid < TOPK) sel[tid] = topidx[t * TOPK + tid];
    __syncthreads();
    int cnt = topcnt[t];
    int lane = tid & 63, wv = tid >> 6;
    int klo = lane >> 3, oct = lane & 7;
    int rows[8];
    bool valid[8];
#pragma unroll
    for (int kg = 0; kg < 8; ++kg) {
        int k = kg * 8 + klo;
        valid[kg] = (k < cnt);
        rows[kg] = sel[valid[kg] ? k : 0];
    }
#pragma unroll
    for (int hh = 0; hh < 4; ++hh) {
        int h = wv * 4 + hh;
        bf16x8 q8 = *(const bf16x8*)(qls + h * HDIM + oct * 8);
        const unsigned short* kbase = Kb + (size_t)h * S_LEN * HDIM + oct * 8;
        float p[8];
#pragma unroll
        for (int kg = 0; kg < 8; ++kg) {
            bf16x8 k8 = *(const bf16x8*)(kbase + (size_t)rows[kg] * HDIM);
            float d = 0.f;
#pragma unroll
            for (int e = 0; e < 8; ++e)
                d += bf2f((unsigned short)k8[e]) * bf2f((unsigned short)q8[e]);
            d += __shfl_xor(d, 1);
            d += __shfl_xor(d, 2);
            d += __shfl_xor(d, 4);
            p[kg] = valid[kg] ? d * 0.125f : -INFINITY;
        }
        float m = p[0];
#pragma unroll
        for (int kg = 1; kg < 8; ++kg) m = fmaxf(m, p[kg]);
        m = fmaxf(m, __shfl_xor(m, 8));
        m = fmaxf(m, __shfl_xor(m, 16));
        m = fmaxf(m, __shfl_xor(m, 32));
        float sum = 0.f;
#pragma unroll
        for (int kg = 0; kg < 8; ++kg) { p[kg] = __expf(p[kg] - m); sum += p[kg]; }
        sum += __shfl_xor(sum, 8);
        sum += __shfl_xor(sum, 16);
        sum += __shfl_xor(sum, 32);
        float rs = 1.f / sum;
        const unsigned short* vbase = Vb + (size_t)h * S_LEN * HDIM + oct * 8;
        float facc[8] = {};
#pragma unroll
        for (int kg = 0; kg < 8; ++kg) {
            bf16x8 v8 = *(const bf16x8*)(vbase + (size_t)rows[kg] * HDIM);
            float pw = p[kg] * rs;
#pragma unroll
            for (int e = 0; e < 8; ++e)
                facc[e] += pw * bf2f((unsigned short)v8[e]);
        }
#pragma unroll
        for (int e = 0; e < 8; ++e) {
            facc[e] += __shfl_xor(facc[e], 8);
            facc[e] += __shfl_xor(facc[e], 16);
            facc[e] += __shfl_xor(facc[e], 32);
        }
        if (klo == 0) {
            ushort4 o0 = { f2bf(facc[0]), f2bf(facc[1]), f2bf(facc[2]), f2bf(facc[3]) };
            ushort4 o1 = { f2bf(facc[4]), f2bf(facc[5]), f2bf(facc[6]), f2bf(facc[7]) };
            *(ushort4*)(out + (size_t)t * D_MODEL + h * HDIM + oct * 8) = o0;
            *(ushort4*)(out + (size_t)t * D_MODEL + h * HDIM + oct * 8 + 4) = o1;
        }
    }
}

extern "C" void kernel_launch(void* const* d_in, const int* in_sizes, int n_in,
                              void* d_out, int out_size, void* d_ws, size_t ws_size,
                              hipStream_t stream)
{
    const float* x      = (const float*)d_in[0];
    const float* w_qkv  = (const float*)d_in[1];
    const float* w_o    = (const float*)d_in[2];
    const float* ffn_w1 = (const float*)d_in[3];
    const float* ffn_b1 = (const float*)d_in[4];
    const float* ffn_w2 = (const float*)d_in[5];
    const float* ffn_b2 = (const float*)d_in[6];
    const float* ln1_g  = (const float*)d_in[7];
    const float* ln1_b  = (const float*)d_in[8];
    const float* ln2_g  = (const float*)d_in[9];
    const float* ln2_b  = (const float*)d_in[10];
    const float* idx_wq = (const float*)d_in[11];
    const float* idx_wk = (const float*)d_in[12];
    const float* idx_ww = (const float*)d_in[13];
    float* outp = (float*)d_out;

    const size_t MB = 1ull << 20;
    char* ws = (char*)d_ws;
    // [0,8)    normx fp32 -> attno_bf (4MB) -> Pf2 (32MB ffn2 partials)
    // [8,12)   normx_bf / h2_bf
    // [12,24)  qkv_bf (dead after rope_pack) -> topidx/topcnt
    // [24,32)  wqkv_t/wo_t    [32,40) w1_t   [40,48) w2_t
    // [48,60)  Qb/Kb/Vb
    // [60,76)  ctab/stab (dead after rope_pack) -> P_idx (11MB) -> scoresb -> Pwo -> ffn1_bf
    // [76,79)  QIW   [79,80.5) Wc
    float*          normx    = (float*)(ws + 0);
    unsigned short* attno_bf = (unsigned short*)(ws + 0);
    float*          Pf2      = (float*)(ws + 0);
    unsigned short* normx_bf = (unsigned short*)(ws + 8 * MB);
    unsigned short* h2_bf    = normx_bf;
    unsigned short* qkv_bf   = (unsigned short*)(ws + 12 * MB);
    int*            topidx   = (int*)(ws + 12 * MB);
    int*            topcnt   = (int*)(ws + 12 * MB + 512 * 1024);
    unsigned short* wqkv_t   = (unsigned short*)(ws + 24 * MB);
    unsigned short* wo_t     = (unsigned short*)(ws + 30 * MB);
    unsigned short* w1_t     = (unsigned short*)(ws + 32 * MB);
    unsigned short* w2_t     = (unsigned short*)(ws + 40 * MB);
    unsigned short* Qb       = (unsigned short*)(ws + 48 * MB);
    unsigned short* Kb       = (unsigned short*)(ws + 52 * MB);
    unsigned short* Vb       = (unsigned short*)(ws + 56 * MB);
    float*          ctab     = (float*)(ws + 60 * MB);
    float*          stab     = (float*)(ws + 60 * MB + 256 * 1024);
    float*          P_idx    = (float*)(ws + 60 * MB);      // 4 x 2048*336*4B = 11MB
    float*          scoresb  = (float*)(ws + 60 * MB);
    float*          Pwo      = (float*)(ws + 60 * MB);      // 16MB w_o partials (2 slices)
    unsigned short* ffn1_bf  = (unsigned short*)(ws + 60 * MB);
    float*          QIW      = (float*)(ws + 76 * MB);
    float*          Wc       = (float*)(ws + 79 * MB);

    dim3 blk256(256);
    auto g64n = [](int N, int M) { return dim3(N / 64, M / 128); };

    // 1. LN1 -> fp32 (indexer) + bf16 (qkv gemm)
    ln_kernel<<<S_LEN, blk256, 0, stream>>>(x, ln1_g, ln1_b, normx, normx_bf);
    // 2. rope tables + weight prep
    rope_table_kernel<<<(S_LEN * 32) / 256, blk256, 0, stream>>>(ctab, stab);
    wtrans_kernel<<<dim3(3 * D_MODEL / 32, D_MODEL / 32), blk256, 0, stream>>>(w_qkv, wqkv_t, D_MODEL, 3 * D_MODEL);
    wtrans_kernel<<<dim3(D_MODEL / 32, D_MODEL / 32), blk256, 0, stream>>>(w_o, wo_t, D_MODEL, D_MODEL);
    wtrans_kernel<<<dim3(DFF / 32, D_MODEL / 32), blk256, 0, stream>>>(ffn_w1, w1_t, D_MODEL, DFF);
    wtrans_kernel<<<dim3(D_MODEL / 32, DFF / 32), blk256, 0, stream>>>(ffn_w2, w2_t, DFF, D_MODEL);
    wpack_kernel<<<(D_MODEL * NIDX + 255) / 256, blk256, 0, stream>>>(idx_wq, idx_wk, idx_ww, Wc);
    // 3. qkv = norm_x @ w_qkv (bf16 out only; 768 blocks)
    gemm_bf16_n64<<<g64n(3 * D_MODEL, S_LEN), blk256, 0, stream>>>(normx_bf, wqkv_t,
        nullptr, qkv_bf, nullptr, nullptr, S_LEN, 3 * D_MODEL, D_MODEL, 0, nullptr, D_MODEL);
    // 4. RoPE + pack Q/K/V (frees qkv_bf + ctab/stab for P_idx)
    rope_pack_kernel<<<S_LEN, dim3(512), 0, stream>>>(qkv_bf, ctab, stab, Qb, Kb, Vb);
    // 5. fused indexer projections (fp32, split-K=4 -> 768 blocks; feeds discrete top-k)
    gemm64<<<dim3((NIDX + 63) / 64, S_LEN / 64, 4), blk256, 0, stream>>>(normx, Wc,
        nullptr, S_LEN, NIDX, D_MODEL, P_idx, D_MODEL / 4);
    kreduce_kernel<<<1024, blk256, 0, stream>>>(P_idx, 4, QIW, nullptr, nullptr, S_LEN, NIDX);
    // 6. indexer scores (overwrites dead P_idx region)
    scores_kernel<<<dim3(64, 64), blk256, 0, stream>>>(QIW, scoresb);
    // 7. top-64 per row (radix select; topidx overlays dead qkv_bf)
    topk_kernel<<<S_LEN, blk256, 0, stream>>>(scoresb, topidx, topcnt);
    // 8. sparse attention -> bf16 (overlays dead normx)
    attn_kernel<<<S_LEN, blk256, 0, stream>>>(Qb, Kb, Vb, topidx, topcnt, attno_bf);
    // 9. x1 = x + attn_out @ w_o  — split-K=2 (512 blocks) into Pwo, then reduce
    gemm_bf16_n64<<<dim3(D_MODEL / 64, S_LEN / 128, 2), blk256, 0, stream>>>(attno_bf, wo_t,
        nullptr, nullptr, nullptr, nullptr, S_LEN, D_MODEL, D_MODEL, 0, Pwo, D_MODEL / 2);
    kreduce_kernel<<<1024, blk256, 0, stream>>>(Pwo, 2, outp, nullptr, x, S_LEN, D_MODEL);
    // 10. h = LN2(x1) -> bf16
    ln_kernel<<<S_LEN, blk256, 0, stream>>>(outp, ln2_g, ln2_b, nullptr, h2_bf);
    // 11. ffn1 = gelu(h @ w1 + b1) -> bf16 (overlays dead Pwo/scoresb; 1024 blocks)
    gemm_bf16_n64<<<g64n(DFF, S_LEN), blk256, 0, stream>>>(h2_bf, w1_t,
        nullptr, ffn1_bf, ffn_b1, nullptr, S_LEN, DFF, D_MODEL, 1, nullptr, D_MODEL);
    // 12. out = x1 + ffn1 @ w2 + b2 — split-K=4 (1024 blocks) into Pf2, then reduce
    gemm_bf16_n64<<<dim3(D_MODEL / 64, S_LEN / 128, 4), blk256, 0, stream>>>(ffn1_bf, w2_t,
        nullptr, nullptr, nullptr, nullptr, S_LEN, D_MODEL, DFF, 0, Pf2, DFF / 4);
    kreduce_kernel<<<1024, blk256, 0, stream>>>(Pf2, 4, outp, ffn_b2, outp, S_LEN, D_MODEL);
}

// Round 9
// 280.610 us; speedup vs baseline: 4.8193x; 1.0705x over previous
//
#include <hip/hip_runtime.h>
#include <math.h>

#define S_LEN 2048
#define D_MODEL 1024
#define NHEAD 16
#define HDIM 64
#define DFF 4096
#define IH 4
#define IDM 64
#define TOPK 64
#define NIDX 336   // 256 qi + 64 ki + 4 wi + 12 pad

typedef float f32x4 __attribute__((ext_vector_type(4)));
typedef short bf16x8 __attribute__((ext_vector_type(8)));

__device__ __forceinline__ unsigned short f2bf(float f) {
    unsigned u = __builtin_bit_cast(unsigned, f);
    u += 0x7fff + ((u >> 16) & 1);
    return (unsigned short)(u >> 16);
}
__device__ __forceinline__ float bf2f(unsigned short us) {
    return __builtin_bit_cast(float, (unsigned)us << 16);
}

__device__ __forceinline__ float gelu_exact(float v) {
    return 0.5f * v * (1.f + erff(v * 0.70710678118654752f));
}

__device__ __forceinline__ void gl_lds16(const void* g, void* l) {
    __builtin_amdgcn_global_load_lds(
        (const __attribute__((address_space(1))) void*)g,
        (__attribute__((address_space(3))) void*)l, 16, 0, 0);
}

// ---------------- LayerNorm: fp32 out (optional) + bf16 out (optional) ----------------
__global__ __launch_bounds__(256) void ln_kernel(const float* __restrict__ x,
    const float* __restrict__ g, const float* __restrict__ b,
    float* __restrict__ outf, unsigned short* __restrict__ outb)
{
    int row = blockIdx.x, tid = threadIdx.x;
    const float4 v = *(const float4*)(x + (size_t)row * D_MODEL + tid * 4);
    float s = v.x + v.y + v.z + v.w;
    float ss = v.x * v.x + v.y * v.y + v.z * v.z + v.w * v.w;
    int lane = tid & 63, wv = tid >> 6;
    for (int o = 32; o; o >>= 1) { s += __shfl_xor(s, o); ss += __shfl_xor(ss, o); }
    __shared__ float rs[4], rss[4];
    if (lane == 0) { rs[wv] = s; rss[wv] = ss; }
    __syncthreads();
    float S = rs[0] + rs[1] + rs[2] + rs[3];
    float SS = rss[0] + rss[1] + rss[2] + rss[3];
    float mean = S * (1.f / D_MODEL);
    float var = SS * (1.f / D_MODEL) - mean * mean;
    float r = rsqrtf(var + 1e-5f);
    float4 gv = *(const float4*)(g + tid * 4);
    float4 bv = *(const float4*)(b + tid * 4);
    float4 o4;
    o4.x = (v.x - mean) * r * gv.x + bv.x;
    o4.y = (v.y - mean) * r * gv.y + bv.y;
    o4.z = (v.z - mean) * r * gv.z + bv.z;
    o4.w = (v.w - mean) * r * gv.w + bv.w;
    if (outf) *(float4*)(outf + (size_t)row * D_MODEL + tid * 4) = o4;
    if (outb) {
        ushort4 u4 = { f2bf(o4.x), f2bf(o4.y), f2bf(o4.z), f2bf(o4.w) };
        *(ushort4*)(outb + (size_t)row * D_MODEL + tid * 4) = u4;
    }
}

// ---------------- Weight convert + transpose: fp32 [K][N] -> bf16 [N][K] ----------------
__global__ __launch_bounds__(256) void wtrans_kernel(const float* __restrict__ in,
    unsigned short* __restrict__ out, int K, int N)
{
    __shared__ float t[32][33];
    int k0 = blockIdx.y * 32, n0 = blockIdx.x * 32;
    int tid = threadIdx.x;
    int r = tid >> 5, c = tid & 31;
#pragma unroll
    for (int p = 0; p < 4; ++p)
        t[r + p * 8][c] = in[(size_t)(k0 + r + p * 8) * N + n0 + c];
    __syncthreads();
#pragma unroll
    for (int p = 0; p < 4; ++p)
        out[(size_t)(n0 + r + p * 8) * K + k0 + c] = f2bf(t[c][r + p * 8]);
}

// ---------------- Pack indexer weights into one fp32 [1024][336] ----------------
__global__ __launch_bounds__(256) void wpack_kernel(const float* __restrict__ wq,
    const float* __restrict__ wk, const float* __restrict__ ww, float* __restrict__ Wc)
{
    int idx = blockIdx.x * 256 + threadIdx.x;
    if (idx >= D_MODEL * NIDX) return;
    int r = idx / NIDX, c = idx % NIDX;
    float v = 0.f;
    if (c < 256) v = wq[r * 256 + c];
    else if (c < 320) v = wk[r * 64 + (c - 256)];
    else if (c < 324) v = ww[r * 4 + (c - 320)];
    Wc[idx] = v;
}

// ---------------- bf16 MFMA GEMM, 128x64 tile (grid-doubling variant) ----------------
// 4 waves; wave w computes rows [bm+32w, bm+32w+32) x all 64 cols. acc[2][4].
// Split-K: if P != nullptr, block z does K-chunk -> raw fp32 partials at P + z*M*N.
__global__ __launch_bounds__(256) void gemm_bf16_n64(
    const unsigned short* __restrict__ A, const unsigned short* __restrict__ Bt,
    float* __restrict__ C, unsigned short* __restrict__ Cb,
    const float* __restrict__ bias, const float* __restrict__ R,
    int M, int N, int K, int act,
    float* __restrict__ P, int kchunk)
{
    __shared__ __attribute__((aligned(16))) unsigned short As[128 * 32];
    __shared__ __attribute__((aligned(16))) unsigned short Bs[64 * 32];
    int tid = threadIdx.x;
    int bm = blockIdx.y * 128, bn = blockIdx.x * 64;
    int wid = tid >> 6, lane = tid & 63;
    int wm = wid * 32;
    const unsigned short* Ab = A + (size_t)bm * K;
    const unsigned short* Bb = Bt + (size_t)bn * K;
    f32x4 acc[2][4];
#pragma unroll
    for (int i = 0; i < 2; ++i)
#pragma unroll
        for (int j = 0; j < 4; ++j)
            acc[i][j] = (f32x4){0.f, 0.f, 0.f, 0.f};

    int kbeg = blockIdx.z * kchunk;
    int kend = kbeg + kchunk;
    int fr = lane & 15, fk = (lane >> 4) * 8;
    int e0 = tid * 8;                 // 2048 elems per pass
    int r0 = e0 >> 5, c0 = e0 & 31;
    for (int k0 = kbeg; k0 < kend; k0 += 32) {
        gl_lds16(Ab + (size_t)r0 * K + k0 + c0, As + e0);
        gl_lds16(Ab + (size_t)(r0 + 64) * K + k0 + c0, As + e0 + 2048);
        gl_lds16(Bb + (size_t)r0 * K + k0 + c0, Bs + e0);
        __syncthreads();
        bf16x8 af[2], bfv[4];
#pragma unroll
        for (int mi = 0; mi < 2; ++mi)
            af[mi] = *(const bf16x8*)&As[(wm + mi * 16 + fr) * 32 + fk];
#pragma unroll
        for (int ni = 0; ni < 4; ++ni)
            bfv[ni] = *(const bf16x8*)&Bs[(ni * 16 + fr) * 32 + fk];
#pragma unroll
        for (int mi = 0; mi < 2; ++mi)
#pragma unroll
            for (int ni = 0; ni < 4; ++ni)
                acc[mi][ni] = __builtin_amdgcn_mfma_f32_16x16x32_bf16(
                    af[mi], bfv[ni], acc[mi][ni], 0, 0, 0);
        __syncthreads();
    }
    int cl = lane & 15, rh = (lane >> 4) * 4;
    if (P) {
        float* Pz = P + (size_t)blockIdx.z * M * N;
#pragma unroll
        for (int mi = 0; mi < 2; ++mi)
#pragma unroll
            for (int ni = 0; ni < 4; ++ni) {
                int col = bn + ni * 16 + cl;
#pragma unroll
                for (int r = 0; r < 4; ++r) {
                    int row = bm + wm + mi * 16 + rh + r;
                    Pz[(size_t)row * N + col] = acc[mi][ni][r];
                }
            }
        return;
    }
#pragma unroll
    for (int mi = 0; mi < 2; ++mi) {
#pragma unroll
        for (int ni = 0; ni < 4; ++ni) {
            int col = bn + ni * 16 + cl;
            float bv = bias ? bias[col] : 0.f;
#pragma unroll
            for (int r = 0; r < 4; ++r) {
                int row = bm + wm + mi * 16 + rh + r;
                float v = acc[mi][ni][r] + bv;
                if (act) v = gelu_exact(v);
                size_t off = (size_t)row * N + col;
                if (R) v += R[off];
                if (C) C[off] = v;
                if (Cb) Cb[off] = f2bf(v);
            }
        }
    }
}

// ---------------- Split-K reduce: C = sum_z P[z] + bias + R (float4 vectorized) ----------------
__global__ __launch_bounds__(256) void kreduce_kernel(const float* __restrict__ P,
    int nslice, float* __restrict__ C, const float* __restrict__ bias,
    const float* __restrict__ R, int M, int N)
{
    size_t total4 = (size_t)M * N / 4;
    size_t stride = (size_t)gridDim.x * 256;
    for (size_t i4 = blockIdx.x * 256 + threadIdx.x; i4 < total4; i4 += stride) {
        size_t off = i4 * 4;
        float4 v = *(const float4*)(P + off);
        for (int z = 1; z < nslice; ++z) {
            float4 p = *(const float4*)(P + (size_t)z * M * N + off);
            v.x += p.x; v.y += p.y; v.z += p.z; v.w += p.w;
        }
        if (bias) {
            float4 b4 = *(const float4*)(bias + (off % N));
            v.x += b4.x; v.y += b4.y; v.z += b4.z; v.w += b4.w;
        }
        if (R) {
            float4 r4 = *(const float4*)(R + off);
            v.x += r4.x; v.y += r4.y; v.z += r4.z; v.w += r4.w;
        }
        *(float4*)(C + off) = v;
    }
}

// ---------------- Generic fp32 GEMM (indexer path): C[M,N] = A[M,K]@B[K,N] ----------------
// Split-K: if P != nullptr, block z does K-chunk [z*kchunk, (z+1)*kchunk) -> P + z*M*N.
__global__ __launch_bounds__(256) void gemm64(const float* __restrict__ A,
    const float* __restrict__ B, float* __restrict__ C,
    int M, int N, int K,
    float* __restrict__ P, int kchunk)
{
    __shared__ float As[16][68];
    __shared__ float Bs[16][68];
    int tid = threadIdx.x;
    int bm = blockIdx.y, bn = blockIdx.x;
    int tx = tid & 15, ty = tid >> 4;
    int arow = tid >> 2;
    int acol = (tid & 3) << 2;
    int brow = tid >> 4;
    int bcol = (tid & 15) << 2;
    const float* Abase = A + (size_t)(bm * 64 + arow) * K + acol;
    float c[4][4] = {};
    int kbeg = blockIdx.z * kchunk;
    int kend = kbeg + kchunk;
    for (int k0 = kbeg; k0 < kend; k0 += 16) {
        float4 av = *(const float4*)(Abase + k0);
        As[acol + 0][arow] = av.x;
        As[acol + 1][arow] = av.y;
        As[acol + 2][arow] = av.z;
        As[acol + 3][arow] = av.w;
        int gcol = bn * 64 + bcol;
        const float* Bb = B + (size_t)(k0 + brow) * N;
        float4 bv;
        if (gcol + 3 < N) {
            bv = *(const float4*)(Bb + gcol);
        } else {
            bv.x = (gcol + 0 < N) ? Bb[gcol + 0] : 0.f;
            bv.y = (gcol + 1 < N) ? Bb[gcol + 1] : 0.f;
            bv.z = (gcol + 2 < N) ? Bb[gcol + 2] : 0.f;
            bv.w = (gcol + 3 < N) ? Bb[gcol + 3] : 0.f;
        }
        *(float4*)&Bs[brow][bcol] = bv;
        __syncthreads();
#pragma unroll
        for (int kk = 0; kk < 16; ++kk) {
            float4 a4 = *(const float4*)&As[kk][ty * 4];
            float4 b4 = *(const float4*)&Bs[kk][tx * 4];
            float av4[4] = { a4.x, a4.y, a4.z, a4.w };
            float bv4[4] = { b4.x, b4.y, b4.z, b4.w };
#pragma unroll
            for (int i = 0; i < 4; ++i)
#pragma unroll
                for (int j = 0; j < 4; ++j)
                    c[i][j] += av4[i] * bv4[j];
        }
        __syncthreads();
    }
    float* Out = P ? (P + (size_t)blockIdx.z * M * N) : C;
#pragma unroll
    for (int i = 0; i < 4; ++i) {
        int row = bm * 64 + ty * 4 + i;
#pragma unroll
        for (int j = 0; j < 4; ++j) {
            int col = bn * 64 + tx * 4 + j;
            if (col < N)
                Out[(size_t)row * N + col] = c[i][j];
        }
    }
}

// ---------------- RoPE table ----------------
__global__ __launch_bounds__(256) void rope_table_kernel(float* __restrict__ ct, float* __restrict__ st)
{
    int g = blockIdx.x * 256 + threadIdx.x;
    int t = g >> 5, i = g & 31;
    float theta = powf(10000.f, -(float)i / 32.f);
    float ang = (float)t * theta;
    ct[g] = cosf(ang);
    st[g] = sinf(ang);
}

// ---------------- RoPE + pack: qkv bf16 [S][3072] -> Qb [S][1024], Kb/Vb [H][S][64] ----------------
__global__ __launch_bounds__(512) void rope_pack_kernel(
    const unsigned short* __restrict__ qkvb,
    const float* __restrict__ ct, const float* __restrict__ st,
    unsigned short* __restrict__ Qb, unsigned short* __restrict__ Kb,
    unsigned short* __restrict__ Vb)
{
    int t = blockIdx.x, tid = threadIdx.x;
    int h = tid >> 5, i = tid & 31;
    float c = ct[t * 32 + i], s = st[t * 32 + i];
    const unsigned short* base = qkvb + (size_t)t * (3 * D_MODEL);
    ushort2 q2 = *(const ushort2*)(base + h * HDIM + 2 * i);
    float q0 = bf2f(q2.x), q1 = bf2f(q2.y);
    ushort2 qo = { f2bf(q0 * c - q1 * s), f2bf(q1 * c + q0 * s) };
    *(ushort2*)(Qb + (size_t)t * D_MODEL + h * HDIM + 2 * i) = qo;
    ushort2 k2 = *(const ushort2*)(base + D_MODEL + h * HDIM + 2 * i);
    float k0 = bf2f(k2.x), k1 = bf2f(k2.y);
    ushort2 ko = { f2bf(k0 * c - k1 * s), f2bf(k1 * c + k0 * s) };
    *(ushort2*)(Kb + ((size_t)h * S_LEN + t) * HDIM + 2 * i) = ko;
    ushort2 v2 = *(const ushort2*)(base + 2 * D_MODEL + 2 * tid);
    int vh = tid >> 5, vd = (2 * tid) & 63;
    *(ushort2*)(Vb + ((size_t)vh * S_LEN + t) * HDIM + vd) = v2;
}

// ---------------- Indexer scores (fp32, fused QIW layout, stride 336) ----------------
__global__ __launch_bounds__(256) void scores_kernel(const float* __restrict__ QIW,
    float* __restrict__ scores)
{
    int t0 = blockIdx.y * 32, s0 = blockIdx.x * 32;
    if (s0 > t0 + 31) return;
    __shared__ float qis[32][256];
    __shared__ float kis[32][65];
    __shared__ float wis[32][4];
    int tid = threadIdx.x;
#pragma unroll
    for (int l = 0; l < 8; ++l) {
        int idx = l * 256 + tid;
        int r = idx >> 6, c = (idx & 63) << 2;
        *(float4*)&qis[r][c] = *(const float4*)(QIW + (size_t)(t0 + r) * NIDX + c);
    }
#pragma unroll
    for (int l = 0; l < 8; ++l) {
        int idx = l * 256 + tid;
        int r = idx >> 6, c = idx & 63;
        kis[r][c] = QIW[(size_t)(s0 + r) * NIDX + 256 + c];
    }
    if (tid < 32) *(float4*)&wis[tid][0] = *(const float4*)(QIW + (size_t)(t0 + tid) * NIDX + 320);
    __syncthreads();
    int sl = tid & 31;
    int tb = (tid >> 5) * 4;
    float acc[4] = { 0.f, 0.f, 0.f, 0.f };
#pragma unroll
    for (int h = 0; h < 4; ++h) {
        float dots[4] = { 0.f, 0.f, 0.f, 0.f };
        for (int d = 0; d < 64; ++d) {
            float kv = kis[sl][d];
#pragma unroll
            for (int i = 0; i < 4; ++i)
                dots[i] += qis[tb + i][h * 64 + d] * kv;
        }
#pragma unroll
        for (int i = 0; i < 4; ++i)
            acc[i] += wis[tb + i][h] * fmaxf(dots[i], 0.f);
    }
#pragma unroll
    for (int i = 0; i < 4; ++i)
        scores[(size_t)(t0 + tb + i) * S_LEN + s0 + sl] = acc[i];
}

// ---------------- Top-K via radix select (exact lax.top_k set semantics) ----------------
__global__ __launch_bounds__(256) void topk_kernel(const float* __restrict__ scores,
    int* __restrict__ topidx, int* __restrict__ topcnt)
{
    int t = blockIdx.x, tid = threadIdx.x;
    int n = t + 1;
    if (n <= TOPK) {
        if (tid < n) topidx[t * TOPK + tid] = tid;
        if (tid == 0) topcnt[t] = n;
        return;
    }
    __shared__ unsigned sc[S_LEN];
    __shared__ unsigned hist[256];
    __shared__ int selbin_s;
    __shared__ int cnt_out;
    __shared__ unsigned wsum[4];
    for (int j = tid; j < n; j += 256) {
        unsigned u = __builtin_bit_cast(unsigned, scores[(size_t)t * S_LEN + j]);
        sc[j] = (u & 0x80000000u) ? ~u : (u | 0x80000000u);
    }
    if (tid == 0) cnt_out = 0;
    int lane = tid & 63, wv = tid >> 6;
    unsigned prefix = 0;
    int kk = TOPK;
#pragma unroll
    for (int round = 0; round < 4; ++round) {
        int shift_pref = 32 - 8 * round;
        int shift_bin = 24 - 8 * round;
        hist[tid] = 0;
        __syncthreads();
        for (int j = tid; j < n; j += 256) {
            unsigned v = sc[j];
            if ((((unsigned long long)(v ^ prefix)) >> shift_pref) == 0)
                atomicAdd(&hist[(v >> shift_bin) & 0xff], 1u);
        }
        __syncthreads();
        if (wv == 0) {
            unsigned h0 = hist[4 * lane], h1 = hist[4 * lane + 1];
            unsigned h2 = hist[4 * lane + 2], h3 = hist[4 * lane + 3];
            unsigned s3 = h3, s2 = h2 + s3, s1 = h1 + s2, s0 = h0 + s1;
            unsigned acc = s0;
            for (int off = 1; off < 64; off <<= 1) {
                unsigned o = __shfl_down(acc, off);
                if (lane + off < 64) acc += o;
            }
            unsigned above = acc - s0;
            hist[4 * lane]     = s0 + above;
            hist[4 * lane + 1] = s1 + above;
            hist[4 * lane + 2] = s2 + above;
            hist[4 * lane + 3] = s3 + above;
        }
        __syncthreads();
        {
            unsigned sufb = hist[tid];
            unsigned sufn = (tid < 255) ? hist[tid + 1] : 0u;
            if (sufb >= (unsigned)kk && sufn < (unsigned)kk)
                selbin_s = tid;
        }
        __syncthreads();
        int b = selbin_s;
        unsigned above = (b < 255) ? hist[b + 1] : 0u;
        kk -= (int)above;
        prefix |= ((unsigned)b) << shift_bin;
        __syncthreads();
    }
    unsigned T = prefix;
    int chunk = (n + 255) >> 8;
    int jb = tid * chunk;
    int je = jb + chunk; if (je > n) je = n;
    int ties = 0;
    for (int j = jb; j < je; ++j) {
        unsigned v = sc[j];
        if (v > T) { int o = atomicAdd(&cnt_out, 1); topidx[t * TOPK + o] = j; }
        else if (v == T) ++ties;
    }
    unsigned inc = (unsigned)ties;
    for (int off = 1; off < 64; off <<= 1) {
        unsigned o = __shfl_up(inc, off);
        if (lane >= off) inc += o;
    }
    if (lane == 63) wsum[wv] = inc;
    __syncthreads();
    unsigned woff = 0;
    for (int w = 0; w < wv; ++w) woff += wsum[w];
    int rank = (int)(woff + inc) - ties;
    for (int j = jb; j < je && rank < kk; ++j) {
        if (sc[j] == T) {
            int o = atomicAdd(&cnt_out, 1);
            topidx[t * TOPK + o] = j;
            ++rank;
        }
    }
    if (tid == 0) topcnt[t] = TOPK;
}

// ---------------- Sparse SDPA v4: one head per wave, grid (S, 4) ----------------
// Same coalesced (key,dim-octet) lane map as v3, but 4x the wave count: each wave
// owns one head, so gather/shuffle latency is hidden by TLP instead of in-wave ILP.
__global__ __launch_bounds__(256) void attn_kernel(
    const unsigned short* __restrict__ Qb, const unsigned short* __restrict__ Kb,
    const unsigned short* __restrict__ Vb,
    const int* __restrict__ topidx, const int* __restrict__ topcnt,
    unsigned short* __restrict__ out)
{
    int t = blockIdx.x, tid = threadIdx.x;
    __shared__ int sel[TOPK];
    if (tid < TOPK) sel[tid] = topidx[t * TOPK + tid];
    __syncthreads();
    int cnt = topcnt[t];
    int lane = tid & 63, wv = tid >> 6;
    int h = blockIdx.y * 4 + wv;
    int klo = lane >> 3, oct = lane & 7;
    int rows[8];
    bool valid[8];
#pragma unroll
    for (int kg = 0; kg < 8; ++kg) {
        int k = kg * 8 + klo;
        valid[kg] = (k < cnt);
        rows[kg] = sel[valid[kg] ? k : 0];
    }
    // q fragment: lanes sharing oct read the same 16B (L1 broadcast)
    bf16x8 q8 = *(const bf16x8*)(Qb + (size_t)t * D_MODEL + h * HDIM + oct * 8);
    float qf[8];
#pragma unroll
    for (int e = 0; e < 8; ++e) qf[e] = bf2f((unsigned short)q8[e]);

    const unsigned short* kbase = Kb + (size_t)h * S_LEN * HDIM + oct * 8;
    float p[8];
#pragma unroll
    for (int kg = 0; kg < 8; ++kg) {
        bf16x8 k8 = *(const bf16x8*)(kbase + (size_t)rows[kg] * HDIM);
        float d = 0.f;
#pragma unroll
        for (int e = 0; e < 8; ++e)
            d += bf2f((unsigned short)k8[e]) * qf[e];
        d += __shfl_xor(d, 1);
        d += __shfl_xor(d, 2);
        d += __shfl_xor(d, 4);
        p[kg] = valid[kg] ? d * 0.125f : -INFINITY;
    }
    float m = p[0];
#pragma unroll
    for (int kg = 1; kg < 8; ++kg) m = fmaxf(m, p[kg]);
    m = fmaxf(m, __shfl_xor(m, 8));
    m = fmaxf(m, __shfl_xor(m, 16));
    m = fmaxf(m, __shfl_xor(m, 32));
    float sum = 0.f;
#pragma unroll
    for (int kg = 0; kg < 8; ++kg) { p[kg] = __expf(p[kg] - m); sum += p[kg]; }
    sum += __shfl_xor(sum, 8);
    sum += __shfl_xor(sum, 16);
    sum += __shfl_xor(sum, 32);
    float rs = 1.f / sum;
    const unsigned short* vbase = Vb + (size_t)h * S_LEN * HDIM + oct * 8;
    float facc[8] = {};
#pragma unroll
    for (int kg = 0; kg < 8; ++kg) {
        bf16x8 v8 = *(const bf16x8*)(vbase + (size_t)rows[kg] * HDIM);
        float pw = p[kg] * rs;
#pragma unroll
        for (int e = 0; e < 8; ++e)
            facc[e] += pw * bf2f((unsigned short)v8[e]);
    }
#pragma unroll
    for (int e = 0; e < 8; ++e) {
        facc[e] += __shfl_xor(facc[e], 8);
        facc[e] += __shfl_xor(facc[e], 16);
        facc[e] += __shfl_xor(facc[e], 32);
    }
    if (klo == 0) {
        ushort4 o0 = { f2bf(facc[0]), f2bf(facc[1]), f2bf(facc[2]), f2bf(facc[3]) };
        ushort4 o1 = { f2bf(facc[4]), f2bf(facc[5]), f2bf(facc[6]), f2bf(facc[7]) };
        *(ushort4*)(out + (size_t)t * D_MODEL + h * HDIM + oct * 8) = o0;
        *(ushort4*)(out + (size_t)t * D_MODEL + h * HDIM + oct * 8 + 4) = o1;
    }
}

extern "C" void kernel_launch(void* const* d_in, const int* in_sizes, int n_in,
                              void* d_out, int out_size, void* d_ws, size_t ws_size,
                              hipStream_t stream)
{
    const float* x      = (const float*)d_in[0];
    const float* w_qkv  = (const float*)d_in[1];
    const float* w_o    = (const float*)d_in[2];
    const float* ffn_w1 = (const float*)d_in[3];
    const float* ffn_b1 = (const float*)d_in[4];
    const float* ffn_w2 = (const float*)d_in[5];
    const float* ffn_b2 = (const float*)d_in[6];
    const float* ln1_g  = (const float*)d_in[7];
    const float* ln1_b  = (const float*)d_in[8];
    const float* ln2_g  = (const float*)d_in[9];
    const float* ln2_b  = (const float*)d_in[10];
    const float* idx_wq = (const float*)d_in[11];
    const float* idx_wk = (const float*)d_in[12];
    const float* idx_ww = (const float*)d_in[13];
    float* outp = (float*)d_out;

    const size_t MB = 1ull << 20;
    char* ws = (char*)d_ws;
    // [0,8)    normx fp32 -> attno_bf (4MB) -> Pf2 (32MB ffn2 partials)
    // [8,12)   normx_bf / h2_bf
    // [12,24)  qkv_bf (dead after rope_pack) -> topidx/topcnt
    // [24,32)  wqkv_t/wo_t    [32,40) w1_t   [40,48) w2_t
    // [48,60)  Qb/Kb/Vb
    // [60,76)  ctab/stab (dead after rope_pack) -> P_idx (11MB) -> scoresb -> Pwo -> ffn1_bf
    // [76,79)  QIW   [79,80.5) Wc
    float*          normx    = (float*)(ws + 0);
    unsigned short* attno_bf = (unsigned short*)(ws + 0);
    float*          Pf2      = (float*)(ws + 0);
    unsigned short* normx_bf = (unsigned short*)(ws + 8 * MB);
    unsigned short* h2_bf    = normx_bf;
    unsigned short* qkv_bf   = (unsigned short*)(ws + 12 * MB);
    int*            topidx   = (int*)(ws + 12 * MB);
    int*            topcnt   = (int*)(ws + 12 * MB + 512 * 1024);
    unsigned short* wqkv_t   = (unsigned short*)(ws + 24 * MB);
    unsigned short* wo_t     = (unsigned short*)(ws + 30 * MB);
    unsigned short* w1_t     = (unsigned short*)(ws + 32 * MB);
    unsigned short* w2_t     = (unsigned short*)(ws + 40 * MB);
    unsigned short* Qb       = (unsigned short*)(ws + 48 * MB);
    unsigned short* Kb       = (unsigned short*)(ws + 52 * MB);
    unsigned short* Vb       = (unsigned short*)(ws + 56 * MB);
    float*          ctab     = (float*)(ws + 60 * MB);
    float*          stab     = (float*)(ws + 60 * MB + 256 * 1024);
    float*          P_idx    = (float*)(ws + 60 * MB);      // 4 x 2048*336*4B = 11MB
    float*          scoresb  = (float*)(ws + 60 * MB);
    float*          Pwo      = (float*)(ws + 60 * MB);      // 16MB w_o partials (2 slices)
    unsigned short* ffn1_bf  = (unsigned short*)(ws + 60 * MB);
    float*          QIW      = (float*)(ws + 76 * MB);
    float*          Wc       = (float*)(ws + 79 * MB);

    dim3 blk256(256);
    auto g64n = [](int N, int M) { return dim3(N / 64, M / 128); };

    // 1. LN1 -> fp32 (indexer) + bf16 (qkv gemm)
    ln_kernel<<<S_LEN, blk256, 0, stream>>>(x, ln1_g, ln1_b, normx, normx_bf);
    // 2. rope tables + weight prep
    rope_table_kernel<<<(S_LEN * 32) / 256, blk256, 0, stream>>>(ctab, stab);
    wtrans_kernel<<<dim3(3 * D_MODEL / 32, D_MODEL / 32), blk256, 0, stream>>>(w_qkv, wqkv_t, D_MODEL, 3 * D_MODEL);
    wtrans_kernel<<<dim3(D_MODEL / 32, D_MODEL / 32), blk256, 0, stream>>>(w_o, wo_t, D_MODEL, D_MODEL);
    wtrans_kernel<<<dim3(DFF / 32, D_MODEL / 32), blk256, 0, stream>>>(ffn_w1, w1_t, D_MODEL, DFF);
    wtrans_kernel<<<dim3(D_MODEL / 32, DFF / 32), blk256, 0, stream>>>(ffn_w2, w2_t, DFF, D_MODEL);
    wpack_kernel<<<(D_MODEL * NIDX + 255) / 256, blk256, 0, stream>>>(idx_wq, idx_wk, idx_ww, Wc);
    // 3. qkv = norm_x @ w_qkv (bf16 out only; 768 blocks)
    gemm_bf16_n64<<<g64n(3 * D_MODEL, S_LEN), blk256, 0, stream>>>(normx_bf, wqkv_t,
        nullptr, qkv_bf, nullptr, nullptr, S_LEN, 3 * D_MODEL, D_MODEL, 0, nullptr, D_MODEL);
    // 4. RoPE + pack Q/K/V (frees qkv_bf + ctab/stab for P_idx)
    rope_pack_kernel<<<S_LEN, dim3(512), 0, stream>>>(qkv_bf, ctab, stab, Qb, Kb, Vb);
    // 5. fused indexer projections (fp32, split-K=4 -> 768 blocks; feeds discrete top-k)
    gemm64<<<dim3((NIDX + 63) / 64, S_LEN / 64, 4), blk256, 0, stream>>>(normx, Wc,
        nullptr, S_LEN, NIDX, D_MODEL, P_idx, D_MODEL / 4);
    kreduce_kernel<<<1024, blk256, 0, stream>>>(P_idx, 4, QIW, nullptr, nullptr, S_LEN, NIDX);
    // 6. indexer scores (overwrites dead P_idx region)
    scores_kernel<<<dim3(64, 64), blk256, 0, stream>>>(QIW, scoresb);
    // 7. top-64 per row (radix select; topidx overlays dead qkv_bf)
    topk_kernel<<<S_LEN, blk256, 0, stream>>>(scoresb, topidx, topcnt);
    // 8. sparse attention -> bf16 (one head per wave; overlays dead normx)
    attn_kernel<<<dim3(S_LEN, 4), blk256, 0, stream>>>(Qb, Kb, Vb, topidx, topcnt, attno_bf);
    // 9. x1 = x + attn_out @ w_o  — split-K=2 (512 blocks) into Pwo, then reduce
    gemm_bf16_n64<<<dim3(D_MODEL / 64, S_LEN / 128, 2), blk256, 0, stream>>>(attno_bf, wo_t,
        nullptr, nullptr, nullptr, nullptr, S_LEN, D_MODEL, D_MODEL, 0, Pwo, D_MODEL / 2);
    kreduce_kernel<<<1024, blk256, 0, stream>>>(Pwo, 2, outp, nullptr, x, S_LEN, D_MODEL);
    // 10. h = LN2(x1) -> bf16
    ln_kernel<<<S_LEN, blk256, 0, stream>>>(outp, ln2_g, ln2_b, nullptr, h2_bf);
    // 11. ffn1 = gelu(h @ w1 + b1) -> bf16 (overlays dead Pwo/scoresb; 1024 blocks)
    gemm_bf16_n64<<<g64n(DFF, S_LEN), blk256, 0, stream>>>(h2_bf, w1_t,
        nullptr, ffn1_bf, ffn_b1, nullptr, S_LEN, DFF, D_MODEL, 1, nullptr, D_MODEL);
    // 12. out = x1 + ffn1 @ w2 + b2 — split-K=4 (1024 blocks) into Pf2, then reduce
    gemm_bf16_n64<<<dim3(D_MODEL / 64, S_LEN / 128, 4), blk256, 0, stream>>>(ffn1_bf, w2_t,
        nullptr, nullptr, nullptr, nullptr, S_LEN, D_MODEL, DFF, 0, Pf2, DFF / 4);
    kreduce_kernel<<<1024, blk256, 0, stream>>>(Pf2, 4, outp, ffn_b2, outp, S_LEN, D_MODEL);
}

// Round 10
// 276.371 us; speedup vs baseline: 4.8932x; 1.0153x over previous
//
#include <hip/hip_runtime.h>
#include <math.h>

#define S_LEN 2048
#define D_MODEL 1024
#define NHEAD 16
#define HDIM 64
#define DFF 4096
#define IH 4
#define IDM 64
#define TOPK 64
#define NIDX 336   // 256 qi + 64 ki + 4 wi + 12 pad

typedef float f32x4 __attribute__((ext_vector_type(4)));
typedef short bf16x8 __attribute__((ext_vector_type(8)));

__device__ __forceinline__ unsigned short f2bf(float f) {
    unsigned u = __builtin_bit_cast(unsigned, f);
    u += 0x7fff + ((u >> 16) & 1);
    return (unsigned short)(u >> 16);
}
__device__ __forceinline__ float bf2f(unsigned short us) {
    return __builtin_bit_cast(float, (unsigned)us << 16);
}

__device__ __forceinline__ float gelu_exact(float v) {
    return 0.5f * v * (1.f + erff(v * 0.70710678118654752f));
}

__device__ __forceinline__ void gl_lds16(const void* g, void* l) {
    __builtin_amdgcn_global_load_lds(
        (const __attribute__((address_space(1))) void*)g,
        (__attribute__((address_space(3))) void*)l, 16, 0, 0);
}

// ---------------- LayerNorm: fp32 out (optional) + bf16 out (optional) ----------------
__global__ __launch_bounds__(256) void ln_kernel(const float* __restrict__ x,
    const float* __restrict__ g, const float* __restrict__ b,
    float* __restrict__ outf, unsigned short* __restrict__ outb)
{
    int row = blockIdx.x, tid = threadIdx.x;
    const float4 v = *(const float4*)(x + (size_t)row * D_MODEL + tid * 4);
    float s = v.x + v.y + v.z + v.w;
    float ss = v.x * v.x + v.y * v.y + v.z * v.z + v.w * v.w;
    int lane = tid & 63, wv = tid >> 6;
    for (int o = 32; o; o >>= 1) { s += __shfl_xor(s, o); ss += __shfl_xor(ss, o); }
    __shared__ float rs[4], rss[4];
    if (lane == 0) { rs[wv] = s; rss[wv] = ss; }
    __syncthreads();
    float S = rs[0] + rs[1] + rs[2] + rs[3];
    float SS = rss[0] + rss[1] + rss[2] + rss[3];
    float mean = S * (1.f / D_MODEL);
    float var = SS * (1.f / D_MODEL) - mean * mean;
    float r = rsqrtf(var + 1e-5f);
    float4 gv = *(const float4*)(g + tid * 4);
    float4 bv = *(const float4*)(b + tid * 4);
    float4 o4;
    o4.x = (v.x - mean) * r * gv.x + bv.x;
    o4.y = (v.y - mean) * r * gv.y + bv.y;
    o4.z = (v.z - mean) * r * gv.z + bv.z;
    o4.w = (v.w - mean) * r * gv.w + bv.w;
    if (outf) *(float4*)(outf + (size_t)row * D_MODEL + tid * 4) = o4;
    if (outb) {
        ushort4 u4 = { f2bf(o4.x), f2bf(o4.y), f2bf(o4.z), f2bf(o4.w) };
        *(ushort4*)(outb + (size_t)row * D_MODEL + tid * 4) = u4;
    }
}

// ---------------- Weight convert + transpose: fp32 [K][N] -> bf16 [N][K] ----------------
__global__ __launch_bounds__(256) void wtrans_kernel(const float* __restrict__ in,
    unsigned short* __restrict__ out, int K, int N)
{
    __shared__ float t[32][33];
    int k0 = blockIdx.y * 32, n0 = blockIdx.x * 32;
    int tid = threadIdx.x;
    int r = tid >> 5, c = tid & 31;
#pragma unroll
    for (int p = 0; p < 4; ++p)
        t[r + p * 8][c] = in[(size_t)(k0 + r + p * 8) * N + n0 + c];
    __syncthreads();
#pragma unroll
    for (int p = 0; p < 4; ++p)
        out[(size_t)(n0 + r + p * 8) * K + k0 + c] = f2bf(t[c][r + p * 8]);
}

// ---------------- Pack indexer weights into one fp32 [1024][336] ----------------
__global__ __launch_bounds__(256) void wpack_kernel(const float* __restrict__ wq,
    const float* __restrict__ wk, const float* __restrict__ ww, float* __restrict__ Wc)
{
    int idx = blockIdx.x * 256 + threadIdx.x;
    if (idx >= D_MODEL * NIDX) return;
    int r = idx / NIDX, c = idx % NIDX;
    float v = 0.f;
    if (c < 256) v = wq[r * 256 + c];
    else if (c < 320) v = wk[r * 64 + (c - 256)];
    else if (c < 324) v = ww[r * 4 + (c - 320)];
    Wc[idx] = v;
}

// ---------------- bf16 MFMA GEMM, 128x64 tile, double-buffered + src-swizzled ----------------
// 4 waves; wave w computes rows [bm+32w, +32) x 64 cols. acc[2][4].
// T3-min 2-phase: prefetch tile k+1 issued BEFORE compute on tile k; 1 barrier/K-step.
// LDS bank fix: linear LDS dest, source slot pre-swizzled (slot ^ row&3), swizzled read.
// Split-K: if P != nullptr, block z does K-chunk -> raw fp32 partials at P + z*M*N.
__global__ __launch_bounds__(256) void gemm_bf16_n64(
    const unsigned short* __restrict__ A, const unsigned short* __restrict__ Bt,
    float* __restrict__ C, unsigned short* __restrict__ Cb,
    const float* __restrict__ bias, const float* __restrict__ R,
    int M, int N, int K, int act,
    float* __restrict__ P, int kchunk)
{
    __shared__ __attribute__((aligned(16))) unsigned short As[2][128 * 32];
    __shared__ __attribute__((aligned(16))) unsigned short Bs[2][64 * 32];
    int tid = threadIdx.x;
    int bm = blockIdx.y * 128, bn = blockIdx.x * 64;
    int wid = tid >> 6, lane = tid & 63;
    int wm = wid * 32;
    const unsigned short* Ab = A + (size_t)bm * K;
    const unsigned short* Bb = Bt + (size_t)bn * K;
    f32x4 acc[2][4];
#pragma unroll
    for (int i = 0; i < 2; ++i)
#pragma unroll
        for (int j = 0; j < 4; ++j)
            acc[i][j] = (f32x4){0.f, 0.f, 0.f, 0.f};

    int kbeg = blockIdx.z * kchunk;
    int kend = kbeg + kchunk;
    int fr = lane & 15;
    // staging geometry: 16B unit per lane; row = tid>>2, dst slot = tid&3,
    // source slot = dst ^ (row&3)  (inverse swizzle on global address)
    int srow = tid >> 2;                          // 0..63
    int cels = (((tid & 3) ^ (srow & 3)) << 3);   // source col (elements)
    int dste = tid * 8;                           // linear LDS dst (elements)
    // read-side swizzled slot: (lane>>4) ^ (fr&3), as element offset
    int selm = (((lane >> 4) ^ (fr & 3)) << 3);

    // prologue: stage tile kbeg into buffer 0
    gl_lds16(Ab + (size_t)srow * K + kbeg + cels, &As[0][dste]);
    gl_lds16(Ab + (size_t)(srow + 64) * K + kbeg + cels, &As[0][dste + 2048]);
    gl_lds16(Bb + (size_t)srow * K + kbeg + cels, &Bs[0][dste]);
    __syncthreads();

    int cur = 0;
    for (int k0 = kbeg; k0 < kend; k0 += 32) {
        int nxt = k0 + 32;
        if (nxt < kend) {   // prefetch next tile into the other buffer
            gl_lds16(Ab + (size_t)srow * K + nxt + cels, &As[cur ^ 1][dste]);
            gl_lds16(Ab + (size_t)(srow + 64) * K + nxt + cels, &As[cur ^ 1][dste + 2048]);
            gl_lds16(Bb + (size_t)srow * K + nxt + cels, &Bs[cur ^ 1][dste]);
        }
        bf16x8 af[2], bfv[4];
#pragma unroll
        for (int mi = 0; mi < 2; ++mi)
            af[mi] = *(const bf16x8*)&As[cur][(wm + mi * 16 + fr) * 32 + selm];
#pragma unroll
        for (int ni = 0; ni < 4; ++ni)
            bfv[ni] = *(const bf16x8*)&Bs[cur][(ni * 16 + fr) * 32 + selm];
#pragma unroll
        for (int mi = 0; mi < 2; ++mi)
#pragma unroll
            for (int ni = 0; ni < 4; ++ni)
                acc[mi][ni] = __builtin_amdgcn_mfma_f32_16x16x32_bf16(
                    af[mi], bfv[ni], acc[mi][ni], 0, 0, 0);
        __syncthreads();   // drains prefetch (vmcnt0) AFTER compute; guards buffer reuse
        cur ^= 1;
    }
    int cl = lane & 15, rh = (lane >> 4) * 4;
    if (P) {
        float* Pz = P + (size_t)blockIdx.z * M * N;
#pragma unroll
        for (int mi = 0; mi < 2; ++mi)
#pragma unroll
            for (int ni = 0; ni < 4; ++ni) {
                int col = bn + ni * 16 + cl;
#pragma unroll
                for (int r = 0; r < 4; ++r) {
                    int row = bm + wm + mi * 16 + rh + r;
                    Pz[(size_t)row * N + col] = acc[mi][ni][r];
                }
            }
        return;
    }
#pragma unroll
    for (int mi = 0; mi < 2; ++mi) {
#pragma unroll
        for (int ni = 0; ni < 4; ++ni) {
            int col = bn + ni * 16 + cl;
            float bv = bias ? bias[col] : 0.f;
#pragma unroll
            for (int r = 0; r < 4; ++r) {
                int row = bm + wm + mi * 16 + rh + r;
                float v = acc[mi][ni][r] + bv;
                if (act) v = gelu_exact(v);
                size_t off = (size_t)row * N + col;
                if (R) v += R[off];
                if (C) C[off] = v;
                if (Cb) Cb[off] = f2bf(v);
            }
        }
    }
}

// ---------------- Split-K reduce: C = sum_z P[z] + bias + R (float4 vectorized) ----------------
__global__ __launch_bounds__(256) void kreduce_kernel(const float* __restrict__ P,
    int nslice, float* __restrict__ C, const float* __restrict__ bias,
    const float* __restrict__ R, int M, int N)
{
    size_t total4 = (size_t)M * N / 4;
    size_t stride = (size_t)gridDim.x * 256;
    for (size_t i4 = blockIdx.x * 256 + threadIdx.x; i4 < total4; i4 += stride) {
        size_t off = i4 * 4;
        float4 v = *(const float4*)(P + off);
        for (int z = 1; z < nslice; ++z) {
            float4 p = *(const float4*)(P + (size_t)z * M * N + off);
            v.x += p.x; v.y += p.y; v.z += p.z; v.w += p.w;
        }
        if (bias) {
            float4 b4 = *(const float4*)(bias + (off % N));
            v.x += b4.x; v.y += b4.y; v.z += b4.z; v.w += b4.w;
        }
        if (R) {
            float4 r4 = *(const float4*)(R + off);
            v.x += r4.x; v.y += r4.y; v.z += r4.z; v.w += r4.w;
        }
        *(float4*)(C + off) = v;
    }
}

// ---------------- Generic fp32 GEMM (indexer path): C[M,N] = A[M,K]@B[K,N] ----------------
// Split-K: if P != nullptr, block z does K-chunk [z*kchunk, (z+1)*kchunk) -> P + z*M*N.
__global__ __launch_bounds__(256) void gemm64(const float* __restrict__ A,
    const float* __restrict__ B, float* __restrict__ C,
    int M, int N, int K,
    float* __restrict__ P, int kchunk)
{
    __shared__ float As[16][68];
    __shared__ float Bs[16][68];
    int tid = threadIdx.x;
    int bm = blockIdx.y, bn = blockIdx.x;
    int tx = tid & 15, ty = tid >> 4;
    int arow = tid >> 2;
    int acol = (tid & 3) << 2;
    int brow = tid >> 4;
    int bcol = (tid & 15) << 2;
    const float* Abase = A + (size_t)(bm * 64 + arow) * K + acol;
    float c[4][4] = {};
    int kbeg = blockIdx.z * kchunk;
    int kend = kbeg + kchunk;
    for (int k0 = kbeg; k0 < kend; k0 += 16) {
        float4 av = *(const float4*)(Abase + k0);
        As[acol + 0][arow] = av.x;
        As[acol + 1][arow] = av.y;
        As[acol + 2][arow] = av.z;
        As[acol + 3][arow] = av.w;
        int gcol = bn * 64 + bcol;
        const float* Bb = B + (size_t)(k0 + brow) * N;
        float4 bv;
        if (gcol + 3 < N) {
            bv = *(const float4*)(Bb + gcol);
        } else {
            bv.x = (gcol + 0 < N) ? Bb[gcol + 0] : 0.f;
            bv.y = (gcol + 1 < N) ? Bb[gcol + 1] : 0.f;
            bv.z = (gcol + 2 < N) ? Bb[gcol + 2] : 0.f;
            bv.w = (gcol + 3 < N) ? Bb[gcol + 3] : 0.f;
        }
        *(float4*)&Bs[brow][bcol] = bv;
        __syncthreads();
#pragma unroll
        for (int kk = 0; kk < 16; ++kk) {
            float4 a4 = *(const float4*)&As[kk][ty * 4];
            float4 b4 = *(const float4*)&Bs[kk][tx * 4];
            float av4[4] = { a4.x, a4.y, a4.z, a4.w };
            float bv4[4] = { b4.x, b4.y, b4.z, b4.w };
#pragma unroll
            for (int i = 0; i < 4; ++i)
#pragma unroll
                for (int j = 0; j < 4; ++j)
                    c[i][j] += av4[i] * bv4[j];
        }
        __syncthreads();
    }
    float* Out = P ? (P + (size_t)blockIdx.z * M * N) : C;
#pragma unroll
    for (int i = 0; i < 4; ++i) {
        int row = bm * 64 + ty * 4 + i;
#pragma unroll
        for (int j = 0; j < 4; ++j) {
            int col = bn * 64 + tx * 4 + j;
            if (col < N)
                Out[(size_t)row * N + col] = c[i][j];
        }
    }
}

// ---------------- RoPE table ----------------
__global__ __launch_bounds__(256) void rope_table_kernel(float* __restrict__ ct, float* __restrict__ st)
{
    int g = blockIdx.x * 256 + threadIdx.x;
    int t = g >> 5, i = g & 31;
    float theta = powf(10000.f, -(float)i / 32.f);
    float ang = (float)t * theta;
    ct[g] = cosf(ang);
    st[g] = sinf(ang);
}

// ---------------- RoPE + pack: qkv bf16 [S][3072] -> Qb [S][1024], Kb/Vb [H][S][64] ----------------
__global__ __launch_bounds__(512) void rope_pack_kernel(
    const unsigned short* __restrict__ qkvb,
    const float* __restrict__ ct, const float* __restrict__ st,
    unsigned short* __restrict__ Qb, unsigned short* __restrict__ Kb,
    unsigned short* __restrict__ Vb)
{
    int t = blockIdx.x, tid = threadIdx.x;
    int h = tid >> 5, i = tid & 31;
    float c = ct[t * 32 + i], s = st[t * 32 + i];
    const unsigned short* base = qkvb + (size_t)t * (3 * D_MODEL);
    ushort2 q2 = *(const ushort2*)(base + h * HDIM + 2 * i);
    float q0 = bf2f(q2.x), q1 = bf2f(q2.y);
    ushort2 qo = { f2bf(q0 * c - q1 * s), f2bf(q1 * c + q0 * s) };
    *(ushort2*)(Qb + (size_t)t * D_MODEL + h * HDIM + 2 * i) = qo;
    ushort2 k2 = *(const ushort2*)(base + D_MODEL + h * HDIM + 2 * i);
    float k0 = bf2f(k2.x), k1 = bf2f(k2.y);
    ushort2 ko = { f2bf(k0 * c - k1 * s), f2bf(k1 * c + k0 * s) };
    *(ushort2*)(Kb + ((size_t)h * S_LEN + t) * HDIM + 2 * i) = ko;
    ushort2 v2 = *(const ushort2*)(base + 2 * D_MODEL + 2 * tid);
    int vh = tid >> 5, vd = (2 * tid) & 63;
    *(ushort2*)(Vb + ((size_t)vh * S_LEN + t) * HDIM + vd) = v2;
}

// ---------------- Indexer scores (fp32, fused QIW layout, stride 336) ----------------
__global__ __launch_bounds__(256) void scores_kernel(const float* __restrict__ QIW,
    float* __restrict__ scores)
{
    int t0 = blockIdx.y * 32, s0 = blockIdx.x * 32;
    if (s0 > t0 + 31) return;
    __shared__ float qis[32][256];
    __shared__ float kis[32][65];
    __shared__ float wis[32][4];
    int tid = threadIdx.x;
#pragma unroll
    for (int l = 0; l < 8; ++l) {
        int idx = l * 256 + tid;
        int r = idx >> 6, c = (idx & 63) << 2;
        *(float4*)&qis[r][c] = *(const float4*)(QIW + (size_t)(t0 + r) * NIDX + c);
    }
#pragma unroll
    for (int l = 0; l < 8; ++l) {
        int idx = l * 256 + tid;
        int r = idx >> 6, c = idx & 63;
        kis[r][c] = QIW[(size_t)(s0 + r) * NIDX + 256 + c];
    }
    if (tid < 32) *(float4*)&wis[tid][0] = *(const float4*)(QIW + (size_t)(t0 + tid) * NIDX + 320);
    __syncthreads();
    int sl = tid & 31;
    int tb = (tid >> 5) * 4;
    float acc[4] = { 0.f, 0.f, 0.f, 0.f };
#pragma unroll
    for (int h = 0; h < 4; ++h) {
        float dots[4] = { 0.f, 0.f, 0.f, 0.f };
        for (int d = 0; d < 64; ++d) {
            float kv = kis[sl][d];
#pragma unroll
            for (int i = 0; i < 4; ++i)
                dots[i] += qis[tb + i][h * 64 + d] * kv;
        }
#pragma unroll
        for (int i = 0; i < 4; ++i)
            acc[i] += wis[tb + i][h] * fmaxf(dots[i], 0.f);
    }
#pragma unroll
    for (int i = 0; i < 4; ++i)
        scores[(size_t)(t0 + tb + i) * S_LEN + s0 + sl] = acc[i];
}

// ---------------- Top-K via radix select (exact lax.top_k set semantics) ----------------
__global__ __launch_bounds__(256) void topk_kernel(const float* __restrict__ scores,
    int* __restrict__ topidx, int* __restrict__ topcnt)
{
    int t = blockIdx.x, tid = threadIdx.x;
    int n = t + 1;
    if (n <= TOPK) {
        if (tid < n) topidx[t * TOPK + tid] = tid;
        if (tid == 0) topcnt[t] = n;
        return;
    }
    __shared__ unsigned sc[S_LEN];
    __shared__ unsigned hist[256];
    __shared__ int selbin_s;
    __shared__ int cnt_out;
    __shared__ unsigned wsum[4];
    for (int j = tid; j < n; j += 256) {
        unsigned u = __builtin_bit_cast(unsigned, scores[(size_t)t * S_LEN + j]);
        sc[j] = (u & 0x80000000u) ? ~u : (u | 0x80000000u);
    }
    if (tid == 0) cnt_out = 0;
    int lane = tid & 63, wv = tid >> 6;
    unsigned prefix = 0;
    int kk = TOPK;
#pragma unroll
    for (int round = 0; round < 4; ++round) {
        int shift_pref = 32 - 8 * round;
        int shift_bin = 24 - 8 * round;
        hist[tid] = 0;
        __syncthreads();
        for (int j = tid; j < n; j += 256) {
            unsigned v = sc[j];
            if ((((unsigned long long)(v ^ prefix)) >> shift_pref) == 0)
                atomicAdd(&hist[(v >> shift_bin) & 0xff], 1u);
        }
        __syncthreads();
        if (wv == 0) {
            unsigned h0 = hist[4 * lane], h1 = hist[4 * lane + 1];
            unsigned h2 = hist[4 * lane + 2], h3 = hist[4 * lane + 3];
            unsigned s3 = h3, s2 = h2 + s3, s1 = h1 + s2, s0 = h0 + s1;
            unsigned acc = s0;
            for (int off = 1; off < 64; off <<= 1) {
                unsigned o = __shfl_down(acc, off);
                if (lane + off < 64) acc += o;
            }
            unsigned above = acc - s0;
            hist[4 * lane]     = s0 + above;
            hist[4 * lane + 1] = s1 + above;
            hist[4 * lane + 2] = s2 + above;
            hist[4 * lane + 3] = s3 + above;
        }
        __syncthreads();
        {
            unsigned sufb = hist[tid];
            unsigned sufn = (tid < 255) ? hist[tid + 1] : 0u;
            if (sufb >= (unsigned)kk && sufn < (unsigned)kk)
                selbin_s = tid;
        }
        __syncthreads();
        int b = selbin_s;
        unsigned above = (b < 255) ? hist[b + 1] : 0u;
        kk -= (int)above;
        prefix |= ((unsigned)b) << shift_bin;
        __syncthreads();
    }
    unsigned T = prefix;
    int chunk = (n + 255) >> 8;
    int jb = tid * chunk;
    int je = jb + chunk; if (je > n) je = n;
    int ties = 0;
    for (int j = jb; j < je; ++j) {
        unsigned v = sc[j];
        if (v > T) { int o = atomicAdd(&cnt_out, 1); topidx[t * TOPK + o] = j; }
        else if (v == T) ++ties;
    }
    unsigned inc = (unsigned)ties;
    for (int off = 1; off < 64; off <<= 1) {
        unsigned o = __shfl_up(inc, off);
        if (lane >= off) inc += o;
    }
    if (lane == 63) wsum[wv] = inc;
    __syncthreads();
    unsigned woff = 0;
    for (int w = 0; w < wv; ++w) woff += wsum[w];
    int rank = (int)(woff + inc) - ties;
    for (int j = jb; j < je && rank < kk; ++j) {
        if (sc[j] == T) {
            int o = atomicAdd(&cnt_out, 1);
            topidx[t * TOPK + o] = j;
            ++rank;
        }
    }
    if (tid == 0) topcnt[t] = TOPK;
}

// ---------------- Sparse SDPA v4: one head per wave, grid (S, 4) ----------------
__global__ __launch_bounds__(256) void attn_kernel(
    const unsigned short* __restrict__ Qb, const unsigned short* __restrict__ Kb,
    const unsigned short* __restrict__ Vb,
    const int* __restrict__ topidx, const int* __restrict__ topcnt,
    unsigned short* __restrict__ out)
{
    int t = blockIdx.x, tid = threadIdx.x;
    __shared__ int sel[TOPK];
    if (tid < TOPK) sel[tid] = topidx[t * TOPK + tid];
    __syncthreads();
    int cnt = topcnt[t];
    int lane = tid & 63, wv = tid >> 6;
    int h = blockIdx.y * 4 + wv;
    int klo = lane >> 3, oct = lane & 7;
    int rows[8];
    bool valid[8];
#pragma unroll
    for (int kg = 0; kg < 8; ++kg) {
        int k = kg * 8 + klo;
        valid[kg] = (k < cnt);
        rows[kg] = sel[valid[kg] ? k : 0];
    }
    bf16x8 q8 = *(const bf16x8*)(Qb + (size_t)t * D_MODEL + h * HDIM + oct * 8);
    float qf[8];
#pragma unroll
    for (int e = 0; e < 8; ++e) qf[e] = bf2f((unsigned short)q8[e]);

    const unsigned short* kbase = Kb + (size_t)h * S_LEN * HDIM + oct * 8;
    float p[8];
#pragma unroll
    for (int kg = 0; kg < 8; ++kg) {
        bf16x8 k8 = *(const bf16x8*)(kbase + (size_t)rows[kg] * HDIM);
        float d = 0.f;
#pragma unroll
        for (int e = 0; e < 8; ++e)
            d += bf2f((unsigned short)k8[e]) * qf[e];
        d += __shfl_xor(d, 1);
        d += __shfl_xor(d, 2);
        d += __shfl_xor(d, 4);
        p[kg] = valid[kg] ? d * 0.125f : -INFINITY;
    }
    float m = p[0];
#pragma unroll
    for (int kg = 1; kg < 8; ++kg) m = fmaxf(m, p[kg]);
    m = fmaxf(m, __shfl_xor(m, 8));
    m = fmaxf(m, __shfl_xor(m, 16));
    m = fmaxf(m, __shfl_xor(m, 32));
    float sum = 0.f;
#pragma unroll
    for (int kg = 0; kg < 8; ++kg) { p[kg] = __expf(p[kg] - m); sum += p[kg]; }
    sum += __shfl_xor(sum, 8);
    sum += __shfl_xor(sum, 16);
    sum += __shfl_xor(sum, 32);
    float rs = 1.f / sum;
    const unsigned short* vbase = Vb + (size_t)h * S_LEN * HDIM + oct * 8;
    float facc[8] = {};
#pragma unroll
    for (int kg = 0; kg < 8; ++kg) {
        bf16x8 v8 = *(const bf16x8*)(vbase + (size_t)rows[kg] * HDIM);
        float pw = p[kg] * rs;
#pragma unroll
        for (int e = 0; e < 8; ++e)
            facc[e] += pw * bf2f((unsigned short)v8[e]);
    }
#pragma unroll
    for (int e = 0; e < 8; ++e) {
        facc[e] += __shfl_xor(facc[e], 8);
        facc[e] += __shfl_xor(facc[e], 16);
        facc[e] += __shfl_xor(facc[e], 32);
    }
    if (klo == 0) {
        ushort4 o0 = { f2bf(facc[0]), f2bf(facc[1]), f2bf(facc[2]), f2bf(facc[3]) };
        ushort4 o1 = { f2bf(facc[4]), f2bf(facc[5]), f2bf(facc[6]), f2bf(facc[7]) };
        *(ushort4*)(out + (size_t)t * D_MODEL + h * HDIM + oct * 8) = o0;
        *(ushort4*)(out + (size_t)t * D_MODEL + h * HDIM + oct * 8 + 4) = o1;
    }
}

extern "C" void kernel_launch(void* const* d_in, const int* in_sizes, int n_in,
                              void* d_out, int out_size, void* d_ws, size_t ws_size,
                              hipStream_t stream)
{
    const float* x      = (const float*)d_in[0];
    const float* w_qkv  = (const float*)d_in[1];
    const float* w_o    = (const float*)d_in[2];
    const float* ffn_w1 = (const float*)d_in[3];
    const float* ffn_b1 = (const float*)d_in[4];
    const float* ffn_w2 = (const float*)d_in[5];
    const float* ffn_b2 = (const float*)d_in[6];
    const float* ln1_g  = (const float*)d_in[7];
    const float* ln1_b  = (const float*)d_in[8];
    const float* ln2_g  = (const float*)d_in[9];
    const float* ln2_b  = (const float*)d_in[10];
    const float* idx_wq = (const float*)d_in[11];
    const float* idx_wk = (const float*)d_in[12];
    const float* idx_ww = (const float*)d_in[13];
    float* outp = (float*)d_out;

    const size_t MB = 1ull << 20;
    char* ws = (char*)d_ws;
    // [0,8)    normx fp32 -> attno_bf (4MB) -> Pf2 (32MB ffn2 partials)
    // [8,12)   normx_bf / h2_bf
    // [12,24)  qkv_bf (dead after rope_pack) -> topidx/topcnt
    // [24,32)  wqkv_t/wo_t    [32,40) w1_t   [40,48) w2_t
    // [48,60)  Qb/Kb/Vb
    // [60,76)  ctab/stab (dead after rope_pack) -> P_idx (11MB) -> scoresb -> Pwo -> ffn1_bf
    // [76,79)  QIW   [79,80.5) Wc
    float*          normx    = (float*)(ws + 0);
    unsigned short* attno_bf = (unsigned short*)(ws + 0);
    float*          Pf2      = (float*)(ws + 0);
    unsigned short* normx_bf = (unsigned short*)(ws + 8 * MB);
    unsigned short* h2_bf    = normx_bf;
    unsigned short* qkv_bf   = (unsigned short*)(ws + 12 * MB);
    int*            topidx   = (int*)(ws + 12 * MB);
    int*            topcnt   = (int*)(ws + 12 * MB + 512 * 1024);
    unsigned short* wqkv_t   = (unsigned short*)(ws + 24 * MB);
    unsigned short* wo_t     = (unsigned short*)(ws + 30 * MB);
    unsigned short* w1_t     = (unsigned short*)(ws + 32 * MB);
    unsigned short* w2_t     = (unsigned short*)(ws + 40 * MB);
    unsigned short* Qb       = (unsigned short*)(ws + 48 * MB);
    unsigned short* Kb       = (unsigned short*)(ws + 52 * MB);
    unsigned short* Vb       = (unsigned short*)(ws + 56 * MB);
    float*          ctab     = (float*)(ws + 60 * MB);
    float*          stab     = (float*)(ws + 60 * MB + 256 * 1024);
    float*          P_idx    = (float*)(ws + 60 * MB);      // 4 x 2048*336*4B = 11MB
    float*          scoresb  = (float*)(ws + 60 * MB);
    float*          Pwo      = (float*)(ws + 60 * MB);      // 16MB w_o partials (2 slices)
    unsigned short* ffn1_bf  = (unsigned short*)(ws + 60 * MB);
    float*          QIW      = (float*)(ws + 76 * MB);
    float*          Wc       = (float*)(ws + 79 * MB);

    dim3 blk256(256);
    auto g64n = [](int N, int M) { return dim3(N / 64, M / 128); };

    // 1. LN1 -> fp32 (indexer) + bf16 (qkv gemm)
    ln_kernel<<<S_LEN, blk256, 0, stream>>>(x, ln1_g, ln1_b, normx, normx_bf);
    // 2. rope tables + weight prep
    rope_table_kernel<<<(S_LEN * 32) / 256, blk256, 0, stream>>>(ctab, stab);
    wtrans_kernel<<<dim3(3 * D_MODEL / 32, D_MODEL / 32), blk256, 0, stream>>>(w_qkv, wqkv_t, D_MODEL, 3 * D_MODEL);
    wtrans_kernel<<<dim3(D_MODEL / 32, D_MODEL / 32), blk256, 0, stream>>>(w_o, wo_t, D_MODEL, D_MODEL);
    wtrans_kernel<<<dim3(DFF / 32, D_MODEL / 32), blk256, 0, stream>>>(ffn_w1, w1_t, D_MODEL, DFF);
    wtrans_kernel<<<dim3(D_MODEL / 32, DFF / 32), blk256, 0, stream>>>(ffn_w2, w2_t, DFF, D_MODEL);
    wpack_kernel<<<(D_MODEL * NIDX + 255) / 256, blk256, 0, stream>>>(idx_wq, idx_wk, idx_ww, Wc);
    // 3. qkv = norm_x @ w_qkv (bf16 out only; 768 blocks)
    gemm_bf16_n64<<<g64n(3 * D_MODEL, S_LEN), blk256, 0, stream>>>(normx_bf, wqkv_t,
        nullptr, qkv_bf, nullptr, nullptr, S_LEN, 3 * D_MODEL, D_MODEL, 0, nullptr, D_MODEL);
    // 4. RoPE + pack Q/K/V (frees qkv_bf + ctab/stab for P_idx)
    rope_pack_kernel<<<S_LEN, dim3(512), 0, stream>>>(qkv_bf, ctab, stab, Qb, Kb, Vb);
    // 5. fused indexer projections (fp32, split-K=4 -> 768 blocks; feeds discrete top-k)
    gemm64<<<dim3((NIDX + 63) / 64, S_LEN / 64, 4), blk256, 0, stream>>>(normx, Wc,
        nullptr, S_LEN, NIDX, D_MODEL, P_idx, D_MODEL / 4);
    kreduce_kernel<<<1024, blk256, 0, stream>>>(P_idx, 4, QIW, nullptr, nullptr, S_LEN, NIDX);
    // 6. indexer scores (overwrites dead P_idx region)
    scores_kernel<<<dim3(64, 64), blk256, 0, stream>>>(QIW, scoresb);
    // 7. top-64 per row (radix select; topidx overlays dead qkv_bf)
    topk_kernel<<<S_LEN, blk256, 0, stream>>>(scoresb, topidx, topcnt);
    // 8. sparse attention -> bf16 (one head per wave; overlays dead normx)
    attn_kernel<<<dim3(S_LEN, 4), blk256, 0, stream>>>(Qb, Kb, Vb, topidx, topcnt, attno_bf);
    // 9. x1 = x + attn_out @ w_o  — split-K=2 (512 blocks) into Pwo, then reduce
    gemm_bf16_n64<<<dim3(D_MODEL / 64, S_LEN / 128, 2), blk256, 0, stream>>>(attno_bf, wo_t,
        nullptr, nullptr, nullptr, nullptr, S_LEN, D_MODEL, D_MODEL, 0, Pwo, D_MODEL / 2);
    kreduce_kernel<<<1024, blk256, 0, stream>>>(Pwo, 2, outp, nullptr, x, S_LEN, D_MODEL);
    // 10. h = LN2(x1) -> bf16
    ln_kernel<<<S_LEN, blk256, 0, stream>>>(outp, ln2_g, ln2_b, nullptr, h2_bf);
    // 11. ffn1 = gelu(h @ w1 + b1) -> bf16 (overlays dead Pwo/scoresb; 1024 blocks)
    gemm_bf16_n64<<<g64n(DFF, S_LEN), blk256, 0, stream>>>(h2_bf, w1_t,
        nullptr, ffn1_bf, ffn_b1, nullptr, S_LEN, DFF, D_MODEL, 1, nullptr, D_MODEL);
    // 12. out = x1 + ffn1 @ w2 + b2 — split-K=4 (1024 blocks) into Pf2, then reduce
    gemm_bf16_n64<<<dim3(D_MODEL / 64, S_LEN / 128, 4), blk256, 0, stream>>>(ffn1_bf, w2_t,
        nullptr, nullptr, nullptr, nullptr, S_LEN, D_MODEL, DFF, 0, Pf2, DFF / 4);
    kreduce_kernel<<<1024, blk256, 0, stream>>>(Pf2, 4, outp, ffn_b2, outp, S_LEN, D_MODEL);
}

// Round 11
// 272.208 us; speedup vs baseline: 4.9681x; 1.0153x over previous
//
#include <hip/hip_runtime.h>
#include <math.h>

#define S_LEN 2048
#define D_MODEL 1024
#define NHEAD 16
#define HDIM 64
#define DFF 4096
#define IH 4
#define IDM 64
#define TOPK 64
#define NIDX 336   // 256 qi + 64 ki + 4 wi + 12 pad

typedef float f32x4 __attribute__((ext_vector_type(4)));
typedef short bf16x8 __attribute__((ext_vector_type(8)));

__device__ __forceinline__ unsigned short f2bf(float f) {
    unsigned u = __builtin_bit_cast(unsigned, f);
    u += 0x7fff + ((u >> 16) & 1);
    return (unsigned short)(u >> 16);
}
__device__ __forceinline__ float bf2f(unsigned short us) {
    return __builtin_bit_cast(float, (unsigned)us << 16);
}

__device__ __forceinline__ float gelu_exact(float v) {
    return 0.5f * v * (1.f + erff(v * 0.70710678118654752f));
}

__device__ __forceinline__ void gl_lds16(const void* g, void* l) {
    __builtin_amdgcn_global_load_lds(
        (const __attribute__((address_space(1))) void*)g,
        (__attribute__((address_space(3))) void*)l, 16, 0, 0);
}

// ---------------- LayerNorm: fp32 out (optional) + bf16 out (optional) ----------------
__global__ __launch_bounds__(256) void ln_kernel(const float* __restrict__ x,
    const float* __restrict__ g, const float* __restrict__ b,
    float* __restrict__ outf, unsigned short* __restrict__ outb)
{
    int row = blockIdx.x, tid = threadIdx.x;
    const float4 v = *(const float4*)(x + (size_t)row * D_MODEL + tid * 4);
    float s = v.x + v.y + v.z + v.w;
    float ss = v.x * v.x + v.y * v.y + v.z * v.z + v.w * v.w;
    int lane = tid & 63, wv = tid >> 6;
    for (int o = 32; o; o >>= 1) { s += __shfl_xor(s, o); ss += __shfl_xor(ss, o); }
    __shared__ float rs[4], rss[4];
    if (lane == 0) { rs[wv] = s; rss[wv] = ss; }
    __syncthreads();
    float S = rs[0] + rs[1] + rs[2] + rs[3];
    float SS = rss[0] + rss[1] + rss[2] + rss[3];
    float mean = S * (1.f / D_MODEL);
    float var = SS * (1.f / D_MODEL) - mean * mean;
    float r = rsqrtf(var + 1e-5f);
    float4 gv = *(const float4*)(g + tid * 4);
    float4 bv = *(const float4*)(b + tid * 4);
    float4 o4;
    o4.x = (v.x - mean) * r * gv.x + bv.x;
    o4.y = (v.y - mean) * r * gv.y + bv.y;
    o4.z = (v.z - mean) * r * gv.z + bv.z;
    o4.w = (v.w - mean) * r * gv.w + bv.w;
    if (outf) *(float4*)(outf + (size_t)row * D_MODEL + tid * 4) = o4;
    if (outb) {
        ushort4 u4 = { f2bf(o4.x), f2bf(o4.y), f2bf(o4.z), f2bf(o4.w) };
        *(ushort4*)(outb + (size_t)row * D_MODEL + tid * 4) = u4;
    }
}

// ---------------- Weight convert + transpose: fp32 [K][N] -> bf16 [N][K] ----------------
__global__ __launch_bounds__(256) void wtrans_kernel(const float* __restrict__ in,
    unsigned short* __restrict__ out, int K, int N)
{
    __shared__ float t[32][33];
    int k0 = blockIdx.y * 32, n0 = blockIdx.x * 32;
    int tid = threadIdx.x;
    int r = tid >> 5, c = tid & 31;
#pragma unroll
    for (int p = 0; p < 4; ++p)
        t[r + p * 8][c] = in[(size_t)(k0 + r + p * 8) * N + n0 + c];
    __syncthreads();
#pragma unroll
    for (int p = 0; p < 4; ++p)
        out[(size_t)(n0 + r + p * 8) * K + k0 + c] = f2bf(t[c][r + p * 8]);
}

// ---------------- Pack indexer weights into one fp32 [1024][336] ----------------
__global__ __launch_bounds__(256) void wpack_kernel(const float* __restrict__ wq,
    const float* __restrict__ wk, const float* __restrict__ ww, float* __restrict__ Wc)
{
    int idx = blockIdx.x * 256 + threadIdx.x;
    if (idx >= D_MODEL * NIDX) return;
    int r = idx / NIDX, c = idx % NIDX;
    float v = 0.f;
    if (c < 256) v = wq[r * 256 + c];
    else if (c < 320) v = wk[r * 64 + (c - 256)];
    else if (c < 324) v = ww[r * 4 + (c - 320)];
    Wc[idx] = v;
}

// ---------------- bf16 MFMA GEMM, 128x64 tile, double-buffered + src-swizzled ----------------
__global__ __launch_bounds__(256) void gemm_bf16_n64(
    const unsigned short* __restrict__ A, const unsigned short* __restrict__ Bt,
    float* __restrict__ C, unsigned short* __restrict__ Cb,
    const float* __restrict__ bias, const float* __restrict__ R,
    int M, int N, int K, int act,
    float* __restrict__ P, int kchunk)
{
    __shared__ __attribute__((aligned(16))) unsigned short As[2][128 * 32];
    __shared__ __attribute__((aligned(16))) unsigned short Bs[2][64 * 32];
    int tid = threadIdx.x;
    int bm = blockIdx.y * 128, bn = blockIdx.x * 64;
    int wid = tid >> 6, lane = tid & 63;
    int wm = wid * 32;
    const unsigned short* Ab = A + (size_t)bm * K;
    const unsigned short* Bb = Bt + (size_t)bn * K;
    f32x4 acc[2][4];
#pragma unroll
    for (int i = 0; i < 2; ++i)
#pragma unroll
        for (int j = 0; j < 4; ++j)
            acc[i][j] = (f32x4){0.f, 0.f, 0.f, 0.f};

    int kbeg = blockIdx.z * kchunk;
    int kend = kbeg + kchunk;
    int fr = lane & 15;
    int srow = tid >> 2;
    int cels = (((tid & 3) ^ (srow & 3)) << 3);
    int dste = tid * 8;
    int selm = (((lane >> 4) ^ (fr & 3)) << 3);

    gl_lds16(Ab + (size_t)srow * K + kbeg + cels, &As[0][dste]);
    gl_lds16(Ab + (size_t)(srow + 64) * K + kbeg + cels, &As[0][dste + 2048]);
    gl_lds16(Bb + (size_t)srow * K + kbeg + cels, &Bs[0][dste]);
    __syncthreads();

    int cur = 0;
    for (int k0 = kbeg; k0 < kend; k0 += 32) {
        int nxt = k0 + 32;
        if (nxt < kend) {
            gl_lds16(Ab + (size_t)srow * K + nxt + cels, &As[cur ^ 1][dste]);
            gl_lds16(Ab + (size_t)(srow + 64) * K + nxt + cels, &As[cur ^ 1][dste + 2048]);
            gl_lds16(Bb + (size_t)srow * K + nxt + cels, &Bs[cur ^ 1][dste]);
        }
        bf16x8 af[2], bfv[4];
#pragma unroll
        for (int mi = 0; mi < 2; ++mi)
            af[mi] = *(const bf16x8*)&As[cur][(wm + mi * 16 + fr) * 32 + selm];
#pragma unroll
        for (int ni = 0; ni < 4; ++ni)
            bfv[ni] = *(const bf16x8*)&Bs[cur][(ni * 16 + fr) * 32 + selm];
#pragma unroll
        for (int mi = 0; mi < 2; ++mi)
#pragma unroll
            for (int ni = 0; ni < 4; ++ni)
                acc[mi][ni] = __builtin_amdgcn_mfma_f32_16x16x32_bf16(
                    af[mi], bfv[ni], acc[mi][ni], 0, 0, 0);
        __syncthreads();
        cur ^= 1;
    }
    int cl = lane & 15, rh = (lane >> 4) * 4;
    if (P) {
        float* Pz = P + (size_t)blockIdx.z * M * N;
#pragma unroll
        for (int mi = 0; mi < 2; ++mi)
#pragma unroll
            for (int ni = 0; ni < 4; ++ni) {
                int col = bn + ni * 16 + cl;
#pragma unroll
                for (int r = 0; r < 4; ++r) {
                    int row = bm + wm + mi * 16 + rh + r;
                    Pz[(size_t)row * N + col] = acc[mi][ni][r];
                }
            }
        return;
    }
#pragma unroll
    for (int mi = 0; mi < 2; ++mi) {
#pragma unroll
        for (int ni = 0; ni < 4; ++ni) {
            int col = bn + ni * 16 + cl;
            float bv = bias ? bias[col] : 0.f;
#pragma unroll
            for (int r = 0; r < 4; ++r) {
                int row = bm + wm + mi * 16 + rh + r;
                float v = acc[mi][ni][r] + bv;
                if (act) v = gelu_exact(v);
                size_t off = (size_t)row * N + col;
                if (R) v += R[off];
                if (C) C[off] = v;
                if (Cb) Cb[off] = f2bf(v);
            }
        }
    }
}

// ---------------- Split-K reduce: C = sum_z P[z] + bias + R (float4 vectorized) ----------------
__global__ __launch_bounds__(256) void kreduce_kernel(const float* __restrict__ P,
    int nslice, float* __restrict__ C, const float* __restrict__ bias,
    const float* __restrict__ R, int M, int N)
{
    size_t total4 = (size_t)M * N / 4;
    size_t stride = (size_t)gridDim.x * 256;
    for (size_t i4 = blockIdx.x * 256 + threadIdx.x; i4 < total4; i4 += stride) {
        size_t off = i4 * 4;
        float4 v = *(const float4*)(P + off);
        for (int z = 1; z < nslice; ++z) {
            float4 p = *(const float4*)(P + (size_t)z * M * N + off);
            v.x += p.x; v.y += p.y; v.z += p.z; v.w += p.w;
        }
        if (bias) {
            float4 b4 = *(const float4*)(bias + (off % N));
            v.x += b4.x; v.y += b4.y; v.z += b4.z; v.w += b4.w;
        }
        if (R) {
            float4 r4 = *(const float4*)(R + off);
            v.x += r4.x; v.y += r4.y; v.z += r4.z; v.w += r4.w;
        }
        *(float4*)(C + off) = v;
    }
}

// ---------------- Generic fp32 GEMM (indexer path): C[M,N] = A[M,K]@B[K,N] ----------------
__global__ __launch_bounds__(256) void gemm64(const float* __restrict__ A,
    const float* __restrict__ B, float* __restrict__ C,
    int M, int N, int K,
    float* __restrict__ P, int kchunk)
{
    __shared__ float As[16][68];
    __shared__ float Bs[16][68];
    int tid = threadIdx.x;
    int bm = blockIdx.y, bn = blockIdx.x;
    int tx = tid & 15, ty = tid >> 4;
    int arow = tid >> 2;
    int acol = (tid & 3) << 2;
    int brow = tid >> 4;
    int bcol = (tid & 15) << 2;
    const float* Abase = A + (size_t)(bm * 64 + arow) * K + acol;
    float c[4][4] = {};
    int kbeg = blockIdx.z * kchunk;
    int kend = kbeg + kchunk;
    for (int k0 = kbeg; k0 < kend; k0 += 16) {
        float4 av = *(const float4*)(Abase + k0);
        As[acol + 0][arow] = av.x;
        As[acol + 1][arow] = av.y;
        As[acol + 2][arow] = av.z;
        As[acol + 3][arow] = av.w;
        int gcol = bn * 64 + bcol;
        const float* Bb = B + (size_t)(k0 + brow) * N;
        float4 bv;
        if (gcol + 3 < N) {
            bv = *(const float4*)(Bb + gcol);
        } else {
            bv.x = (gcol + 0 < N) ? Bb[gcol + 0] : 0.f;
            bv.y = (gcol + 1 < N) ? Bb[gcol + 1] : 0.f;
            bv.z = (gcol + 2 < N) ? Bb[gcol + 2] : 0.f;
            bv.w = (gcol + 3 < N) ? Bb[gcol + 3] : 0.f;
        }
        *(float4*)&Bs[brow][bcol] = bv;
        __syncthreads();
#pragma unroll
        for (int kk = 0; kk < 16; ++kk) {
            float4 a4 = *(const float4*)&As[kk][ty * 4];
            float4 b4 = *(const float4*)&Bs[kk][tx * 4];
            float av4[4] = { a4.x, a4.y, a4.z, a4.w };
            float bv4[4] = { b4.x, b4.y, b4.z, b4.w };
#pragma unroll
            for (int i = 0; i < 4; ++i)
#pragma unroll
                for (int j = 0; j < 4; ++j)
                    c[i][j] += av4[i] * bv4[j];
        }
        __syncthreads();
    }
    float* Out = P ? (P + (size_t)blockIdx.z * M * N) : C;
#pragma unroll
    for (int i = 0; i < 4; ++i) {
        int row = bm * 64 + ty * 4 + i;
#pragma unroll
        for (int j = 0; j < 4; ++j) {
            int col = bn * 64 + tx * 4 + j;
            if (col < N)
                Out[(size_t)row * N + col] = c[i][j];
        }
    }
}

// ---------------- RoPE table ----------------
__global__ __launch_bounds__(256) void rope_table_kernel(float* __restrict__ ct, float* __restrict__ st)
{
    int g = blockIdx.x * 256 + threadIdx.x;
    int t = g >> 5, i = g & 31;
    float theta = powf(10000.f, -(float)i / 32.f);
    float ang = (float)t * theta;
    ct[g] = cosf(ang);
    st[g] = sinf(ang);
}

// ---------------- RoPE + pack: qkv bf16 [S][3072] -> Qb [S][1024], Kb/Vb [H][S][64] ----------------
__global__ __launch_bounds__(512) void rope_pack_kernel(
    const unsigned short* __restrict__ qkvb,
    const float* __restrict__ ct, const float* __restrict__ st,
    unsigned short* __restrict__ Qb, unsigned short* __restrict__ Kb,
    unsigned short* __restrict__ Vb)
{
    int t = blockIdx.x, tid = threadIdx.x;
    int h = tid >> 5, i = tid & 31;
    float c = ct[t * 32 + i], s = st[t * 32 + i];
    const unsigned short* base = qkvb + (size_t)t * (3 * D_MODEL);
    ushort2 q2 = *(const ushort2*)(base + h * HDIM + 2 * i);
    float q0 = bf2f(q2.x), q1 = bf2f(q2.y);
    ushort2 qo = { f2bf(q0 * c - q1 * s), f2bf(q1 * c + q0 * s) };
    *(ushort2*)(Qb + (size_t)t * D_MODEL + h * HDIM + 2 * i) = qo;
    ushort2 k2 = *(const ushort2*)(base + D_MODEL + h * HDIM + 2 * i);
    float k0 = bf2f(k2.x), k1 = bf2f(k2.y);
    ushort2 ko = { f2bf(k0 * c - k1 * s), f2bf(k1 * c + k0 * s) };
    *(ushort2*)(Kb + ((size_t)h * S_LEN + t) * HDIM + 2 * i) = ko;
    ushort2 v2 = *(const ushort2*)(base + 2 * D_MODEL + 2 * tid);
    int vh = tid >> 5, vd = (2 * tid) & 63;
    *(ushort2*)(Vb + ((size_t)vh * S_LEN + t) * HDIM + vd) = v2;
}

// ---------------- Indexer scores v2: 64x64 tile, d-major LDS, 4x4 register blocking ----------------
// I[t,s] = sum_h wi[t,h]*relu(qi[t,h,:].ki[s,:]). Per d: 2 x ds_read_b128 + 16 FMA -> VALU-bound.
__global__ __launch_bounds__(256) void scores_kernel(const float* __restrict__ QIW,
    float* __restrict__ scores)
{
    int t0 = blockIdx.y * 64, s0 = blockIdx.x * 64;
    if (s0 > t0 + 63) return;
    __shared__ float qit[64][68];   // [d][t]
    __shared__ float kit[64][68];   // [d][s]
    __shared__ float wis[64][4];
    int tid = threadIdx.x;
    int tx = tid & 15, ty = tid >> 4;
    int lr = tid & 63;              // tile row handled by this thread for loads
    int cseg = tid >> 6;            // 16-wide d segment
    if (tid < 64) {
        float4 w4 = *(const float4*)(QIW + (size_t)(t0 + tid) * NIDX + 320);
        wis[tid][0] = w4.x; wis[tid][1] = w4.y; wis[tid][2] = w4.z; wis[tid][3] = w4.w;
    }
    float acc[4][4] = {};
#pragma unroll
    for (int h = 0; h < 4; ++h) {
        __syncthreads();   // previous-h reads done (also covers wis on h=0)
        const float* qrow = QIW + (size_t)(t0 + lr) * NIDX + h * 64 + cseg * 16;
        const float* krow = QIW + (size_t)(s0 + lr) * NIDX + 256 + cseg * 16;
#pragma unroll
        for (int q4 = 0; q4 < 4; ++q4) {
            int d = cseg * 16 + q4 * 4;
            float4 v = *(const float4*)(qrow + q4 * 4);
            qit[d + 0][lr] = v.x; qit[d + 1][lr] = v.y;
            qit[d + 2][lr] = v.z; qit[d + 3][lr] = v.w;
            if (h == 0) {
                float4 u = *(const float4*)(krow + q4 * 4);
                kit[d + 0][lr] = u.x; kit[d + 1][lr] = u.y;
                kit[d + 2][lr] = u.z; kit[d + 3][lr] = u.w;
            }
        }
        __syncthreads();
        float dot[4][4] = {};
#pragma unroll 8
        for (int d = 0; d < 64; ++d) {
            float4 a4 = *(const float4*)&qit[d][ty * 4];
            float4 b4 = *(const float4*)&kit[d][tx * 4];
            float av[4] = { a4.x, a4.y, a4.z, a4.w };
            float bv[4] = { b4.x, b4.y, b4.z, b4.w };
#pragma unroll
            for (int i = 0; i < 4; ++i)
#pragma unroll
                for (int j = 0; j < 4; ++j)
                    dot[i][j] += av[i] * bv[j];
        }
#pragma unroll
        for (int i = 0; i < 4; ++i) {
            float w = wis[ty * 4 + i][h];
#pragma unroll
            for (int j = 0; j < 4; ++j)
                acc[i][j] += w * fmaxf(dot[i][j], 0.f);
        }
    }
#pragma unroll
    for (int i = 0; i < 4; ++i) {
        float4 o4 = { acc[i][0], acc[i][1], acc[i][2], acc[i][3] };
        *(float4*)&scores[(size_t)(t0 + ty * 4 + i) * S_LEN + s0 + tx * 4] = o4;
    }
}

// ---------------- Top-K via radix select (exact lax.top_k set semantics) ----------------
__global__ __launch_bounds__(256) void topk_kernel(const float* __restrict__ scores,
    int* __restrict__ topidx, int* __restrict__ topcnt)
{
    int t = blockIdx.x, tid = threadIdx.x;
    int n = t + 1;
    if (n <= TOPK) {
        if (tid < n) topidx[t * TOPK + tid] = tid;
        if (tid == 0) topcnt[t] = n;
        return;
    }
    __shared__ unsigned sc[S_LEN];
    __shared__ unsigned hist[256];
    __shared__ int selbin_s;
    __shared__ int cnt_out;
    __shared__ unsigned wsum[4];
    for (int j = tid; j < n; j += 256) {
        unsigned u = __builtin_bit_cast(unsigned, scores[(size_t)t * S_LEN + j]);
        sc[j] = (u & 0x80000000u) ? ~u : (u | 0x80000000u);
    }
    if (tid == 0) cnt_out = 0;
    int lane = tid & 63, wv = tid >> 6;
    unsigned prefix = 0;
    int kk = TOPK;
#pragma unroll
    for (int round = 0; round < 4; ++round) {
        int shift_pref = 32 - 8 * round;
        int shift_bin = 24 - 8 * round;
        hist[tid] = 0;
        __syncthreads();
        for (int j = tid; j < n; j += 256) {
            unsigned v = sc[j];
            if ((((unsigned long long)(v ^ prefix)) >> shift_pref) == 0)
                atomicAdd(&hist[(v >> shift_bin) & 0xff], 1u);
        }
        __syncthreads();
        if (wv == 0) {
            unsigned h0 = hist[4 * lane], h1 = hist[4 * lane + 1];
            unsigned h2 = hist[4 * lane + 2], h3 = hist[4 * lane + 3];
            unsigned s3 = h3, s2 = h2 + s3, s1 = h1 + s2, s0 = h0 + s1;
            unsigned acc = s0;
            for (int off = 1; off < 64; off <<= 1) {
                unsigned o = __shfl_down(acc, off);
                if (lane + off < 64) acc += o;
            }
            unsigned above = acc - s0;
            hist[4 * lane]     = s0 + above;
            hist[4 * lane + 1] = s1 + above;
            hist[4 * lane + 2] = s2 + above;
            hist[4 * lane + 3] = s3 + above;
        }
        __syncthreads();
        {
            unsigned sufb = hist[tid];
            unsigned sufn = (tid < 255) ? hist[tid + 1] : 0u;
            if (sufb >= (unsigned)kk && sufn < (unsigned)kk)
                selbin_s = tid;
        }
        __syncthreads();
        int b = selbin_s;
        unsigned above = (b < 255) ? hist[b + 1] : 0u;
        kk -= (int)above;
        prefix |= ((unsigned)b) << shift_bin;
        __syncthreads();
    }
    unsigned T = prefix;
    int chunk = (n + 255) >> 8;
    int jb = tid * chunk;
    int je = jb + chunk; if (je > n) je = n;
    int ties = 0;
    for (int j = jb; j < je; ++j) {
        unsigned v = sc[j];
        if (v > T) { int o = atomicAdd(&cnt_out, 1); topidx[t * TOPK + o] = j; }
        else if (v == T) ++ties;
    }
    unsigned inc = (unsigned)ties;
    for (int off = 1; off < 64; off <<= 1) {
        unsigned o = __shfl_up(inc, off);
        if (lane >= off) inc += o;
    }
    if (lane == 63) wsum[wv] = inc;
    __syncthreads();
    unsigned woff = 0;
    for (int w = 0; w < wv; ++w) woff += wsum[w];
    int rank = (int)(woff + inc) - ties;
    for (int j = jb; j < je && rank < kk; ++j) {
        if (sc[j] == T) {
            int o = atomicAdd(&cnt_out, 1);
            topidx[t * TOPK + o] = j;
            ++rank;
        }
    }
    if (tid == 0) topcnt[t] = TOPK;
}

// ---------------- Sparse SDPA v4: one head per wave, grid (S, 4) ----------------
__global__ __launch_bounds__(256) void attn_kernel(
    const unsigned short* __restrict__ Qb, const unsigned short* __restrict__ Kb,
    const unsigned short* __restrict__ Vb,
    const int* __restrict__ topidx, const int* __restrict__ topcnt,
    unsigned short* __restrict__ out)
{
    int t = blockIdx.x, tid = threadIdx.x;
    __shared__ int sel[TOPK];
    if (tid < TOPK) sel[tid] = topidx[t * TOPK + tid];
    __syncthreads();
    int cnt = topcnt[t];
    int lane = tid & 63, wv = tid >> 6;
    int h = blockIdx.y * 4 + wv;
    int klo = lane >> 3, oct = lane & 7;
    int rows[8];
    bool valid[8];
#pragma unroll
    for (int kg = 0; kg < 8; ++kg) {
        int k = kg * 8 + klo;
        valid[kg] = (k < cnt);
        rows[kg] = sel[valid[kg] ? k : 0];
    }
    bf16x8 q8 = *(const bf16x8*)(Qb + (size_t)t * D_MODEL + h * HDIM + oct * 8);
    float qf[8];
#pragma unroll
    for (int e = 0; e < 8; ++e) qf[e] = bf2f((unsigned short)q8[e]);

    const unsigned short* kbase = Kb + (size_t)h * S_LEN * HDIM + oct * 8;
    float p[8];
#pragma unroll
    for (int kg = 0; kg < 8; ++kg) {
        bf16x8 k8 = *(const bf16x8*)(kbase + (size_t)rows[kg] * HDIM);
        float d = 0.f;
#pragma unroll
        for (int e = 0; e < 8; ++e)
            d += bf2f((unsigned short)k8[e]) * qf[e];
        d += __shfl_xor(d, 1);
        d += __shfl_xor(d, 2);
        d += __shfl_xor(d, 4);
        p[kg] = valid[kg] ? d * 0.125f : -INFINITY;
    }
    float m = p[0];
#pragma unroll
    for (int kg = 1; kg < 8; ++kg) m = fmaxf(m, p[kg]);
    m = fmaxf(m, __shfl_xor(m, 8));
    m = fmaxf(m, __shfl_xor(m, 16));
    m = fmaxf(m, __shfl_xor(m, 32));
    float sum = 0.f;
#pragma unroll
    for (int kg = 0; kg < 8; ++kg) { p[kg] = __expf(p[kg] - m); sum += p[kg]; }
    sum += __shfl_xor(sum, 8);
    sum += __shfl_xor(sum, 16);
    sum += __shfl_xor(sum, 32);
    float rs = 1.f / sum;
    const unsigned short* vbase = Vb + (size_t)h * S_LEN * HDIM + oct * 8;
    float facc[8] = {};
#pragma unroll
    for (int kg = 0; kg < 8; ++kg) {
        bf16x8 v8 = *(const bf16x8*)(vbase + (size_t)rows[kg] * HDIM);
        float pw = p[kg] * rs;
#pragma unroll
        for (int e = 0; e < 8; ++e)
            facc[e] += pw * bf2f((unsigned short)v8[e]);
    }
#pragma unroll
    for (int e = 0; e < 8; ++e) {
        facc[e] += __shfl_xor(facc[e], 8);
        facc[e] += __shfl_xor(facc[e], 16);
        facc[e] += __shfl_xor(facc[e], 32);
    }
    if (klo == 0) {
        ushort4 o0 = { f2bf(facc[0]), f2bf(facc[1]), f2bf(facc[2]), f2bf(facc[3]) };
        ushort4 o1 = { f2bf(facc[4]), f2bf(facc[5]), f2bf(facc[6]), f2bf(facc[7]) };
        *(ushort4*)(out + (size_t)t * D_MODEL + h * HDIM + oct * 8) = o0;
        *(ushort4*)(out + (size_t)t * D_MODEL + h * HDIM + oct * 8 + 4) = o1;
    }
}

extern "C" void kernel_launch(void* const* d_in, const int* in_sizes, int n_in,
                              void* d_out, int out_size, void* d_ws, size_t ws_size,
                              hipStream_t stream)
{
    const float* x      = (const float*)d_in[0];
    const float* w_qkv  = (const float*)d_in[1];
    const float* w_o    = (const float*)d_in[2];
    const float* ffn_w1 = (const float*)d_in[3];
    const float* ffn_b1 = (const float*)d_in[4];
    const float* ffn_w2 = (const float*)d_in[5];
    const float* ffn_b2 = (const float*)d_in[6];
    const float* ln1_g  = (const float*)d_in[7];
    const float* ln1_b  = (const float*)d_in[8];
    const float* ln2_g  = (const float*)d_in[9];
    const float* ln2_b  = (const float*)d_in[10];
    const float* idx_wq = (const float*)d_in[11];
    const float* idx_wk = (const float*)d_in[12];
    const float* idx_ww = (const float*)d_in[13];
    float* outp = (float*)d_out;

    const size_t MB = 1ull << 20;
    char* ws = (char*)d_ws;
    float*          normx    = (float*)(ws + 0);
    unsigned short* attno_bf = (unsigned short*)(ws + 0);
    float*          Pf2      = (float*)(ws + 0);
    unsigned short* normx_bf = (unsigned short*)(ws + 8 * MB);
    unsigned short* h2_bf    = normx_bf;
    unsigned short* qkv_bf   = (unsigned short*)(ws + 12 * MB);
    int*            topidx   = (int*)(ws + 12 * MB);
    int*            topcnt   = (int*)(ws + 12 * MB + 512 * 1024);
    unsigned short* wqkv_t   = (unsigned short*)(ws + 24 * MB);
    unsigned short* wo_t     = (unsigned short*)(ws + 30 * MB);
    unsigned short* w1_t     = (unsigned short*)(ws + 32 * MB);
    unsigned short* w2_t     = (unsigned short*)(ws + 40 * MB);
    unsigned short* Qb       = (unsigned short*)(ws + 48 * MB);
    unsigned short* Kb       = (unsigned short*)(ws + 52 * MB);
    unsigned short* Vb       = (unsigned short*)(ws + 56 * MB);
    float*          ctab     = (float*)(ws + 60 * MB);
    float*          stab     = (float*)(ws + 60 * MB + 256 * 1024);
    float*          P_idx    = (float*)(ws + 60 * MB);
    float*          scoresb  = (float*)(ws + 60 * MB);
    float*          Pwo      = (float*)(ws + 60 * MB);
    unsigned short* ffn1_bf  = (unsigned short*)(ws + 60 * MB);
    float*          QIW      = (float*)(ws + 76 * MB);
    float*          Wc       = (float*)(ws + 79 * MB);

    dim3 blk256(256);
    auto g64n = [](int N, int M) { return dim3(N / 64, M / 128); };

    // 1. LN1 -> fp32 (indexer) + bf16 (qkv gemm)
    ln_kernel<<<S_LEN, blk256, 0, stream>>>(x, ln1_g, ln1_b, normx, normx_bf);
    // 2. rope tables + weight prep
    rope_table_kernel<<<(S_LEN * 32) / 256, blk256, 0, stream>>>(ctab, stab);
    wtrans_kernel<<<dim3(3 * D_MODEL / 32, D_MODEL / 32), blk256, 0, stream>>>(w_qkv, wqkv_t, D_MODEL, 3 * D_MODEL);
    wtrans_kernel<<<dim3(D_MODEL / 32, D_MODEL / 32), blk256, 0, stream>>>(w_o, wo_t, D_MODEL, D_MODEL);
    wtrans_kernel<<<dim3(DFF / 32, D_MODEL / 32), blk256, 0, stream>>>(ffn_w1, w1_t, D_MODEL, DFF);
    wtrans_kernel<<<dim3(D_MODEL / 32, DFF / 32), blk256, 0, stream>>>(ffn_w2, w2_t, DFF, D_MODEL);
    wpack_kernel<<<(D_MODEL * NIDX + 255) / 256, blk256, 0, stream>>>(idx_wq, idx_wk, idx_ww, Wc);
    // 3. qkv = norm_x @ w_qkv (bf16 out only; 768 blocks)
    gemm_bf16_n64<<<g64n(3 * D_MODEL, S_LEN), blk256, 0, stream>>>(normx_bf, wqkv_t,
        nullptr, qkv_bf, nullptr, nullptr, S_LEN, 3 * D_MODEL, D_MODEL, 0, nullptr, D_MODEL);
    // 4. RoPE + pack Q/K/V (frees qkv_bf + ctab/stab for P_idx)
    rope_pack_kernel<<<S_LEN, dim3(512), 0, stream>>>(qkv_bf, ctab, stab, Qb, Kb, Vb);
    // 5. fused indexer projections (fp32, split-K=4 -> 768 blocks; feeds discrete top-k)
    gemm64<<<dim3((NIDX + 63) / 64, S_LEN / 64, 4), blk256, 0, stream>>>(normx, Wc,
        nullptr, S_LEN, NIDX, D_MODEL, P_idx, D_MODEL / 4);
    kreduce_kernel<<<1024, blk256, 0, stream>>>(P_idx, 4, QIW, nullptr, nullptr, S_LEN, NIDX);
    // 6. indexer scores v2 (64x64 tiles; overwrites dead P_idx region)
    scores_kernel<<<dim3(32, 32), blk256, 0, stream>>>(QIW, scoresb);
    // 7. top-64 per row (radix select; topidx overlays dead qkv_bf)
    topk_kernel<<<S_LEN, blk256, 0, stream>>>(scoresb, topidx, topcnt);
    // 8. sparse attention -> bf16 (one head per wave; overlays dead normx)
    attn_kernel<<<dim3(S_LEN, 4), blk256, 0, stream>>>(Qb, Kb, Vb, topidx, topcnt, attno_bf);
    // 9. x1 = x + attn_out @ w_o  — split-K=2 (512 blocks) into Pwo, then reduce
    gemm_bf16_n64<<<dim3(D_MODEL / 64, S_LEN / 128, 2), blk256, 0, stream>>>(attno_bf, wo_t,
        nullptr, nullptr, nullptr, nullptr, S_LEN, D_MODEL, D_MODEL, 0, Pwo, D_MODEL / 2);
    kreduce_kernel<<<1024, blk256, 0, stream>>>(Pwo, 2, outp, nullptr, x, S_LEN, D_MODEL);
    // 10. h = LN2(x1) -> bf16
    ln_kernel<<<S_LEN, blk256, 0, stream>>>(outp, ln2_g, ln2_b, nullptr, h2_bf);
    // 11. ffn1 = gelu(h @ w1 + b1) -> bf16 (overlays dead Pwo/scoresb; 1024 blocks)
    gemm_bf16_n64<<<g64n(DFF, S_LEN), blk256, 0, stream>>>(h2_bf, w1_t,
        nullptr, ffn1_bf, ffn_b1, nullptr, S_LEN, DFF, D_MODEL, 1, nullptr, D_MODEL);
    // 12. out = x1 + ffn1 @ w2 + b2 — split-K=4 (1024 blocks) into Pf2, then reduce
    gemm_bf16_n64<<<dim3(D_MODEL / 64, S_LEN / 128, 4), blk256, 0, stream>>>(ffn1_bf, w2_t,
        nullptr, nullptr, nullptr, nullptr, S_LEN, D_MODEL, DFF, 0, Pf2, DFF / 4);
    kreduce_kernel<<<1024, blk256, 0, stream>>>(Pf2, 4, outp, ffn_b2, outp, S_LEN, D_MODEL);
}